// Round 7
// baseline (569.397 us; speedup 1.0000x reference)
//
#include <hip/hip_runtime.h>

#define T_ 48
#define B_ 32
#define N_ 96
#define E_ 24576
#define BN_ (B_*N_)      // 3072
#define M_ (T_*BN_)      // 147456
#define FIN_ 16
#define H_ 128
#define C_ 500
#define TE_ (T_*E_)      // 1179648
#define EPS_ 1e-5f
#define SCAN_NB (M_/256) // 576

typedef __bf16 bf16x8 __attribute__((ext_vector_type(8)));
typedef float  f32x4  __attribute__((ext_vector_type(4)));
typedef _Float16 half2v __attribute__((ext_vector_type(2)));

__device__ __forceinline__ float bf2f(ushort u) {
    union { unsigned int i; float f; } v;
    v.i = ((unsigned int)u) << 16;
    return v.f;
}
__device__ __forceinline__ float bits2f(unsigned int u) {
    union { unsigned int i; float f; } v;
    v.i = u;
    return v.f;
}
__device__ __forceinline__ ushort f2bf(float f) {
    union { float f; unsigned int i; } v;
    v.f = f;
    unsigned int u = v.i;
    unsigned int r = (u + 0x7fffu + ((u >> 16) & 1u)) >> 16;
    return (ushort)r;
}
__device__ __forceinline__ ushort f2h(float f) {
    _Float16 h = (_Float16)f;
    union { _Float16 h; ushort u; } v;
    v.h = h;
    return v.u;
}
__device__ __forceinline__ float h2f(ushort u) {
    union { ushort u; _Float16 h; } v;
    v.u = u;
    return (float)v.h;
}
__device__ __forceinline__ float dot2pk(unsigned int hbits, unsigned int wbits, float acc) {
#if __has_builtin(__builtin_amdgcn_fdot2)
    return __builtin_amdgcn_fdot2(__builtin_bit_cast(half2v, hbits),
                                  __builtin_bit_cast(half2v, wbits), acc, false);
#else
    half2v hv = __builtin_bit_cast(half2v, hbits);
    half2v wv = __builtin_bit_cast(half2v, wbits);
    acc = fmaf((float)hv[0], (float)wv[0], acc);
    acc = fmaf((float)hv[1], (float)wv[1], acc);
    return acc;
#endif
}
__device__ __forceinline__ float sigm(float x) {
    return 1.f / (1.f + __expf(-x));
}
__device__ __forceinline__ float ftanh(float x) {
    x = fminf(15.f, fmaxf(-15.f, x));
    float e = __expf(2.f * x);
    return (e - 1.f) / (e + 1.f);
}
// slice-major (8 feats/slice) index for node-feature buffers: [f/8][M][8]
__device__ __forceinline__ size_t smi(int node, int f) {
    return ((size_t)(f >> 3) * M_ + node) * 8 + (f & 7);
}

// ---------------- graph preprocessing ----------------

__global__ void count_edges_k(const int* __restrict__ ei, int* __restrict__ cnt) {
    int i = blockIdx.x * blockDim.x + threadIdx.x;
    if (i >= TE_) return;
    int t = i / E_, e = i % E_;
    int dst = ei[(t*2+1)*E_ + e] + t*BN_;
    atomicAdd(&cnt[dst], 1);
}

__global__ void scan1_k(const int* __restrict__ cnt, int* __restrict__ bsum,
                        float* __restrict__ dinv) {
    __shared__ int s[256];
    int i = blockIdx.x*256 + threadIdx.x;
    int v = cnt[i];
    dinv[i] = rsqrtf((float)v + 1.0f);
    s[threadIdx.x] = v;
    __syncthreads();
    for (int d = 128; d > 0; d >>= 1) {
        if (threadIdx.x < d) s[threadIdx.x] += s[threadIdx.x + d];
        __syncthreads();
    }
    if (threadIdx.x == 0) bsum[blockIdx.x] = s[0];
}

__global__ __launch_bounds__(256) void scan2_k(const int* __restrict__ bsum,
                                               int* __restrict__ bexcl,
                                               int* __restrict__ csr_off) {
    __shared__ int part[256];
    int tid = threadIdx.x;
    int base = tid*3;   // 256*3 = 768 >= 576
    int a = (base   < SCAN_NB) ? bsum[base]   : 0;
    int b = (base+1 < SCAN_NB) ? bsum[base+1] : 0;
    int c = (base+2 < SCAN_NB) ? bsum[base+2] : 0;
    int tot = a + b + c;
    part[tid] = tot;
    __syncthreads();
    for (int d = 1; d < 256; d <<= 1) {
        int add = (tid >= d) ? part[tid - d] : 0;
        __syncthreads();
        part[tid] += add;
        __syncthreads();
    }
    int excl = part[tid] - tot;
    if (base   < SCAN_NB) bexcl[base]   = excl;
    if (base+1 < SCAN_NB) bexcl[base+1] = excl + a;
    if (base+2 < SCAN_NB) bexcl[base+2] = excl + a + b;
    if (tid == 255) csr_off[M_] = part[255];
}

__global__ void scan3_k(const int* __restrict__ cnt, const int* __restrict__ bexcl,
                        int* __restrict__ csr_off) {
    __shared__ int s[256];
    int i = blockIdx.x*256 + threadIdx.x;
    int v = cnt[i];
    s[threadIdx.x] = v;
    __syncthreads();
    for (int d = 1; d < 256; d <<= 1) {
        int add = (threadIdx.x >= d) ? s[threadIdx.x - d] : 0;
        __syncthreads();
        s[threadIdx.x] += add;
        __syncthreads();
    }
    csr_off[i] = bexcl[blockIdx.x] + s[threadIdx.x] - v;  // exclusive
}

// pack edges: low16 = src LOCAL index (0..3071), high16 = f16 weight
__global__ void fill_k(const int* __restrict__ ei, const int* __restrict__ csr_off,
                       int* __restrict__ cur, unsigned int* __restrict__ csr_pk,
                       const float* __restrict__ dinv) {
    int i = blockIdx.x * blockDim.x + threadIdx.x;
    if (i >= TE_) return;
    int t = i / E_, e = i % E_;
    int srcl = ei[(t*2+0)*E_ + e];
    int dst  = ei[(t*2+1)*E_ + e] + t*BN_;
    int src  = srcl + t*BN_;
    int pos = atomicAdd(&cur[dst], 1);
    int o = csr_off[dst] + pos;
    float w = dinv[src] * dinv[dst];
    csr_pk[o] = (unsigned int)srcl | ((unsigned int)f2h(w) << 16);
}

// ---------------- conversions / merged weight prep ----------------

__global__ void convx_k(const float* __restrict__ in, ushort* __restrict__ out) {
    int i = blockIdx.x * blockDim.x + threadIdx.x;   // one per 4 elems
    if (i >= M_*FIN_/4) return;
    float4 v = *(const float4*)&in[i*4];
    ushort4 o;
    o.x = f2bf(v.x); o.y = f2bf(v.y); o.z = f2bf(v.z); o.w = f2bf(v.w);
    *(ushort4*)&out[i*4] = o;
}

#define WPREP_TOTAL (384+1024+2048+16384+16384+65536+65536+131072+262144)
__global__ void wprep_k(
    const float* __restrict__ gcn_b, const float* __restrict__ gam,
    const float* __restrict__ bet, const float* __restrict__ mu,
    const float* __restrict__ var,
    float* __restrict__ bn_sc, float* __restrict__ bn_sh,
    const float* __restrict__ bih0, const float* __restrict__ bhh0,
    float* __restrict__ bias0,
    const float* __restrict__ bih1, const float* __restrict__ bhh1,
    float* __restrict__ bias1,
    const float* __restrict__ gcn_w0, const float* __restrict__ gcn_w12,
    ushort* __restrict__ w0t, ushort* __restrict__ w1t, ushort* __restrict__ w2t,
    const float* __restrict__ whh0, const float* __restrict__ whh1,
    unsigned int* __restrict__ wpk0, unsigned int* __restrict__ wpk1,
    const float* __restrict__ wih0, const float* __restrict__ wih1,
    ushort* __restrict__ wih0b, ushort* __restrict__ wih1b)
{
    int i = blockIdx.x * blockDim.x + threadIdx.x;
    if (i >= WPREP_TOTAL) return;
    if (i < 384) {
        float sc = gam[i] * rsqrtf(var[i] + EPS_);
        bn_sc[i] = sc;
        bn_sh[i] = gcn_b[i]*sc + bet[i] - mu[i]*sc;
        return;
    }
    i -= 384;
    if (i < 1024) {
        bias0[i] = bih0[i] + bhh0[i];
        bias1[i] = bih1[i] + bhh1[i];
        return;
    }
    i -= 1024;
    if (i < 2048) {
        int k = i >> 7, c = i & 127;
        w0t[c*16 + k] = f2bf(gcn_w0[i]);
        return;
    }
    i -= 2048;
    if (i < 16384) {
        int k = i >> 7, c = i & 127;
        w1t[c*128 + k] = f2bf(gcn_w12[i]);
        return;
    }
    i -= 16384;
    if (i < 16384) {
        int k = i >> 7, c = i & 127;
        w2t[c*128 + k] = f2bf(gcn_w12[16384 + i]);
        return;
    }
    i -= 16384;
    if (i < 65536) {
        int g = i & 511;
        int qd = i >> 9;
        int dir = qd >> 6, q = qd & 63;
        const float* wr = whh0 + ((long)(dir*512 + g))*128 + 2*q;
        wpk0[i] = (unsigned int)f2h(wr[0]) | ((unsigned int)f2h(wr[1]) << 16);
        return;
    }
    i -= 65536;
    if (i < 65536) {
        int g = i & 511;
        int qd = i >> 9;
        int dir = qd >> 6, q = qd & 63;
        const float* wr = whh1 + ((long)(dir*512 + g))*128 + 2*q;
        wpk1[i] = (unsigned int)f2h(wr[0]) | ((unsigned int)f2h(wr[1]) << 16);
        return;
    }
    i -= 65536;
    if (i < 131072) {
        wih0b[i] = f2bf(wih0[i]);
        return;
    }
    i -= 131072;
    wih1b[i] = f2bf(wih1[i]);
}

// ---------------- gathers ----------------
// out[node,:] = h[node,:]*dinv[node]^2 + sum_e h[src,:]*w[e]

// F=128, LDS-staged per (timestep, 8-feat slice). h/out slice-major [16][M][8].
// Block 256 thr, LDS 48KB, grid (48, 16). 12 dst nodes per thread.
__global__ __launch_bounds__(256) void gather128_lds_k(
    const ushort* __restrict__ h_sl, ushort* __restrict__ out_sl,
    const int* __restrict__ csr_off, const unsigned int* __restrict__ csr_pk,
    const float* __restrict__ dinv)
{
    int t = blockIdx.x;      // timestep
    int s = blockIdx.y;      // feature slice
    int tid = threadIdx.x;
    __shared__ unsigned int lds[4*BN_];   // [4 feat-pair][3072 node] = 48 KB
    int base = t * BN_;

    // stage: contiguous 48KB slice -> LDS (pair-major for conflict-free reads)
    const uint4* gsrc = (const uint4*)(h_sl + ((size_t)s*M_ + base)*8);
    for (int n = tid; n < BN_; n += 256) {
        uint4 v = gsrc[n];
        lds[n] = v.x; lds[BN_ + n] = v.y; lds[2*BN_ + n] = v.z; lds[3*BN_ + n] = v.w;
    }
    __syncthreads();

    int d0 = tid * 12;
    for (int dd = 0; dd < 12; dd++) {
        int dl = d0 + dd;
        int dg = base + dl;
        float dv = dinv[dg];
        float sw = dv * dv;
        float a[8];
        #pragma unroll
        for (int fp = 0; fp < 4; fp++) {
            unsigned int hv = lds[fp*BN_ + dl];
            a[2*fp]   = bits2f(hv << 16) * sw;
            a[2*fp+1] = bits2f(hv & 0xffff0000u) * sw;
        }
        int e0 = csr_off[dg], e1 = csr_off[dg+1];
        for (int j = e0; j < e1; j++) {
            unsigned int pk = csr_pk[j];
            int src = (int)(pk & 0xffffu);
            float w = h2f((ushort)(pk >> 16));
            #pragma unroll
            for (int fp = 0; fp < 4; fp++) {
                unsigned int hv = lds[fp*BN_ + src];
                a[2*fp]   = fmaf(bits2f(hv << 16), w, a[2*fp]);
                a[2*fp+1] = fmaf(bits2f(hv & 0xffff0000u), w, a[2*fp+1]);
            }
        }
        unsigned int ov0 = (unsigned int)f2bf(a[0]) | ((unsigned int)f2bf(a[1]) << 16);
        unsigned int ov1 = (unsigned int)f2bf(a[2]) | ((unsigned int)f2bf(a[3]) << 16);
        unsigned int ov2 = (unsigned int)f2bf(a[4]) | ((unsigned int)f2bf(a[5]) << 16);
        unsigned int ov3 = (unsigned int)f2bf(a[6]) | ((unsigned int)f2bf(a[7]) << 16);
        uint4 o4; o4.x = ov0; o4.y = ov1; o4.z = ov2; o4.w = ov3;
        *(uint4*)(out_sl + ((size_t)s*M_ + dg)*8) = o4;
    }
}

// F=16: flat [M][16] in, slice-major [2][M][8] out. 32 nodes/block, 8 lanes/node.
__global__ __launch_bounds__(256) void gather16_k(
    const ushort* __restrict__ h, ushort* __restrict__ out,
    const int* __restrict__ csr_off, const unsigned int* __restrict__ csr_pk,
    const float* __restrict__ dinv)
{
    int nb = gridDim.x;                  // M/32
    int chunk = nb >> 3;
    int bswz = (blockIdx.x & 7) * chunk + (blockIdx.x >> 3);
    int node = bswz * 32 + (threadIdx.x >> 3);
    int f0 = (threadIdx.x & 7) * 2;
    int tbase = (node / BN_) * BN_;
    float dv = dinv[node];
    ushort2 sv = *(const ushort2*)(h + (long)node*16 + f0);
    float s = dv * dv;
    float a0 = bf2f(sv.x)*s, a1 = bf2f(sv.y)*s;
    int e0 = csr_off[node], e1 = csr_off[node+1];
    int j = e0;
    for (; j + 4 <= e1; j += 4) {
        unsigned int p0 = csr_pk[j], p1 = csr_pk[j+1], p2 = csr_pk[j+2], p3 = csr_pk[j+3];
        int s0 = tbase + (int)(p0 & 0xffffu), s1 = tbase + (int)(p1 & 0xffffu);
        int s2 = tbase + (int)(p2 & 0xffffu), s3 = tbase + (int)(p3 & 0xffffu);
        float w0 = h2f((ushort)(p0 >> 16)), w1 = h2f((ushort)(p1 >> 16));
        float w2 = h2f((ushort)(p2 >> 16)), w3 = h2f((ushort)(p3 >> 16));
        ushort2 v0 = *(const ushort2*)(h + (long)s0*16 + f0);
        ushort2 v1 = *(const ushort2*)(h + (long)s1*16 + f0);
        ushort2 v2 = *(const ushort2*)(h + (long)s2*16 + f0);
        ushort2 v3 = *(const ushort2*)(h + (long)s3*16 + f0);
        a0 += bf2f(v0.x)*w0 + bf2f(v1.x)*w1 + bf2f(v2.x)*w2 + bf2f(v3.x)*w3;
        a1 += bf2f(v0.y)*w0 + bf2f(v1.y)*w1 + bf2f(v2.y)*w2 + bf2f(v3.y)*w3;
    }
    for (; j < e1; j++) {
        unsigned int pk = csr_pk[j];
        int sc = tbase + (int)(pk & 0xffffu);
        float en = h2f((ushort)(pk >> 16));
        ushort2 v = *(const ushort2*)(h + (long)sc*16 + f0);
        a0 += bf2f(v.x)*en; a1 += bf2f(v.y)*en;
    }
    ushort2 o;
    o.x = f2bf(a0); o.y = f2bf(a1);
    *(ushort2*)(out + smi(node, f0)) = o;
}

// ---------------- MFMA GEMM: GCN layers (BN+ReLU+resid epilogue) ----------------
// A, Cout, resid in slice-major [K/8|16][M][8]; Wt flat col-major [128][K].
template<int K, bool HASRES>
__global__ __launch_bounds__(256) void mm_mfma_k(
    const ushort* __restrict__ A, const ushort* __restrict__ Wt,
    ushort* __restrict__ Cout,
    const float* __restrict__ bnsc, const float* __restrict__ bnsh,
    const ushort* __restrict__ resid)
{
    int tid = threadIdx.x;
    int w = tid >> 6, lane = tid & 63;
    int l16 = lane & 15, lh = lane >> 4;
    int row0 = blockIdx.x * 64 + w * 16;

    f32x4 acc[8];
    #pragma unroll
    for (int i = 0; i < 8; i++) acc[i] = (f32x4){0.f, 0.f, 0.f, 0.f};

    #pragma unroll
    for (int k0 = 0; k0 < K; k0 += 32) {
        int ka = k0 + lh*8;
        bf16x8 af;
        bool valid = (K >= 32) || (ka < K);
        if (valid) {
            af = *reinterpret_cast<const bf16x8*>(&A[((size_t)(ka>>3)*M_ + row0 + l16)*8]);
        } else {
            #pragma unroll
            for (int e = 0; e < 8; e++) af[e] = (__bf16)0.f;
        }
        #pragma unroll
        for (int ct = 0; ct < 8; ct++) {
            bf16x8 bfr;
            if (valid) {
                bfr = *reinterpret_cast<const bf16x8*>(&Wt[(long)(ct*16 + l16)*K + ka]);
            } else {
                #pragma unroll
                for (int e = 0; e < 8; e++) bfr[e] = (__bf16)0.f;
            }
            acc[ct] = __builtin_amdgcn_mfma_f32_16x16x32_bf16(af, bfr, acc[ct], 0, 0, 0);
        }
    }

    #pragma unroll
    for (int ct = 0; ct < 8; ct++) {
        int col = ct*16 + l16;
        float sc = bnsc[col], sh = bnsh[col];
        #pragma unroll
        for (int r = 0; r < 4; r++) {
            int row = row0 + lh*4 + r;
            float v = acc[ct][r] * sc + sh;
            v = fmaxf(v, 0.f);
            if (HASRES) v += bf2f(resid[smi(row, col)]);
            Cout[smi(row, col)] = f2bf(v);
        }
    }
}

// ---------------- MFMA GEMM: LSTM input projection (both dirs via blockIdx.z) ----
// A flat [Mr][K] bf16.
template<int K>
__global__ __launch_bounds__(256) void mm_pre_k(
    const ushort* __restrict__ A, const ushort* __restrict__ Wt_all,
    float* __restrict__ Cout_all, const float* __restrict__ bias_all)
{
    int dir = blockIdx.z;
    const ushort* Wt = Wt_all + (size_t)dir * 512 * K;
    float* Cout = Cout_all + (size_t)dir * T_ * B_ * 512;
    const float* bias = bias_all + dir * 512;

    int tid = threadIdx.x;
    int w = tid >> 6, lane = tid & 63;
    int l16 = lane & 15, lh = lane >> 4;
    int row0 = blockIdx.x * 64 + w * 16;
    int c0 = blockIdx.y * 128;

    f32x4 acc[8];
    #pragma unroll
    for (int i = 0; i < 8; i++) acc[i] = (f32x4){0.f, 0.f, 0.f, 0.f};

    #pragma unroll
    for (int k0 = 0; k0 < K; k0 += 32) {
        int ka = k0 + lh*8;
        bf16x8 af = *reinterpret_cast<const bf16x8*>(&A[(long)(row0 + l16)*K + ka]);
        #pragma unroll
        for (int ct = 0; ct < 8; ct++) {
            bf16x8 bfr = *reinterpret_cast<const bf16x8*>(&Wt[(long)(c0 + ct*16 + l16)*K + ka]);
            acc[ct] = __builtin_amdgcn_mfma_f32_16x16x32_bf16(af, bfr, acc[ct], 0, 0, 0);
        }
    }

    #pragma unroll
    for (int ct = 0; ct < 8; ct++) {
        int col = c0 + ct*16 + l16;
        float bv = bias[col];
        #pragma unroll
        for (int r = 0; r < 4; r++) {
            int row = row0 + lh*4 + r;
            Cout[(long)row*512 + col] = acc[ct][r] + bv;
        }
    }
}

// ---------------- mean pool (slice-major bf16 in, flat bf16 out) ----------------

__global__ void meanpool_k(const ushort* __restrict__ h, ushort* __restrict__ embb) {
    int row = blockIdx.x;            // t*B + b
    int t = row / B_, b = row - t*B_;
    int hh = threadIdx.x;
    int node0 = t*BN_ + b*N_;
    const ushort* base = h + ((size_t)(hh>>3)*M_)*8 + (hh&7);
    float acc = 0.f;
    for (int n = 0; n < N_; n++) acc += bf2f(base[(size_t)(node0 + n)*8]);
    embb[(long)row*H_ + hh] = f2bf(acc * (1.f / N_));
}

// ---------------- LSTM scan: f16 dot2, k-split x2, pre-prefetch ----------------
__global__ __launch_bounds__(1024) void lstm_scan_k(
    const float* __restrict__ pre,            // [2][T*B][512]
    const unsigned int* __restrict__ wpkbuf,  // [2][64][512] packed f16 pairs
    float* __restrict__ out,                  // [T*B][256] f32
    ushort* __restrict__ outb)                // [T*B][256] bf16 (nullable)
{
    int dir = blockIdx.x >> 5;
    int b   = blockIdx.x & 31;
    int tid = threadIdx.x;
    int half = tid >> 9;
    int g    = tid & 511;

    __shared__ ushort h_s[H_];               // f16 bits
    __shared__ float part[1024];
    if (tid < H_) h_s[tid] = 0;
    float creg = 0.f;

    const unsigned int* wp = wpkbuf + (long)dir * 64 * 512 + (long)half * 32 * 512;
    unsigned int wpk[32];
    #pragma unroll
    for (int q = 0; q < 32; q++) wpk[q] = wp[q*512 + g];

    const float* pred = pre + (long)dir * T_ * B_ * 512;
    int t = dir ? (T_ - 1) : 0;
    int tstep = dir ? -1 : 1;
    float pv = (half == 0) ? pred[((long)t*B_ + b)*512 + g] : 0.f;
    __syncthreads();

    for (int st = 0; st < T_; st++) {
        int tn = t + tstep;
        tn = (tn < 0) ? 0 : ((tn >= T_) ? T_ - 1 : tn);
        float pvn = (half == 0) ? pred[((long)tn*B_ + b)*512 + g] : 0.f;

        const uint4* h4 = (const uint4*)(h_s + half*64);
        float acc = pv;
        #pragma unroll
        for (int jj = 0; jj < 8; jj++) {
            uint4 hv = h4[jj];
            acc = dot2pk(hv.x, wpk[jj*4+0], acc);
            acc = dot2pk(hv.y, wpk[jj*4+1], acc);
            acc = dot2pk(hv.z, wpk[jj*4+2], acc);
            acc = dot2pk(hv.w, wpk[jj*4+3], acc);
        }
        part[tid] = acc;
        __syncthreads();

        if (tid < H_) {
            float ig = sigm (part[tid]       + part[512 + tid]);
            float fg = sigm (part[128 + tid] + part[640 + tid]);
            float gg = ftanh(part[256 + tid] + part[768 + tid]);
            float og = sigm (part[384 + tid] + part[896 + tid]);
            float c = fg * creg + ig * gg;
            float h = og * ftanh(c);
            creg = c;
            h_s[tid] = f2h(h);
            long orow = ((long)t*B_ + b)*256 + dir*H_ + tid;
            out[orow] = h;
            if (outb) outb[orow] = f2bf(h);
        }
        __syncthreads();
        pv = pvn;
        t = tn;
    }
}

// ---------------- attention ----------------

__global__ __launch_bounds__(128) void attn_a_k(
    const float* __restrict__ out2, const float* __restrict__ w1,
    const float* __restrict__ b1, const float* __restrict__ w2,
    const float* __restrict__ b2v, float* __restrict__ a)
{
    int row = blockIdx.x;
    int j = threadIdx.x;
    const float* xr = out2 + (long)row * 256;
    float acc = b1[j];
    for (int k = 0; k < 256; k++) acc += xr[k] * w1[k*128 + j];
    float u = tanhf(acc) * w2[j];
    __shared__ float red[128];
    red[j] = u;
    __syncthreads();
    for (int d = 64; d > 0; d >>= 1) {
        if (j < d) red[j] += red[j + d];
        __syncthreads();
    }
    if (j == 0) {
        int t = row / B_, b = row - t*B_;
        a[b*T_ + t] = red[0] + b2v[0];
    }
}

__global__ __launch_bounds__(256) void attn_pool_k(
    const float* __restrict__ out2, const float* __restrict__ a,
    float* __restrict__ wsv)
{
    int b = blockIdx.x;
    __shared__ float w[T_];
    if (threadIdx.x == 0) {
        float m = -1e30f;
        for (int t = 0; t < T_; t++) m = fmaxf(m, a[b*T_ + t]);
        float s = 0.f;
        for (int t = 0; t < T_; t++) { float e = __expf(a[b*T_ + t] - m); w[t] = e; s += e; }
        float inv = 1.f / s;
        for (int t = 0; t < T_; t++) w[t] *= inv;
    }
    __syncthreads();
    int h2 = threadIdx.x;
    float acc = 0.f;
    for (int t = 0; t < T_; t++) acc += w[t] * out2[((long)t*B_ + b)*256 + h2];
    wsv[b*256 + h2] = acc;
}

// ---------------- FC head + log_softmax ----------------

__global__ __launch_bounds__(512) void head_k(
    const float* __restrict__ wsv, const float* __restrict__ w1,
    const float* __restrict__ b1, const float* __restrict__ w2,
    const float* __restrict__ b2, float* __restrict__ outp)
{
    int b = blockIdx.x;
    int tid = threadIdx.x;
    __shared__ float r[128];
    __shared__ float y[C_];
    __shared__ float red[512];
    if (tid < 128) {
        float acc = b1[tid];
        for (int k = 0; k < 256; k++) acc += wsv[b*256 + k] * w1[k*128 + tid];
        r[tid] = fmaxf(acc, 0.f);
    }
    __syncthreads();
    for (int c = tid; c < C_; c += 512) {
        float acc = b2[c];
        for (int k = 0; k < 128; k++) acc += r[k] * w2[k*C_ + c];
        y[c] = acc;
    }
    __syncthreads();
    float m = -1e30f;
    for (int c = tid; c < C_; c += 512) m = fmaxf(m, y[c]);
    red[tid] = m;
    __syncthreads();
    for (int d = 256; d > 0; d >>= 1) {
        if (tid < d) red[tid] = fmaxf(red[tid], red[tid + d]);
        __syncthreads();
    }
    m = red[0];
    __syncthreads();
    float s = 0.f;
    for (int c = tid; c < C_; c += 512) s += __expf(y[c] - m);
    red[tid] = s;
    __syncthreads();
    for (int d = 256; d > 0; d >>= 1) {
        if (tid < d) red[tid] += red[tid + d];
        __syncthreads();
    }
    float lse = m + logf(red[0]);
    for (int c = tid; c < C_; c += 512) outp[(long)b*C_ + c] = y[c] - lse;
}

// ---------------- launch ----------------

extern "C" void kernel_launch(void* const* d_in, const int* in_sizes, int n_in,
                              void* d_out, int out_size, void* d_ws, size_t ws_size,
                              hipStream_t stream) {
    const float* x        = (const float*)d_in[0];
    const int*   ei       = (const int*)d_in[1];
    const float* gcn_w0   = (const float*)d_in[2];
    const float* gcn_w12  = (const float*)d_in[3];
    const float* gcn_b    = (const float*)d_in[4];
    const float* bn_gamma = (const float*)d_in[5];
    const float* bn_beta  = (const float*)d_in[6];
    const float* bn_mean  = (const float*)d_in[7];
    const float* bn_var   = (const float*)d_in[8];
    const float* wih0     = (const float*)d_in[9];
    const float* whh0     = (const float*)d_in[10];
    const float* bih0     = (const float*)d_in[11];
    const float* bhh0     = (const float*)d_in[12];
    const float* wih1     = (const float*)d_in[13];
    const float* whh1     = (const float*)d_in[14];
    const float* bih1     = (const float*)d_in[15];
    const float* bhh1     = (const float*)d_in[16];
    const float* attn_w1  = (const float*)d_in[17];
    const float* attn_b1  = (const float*)d_in[18];
    const float* attn_w2  = (const float*)d_in[19];
    const float* attn_b2  = (const float*)d_in[20];
    const float* fc1_w    = (const float*)d_in[21];
    const float* fc1_b    = (const float*)d_in[22];
    const float* fc2_w    = (const float*)d_in[23];
    const float* fc2_b    = (const float*)d_in[24];

    char* p = (char*)d_ws;
    auto alloc = [&](size_t bytes) {
        void* r = (void*)p;
        p += (bytes + 255) & ~(size_t)255;
        return r;
    };
    ushort* xb     = (ushort*)alloc((size_t)M_*FIN_*2);
    ushort* aggbuf = (ushort*)alloc((size_t)M_*H_*2);
    ushort* hbA    = (ushort*)alloc((size_t)M_*H_*2);
    ushort* hbB    = (ushort*)alloc((size_t)M_*H_*2);
    int*   cnt     = (int*)  alloc((size_t)M_*4);   // cnt + csr_cur contiguous
    int*   csr_cur = (int*)  alloc((size_t)M_*4);   // (single memset covers both)
    float* dinv    = (float*)alloc((size_t)M_*4);
    int*   bsum    = (int*)  alloc((size_t)SCAN_NB*4);
    int*   bexcl   = (int*)  alloc((size_t)SCAN_NB*4);
    int*   csr_off = (int*)  alloc((size_t)(M_+1)*4);
    unsigned int* csr_pk = (unsigned int*)alloc((size_t)TE_*4);
    float* bn_sc   = (float*)alloc(384*4);
    float* bn_sh   = (float*)alloc(384*4);
    float* bias0   = (float*)alloc(1024*4);
    float* bias1   = (float*)alloc(1024*4);
    ushort* w0t    = (ushort*)alloc((size_t)128*16*2);
    ushort* w1t    = (ushort*)alloc((size_t)128*128*2);
    ushort* w2t    = (ushort*)alloc((size_t)128*128*2);
    unsigned int* wpk0 = (unsigned int*)alloc((size_t)2*64*512*4);
    unsigned int* wpk1 = (unsigned int*)alloc((size_t)2*64*512*4);
    ushort* wih0b  = (ushort*)alloc((size_t)2*512*128*2);
    ushort* wih1b  = (ushort*)alloc((size_t)2*512*256*2);
    ushort* embb   = (ushort*)alloc((size_t)T_*B_*H_*2);
    float* pre     = (float*)alloc((size_t)2*T_*B_*512*4);
    float* out1    = (float*)alloc((size_t)T_*B_*256*4);
    ushort* out1b  = (ushort*)alloc((size_t)T_*B_*256*2);
    float* out2v   = (float*)alloc((size_t)T_*B_*256*4);
    float* attn_av = (float*)alloc((size_t)B_*T_*4);
    float* wsv     = (float*)alloc((size_t)B_*256*4);

    // --- graph preprocessing (CSR by dst, packed u16 src + f16 weight) ---
    hipMemsetAsync(cnt, 0, (size_t)2*M_*4, stream);   // cnt + csr_cur
    count_edges_k<<<(TE_+255)/256, 256, 0, stream>>>(ei, cnt);
    scan1_k<<<SCAN_NB, 256, 0, stream>>>(cnt, bsum, dinv);
    scan2_k<<<1, 256, 0, stream>>>(bsum, bexcl, csr_off);
    scan3_k<<<SCAN_NB, 256, 0, stream>>>(cnt, bexcl, csr_off);
    fill_k<<<(TE_+255)/256, 256, 0, stream>>>(ei, csr_off, csr_cur, csr_pk, dinv);

    // --- weight prep (merged) ---
    wprep_k<<<(WPREP_TOTAL+255)/256, 256, 0, stream>>>(
        gcn_b, bn_gamma, bn_beta, bn_mean, bn_var, bn_sc, bn_sh,
        bih0, bhh0, bias0, bih1, bhh1, bias1,
        gcn_w0, gcn_w12, w0t, w1t, w2t,
        whh0, whh1, wpk0, wpk1,
        wih0, wih1, wih0b, wih1b);
    convx_k<<<(M_*FIN_/4 + 255)/256, 256, 0, stream>>>(x, xb);

    // --- GCN layer 0 ---
    gather16_k<<<M_/32, 256, 0, stream>>>(xb, aggbuf, csr_off, csr_pk, dinv);
    mm_mfma_k<16, false><<<M_/64, 256, 0, stream>>>(aggbuf, w0t, hbA,
                                                    bn_sc + 0, bn_sh + 0, nullptr);
    // --- GCN layer 1 ---
    gather128_lds_k<<<dim3(T_, 16), 256, 0, stream>>>(hbA, aggbuf, csr_off, csr_pk, dinv);
    mm_mfma_k<128, true><<<M_/64, 256, 0, stream>>>(aggbuf, w1t, hbB,
                                                    bn_sc + 128, bn_sh + 128, hbA);
    // --- GCN layer 2 ---
    gather128_lds_k<<<dim3(T_, 16), 256, 0, stream>>>(hbB, aggbuf, csr_off, csr_pk, dinv);
    mm_mfma_k<128, true><<<M_/64, 256, 0, stream>>>(aggbuf, w2t, hbA,
                                                    bn_sc + 256, bn_sh + 256, hbB);

    // --- mean pool -> embb [T*B,128] bf16 ---
    meanpool_k<<<T_*B_, 128, 0, stream>>>(hbA, embb);

    // --- BiLSTM layer 0 ---
    mm_pre_k<128><<<dim3((T_*B_)/64, 4, 2), 256, 0, stream>>>(embb, wih0b, pre, bias0);
    lstm_scan_k<<<64, 1024, 0, stream>>>(pre, wpk0, out1, out1b);

    // --- BiLSTM layer 1 ---
    mm_pre_k<256><<<dim3((T_*B_)/64, 4, 2), 256, 0, stream>>>(out1b, wih1b, pre, bias1);
    lstm_scan_k<<<64, 1024, 0, stream>>>(pre, wpk1, out2v, nullptr);

    // --- attention ---
    attn_a_k<<<T_*B_, 128, 0, stream>>>(out2v, attn_w1, attn_b1, attn_w2, attn_b2, attn_av);
    attn_pool_k<<<B_, 256, 0, stream>>>(out2v, attn_av, wsv);

    // --- head ---
    head_k<<<B_, 512, 0, stream>>>(wsv, fc1_w, fc1_b, fc2_w, fc2_b, (float*)d_out);
}

// Round 8
// 467.666 us; speedup vs baseline: 1.2175x; 1.2175x over previous
//
#include <hip/hip_runtime.h>

#define T_ 48
#define B_ 32
#define N_ 96
#define E_ 24576
#define BN_ (B_*N_)      // 3072
#define M_ (T_*BN_)      // 147456
#define FIN_ 16
#define H_ 128
#define C_ 500
#define TE_ (T_*E_)      // 1179648
#define EPS_ 1e-5f
#define SCAN_NB (M_/256) // 576

typedef _Float16 f16x8 __attribute__((ext_vector_type(8)));
typedef float    f32x4 __attribute__((ext_vector_type(4)));
typedef _Float16 half2v __attribute__((ext_vector_type(2)));

__device__ __forceinline__ ushort f2h(float f) {
    _Float16 h = (_Float16)f;
    union { _Float16 h; ushort u; } v;
    v.h = h;
    return v.u;
}
__device__ __forceinline__ float h2f(ushort u) {
    union { ushort u; _Float16 h; } v;
    v.u = u;
    return (float)v.h;
}
__device__ __forceinline__ half2v pkfma(unsigned int v, unsigned int w, half2v acc) {
#if __has_builtin(__builtin_elementwise_fma)
    return __builtin_elementwise_fma(__builtin_bit_cast(half2v, v),
                                     __builtin_bit_cast(half2v, w), acc);
#else
    half2v hv = __builtin_bit_cast(half2v, v);
    half2v wv = __builtin_bit_cast(half2v, w);
    acc[0] += hv[0]*wv[0];
    acc[1] += hv[1]*wv[1];
    return acc;
#endif
}
__device__ __forceinline__ float dot2pk(unsigned int hbits, unsigned int wbits, float acc) {
#if __has_builtin(__builtin_amdgcn_fdot2)
    return __builtin_amdgcn_fdot2(__builtin_bit_cast(half2v, hbits),
                                  __builtin_bit_cast(half2v, wbits), acc, false);
#else
    half2v hv = __builtin_bit_cast(half2v, hbits);
    half2v wv = __builtin_bit_cast(half2v, wbits);
    acc = fmaf((float)hv[0], (float)wv[0], acc);
    acc = fmaf((float)hv[1], (float)wv[1], acc);
    return acc;
#endif
}
__device__ __forceinline__ float sigm(float x) {
    return 1.f / (1.f + __expf(-x));
}
__device__ __forceinline__ float ftanh(float x) {
    x = fminf(15.f, fmaxf(-15.f, x));
    float e = __expf(2.f * x);
    return (e - 1.f) / (e + 1.f);
}

// ---------------- graph preprocessing ----------------

__global__ void count_edges_k(const int* __restrict__ ei, int* __restrict__ cnt) {
    int i = blockIdx.x * blockDim.x + threadIdx.x;
    if (i >= TE_) return;
    int t = i / E_, e = i % E_;
    int dst = ei[(t*2+1)*E_ + e] + t*BN_;
    atomicAdd(&cnt[dst], 1);
}

__global__ void scan1_k(const int* __restrict__ cnt, int* __restrict__ bsum,
                        float* __restrict__ dinv) {
    __shared__ int s[256];
    int i = blockIdx.x*256 + threadIdx.x;
    int v = cnt[i];
    dinv[i] = rsqrtf((float)v + 1.0f);
    s[threadIdx.x] = v;
    __syncthreads();
    for (int d = 128; d > 0; d >>= 1) {
        if (threadIdx.x < d) s[threadIdx.x] += s[threadIdx.x + d];
        __syncthreads();
    }
    if (threadIdx.x == 0) bsum[blockIdx.x] = s[0];
}

__global__ __launch_bounds__(256) void scan2_k(const int* __restrict__ bsum,
                                               int* __restrict__ bexcl,
                                               int* __restrict__ csr_off) {
    __shared__ int part[256];
    int tid = threadIdx.x;
    int base = tid*3;   // 256*3 = 768 >= 576
    int a = (base   < SCAN_NB) ? bsum[base]   : 0;
    int b = (base+1 < SCAN_NB) ? bsum[base+1] : 0;
    int c = (base+2 < SCAN_NB) ? bsum[base+2] : 0;
    int tot = a + b + c;
    part[tid] = tot;
    __syncthreads();
    for (int d = 1; d < 256; d <<= 1) {
        int add = (tid >= d) ? part[tid - d] : 0;
        __syncthreads();
        part[tid] += add;
        __syncthreads();
    }
    int excl = part[tid] - tot;
    if (base   < SCAN_NB) bexcl[base]   = excl;
    if (base+1 < SCAN_NB) bexcl[base+1] = excl + a;
    if (base+2 < SCAN_NB) bexcl[base+2] = excl + a + b;
    if (tid == 255) csr_off[M_] = part[255];
}

__global__ void scan3_k(const int* __restrict__ cnt, const int* __restrict__ bexcl,
                        int* __restrict__ csr_off) {
    __shared__ int s[256];
    int i = blockIdx.x*256 + threadIdx.x;
    int v = cnt[i];
    s[threadIdx.x] = v;
    __syncthreads();
    for (int d = 1; d < 256; d <<= 1) {
        int add = (threadIdx.x >= d) ? s[threadIdx.x - d] : 0;
        __syncthreads();
        s[threadIdx.x] += add;
        __syncthreads();
    }
    csr_off[i] = bexcl[blockIdx.x] + s[threadIdx.x] - v;  // exclusive
}

// pack edges: low16 = src LOCAL index (0..3071), high16 = f16 weight
__global__ void fill_k(const int* __restrict__ ei, const int* __restrict__ csr_off,
                       int* __restrict__ cur, unsigned int* __restrict__ csr_pk,
                       const float* __restrict__ dinv) {
    int i = blockIdx.x * blockDim.x + threadIdx.x;
    if (i >= TE_) return;
    int t = i / E_, e = i % E_;
    int srcl = ei[(t*2+0)*E_ + e];
    int dst  = ei[(t*2+1)*E_ + e] + t*BN_;
    int src  = srcl + t*BN_;
    int pos = atomicAdd(&cur[dst], 1);
    int o = csr_off[dst] + pos;
    float w = dinv[src] * dinv[dst];
    csr_pk[o] = (unsigned int)srcl | ((unsigned int)f2h(w) << 16);
}

// ---------------- conversions / merged weight prep ----------------

__global__ void convx_k(const float* __restrict__ in, ushort* __restrict__ out) {
    int i = blockIdx.x * blockDim.x + threadIdx.x;   // one per 4 elems
    if (i >= M_*FIN_/4) return;
    float4 v = *(const float4*)&in[i*4];
    ushort4 o;
    o.x = f2h(v.x); o.y = f2h(v.y); o.z = f2h(v.z); o.w = f2h(v.w);
    *(ushort4*)&out[i*4] = o;
}

#define WPREP_TOTAL (384+1024+2048+16384+16384+65536+65536+131072+262144)
__global__ void wprep_k(
    const float* __restrict__ gcn_b, const float* __restrict__ gam,
    const float* __restrict__ bet, const float* __restrict__ mu,
    const float* __restrict__ var,
    float* __restrict__ bn_sc, float* __restrict__ bn_sh,
    const float* __restrict__ bih0, const float* __restrict__ bhh0,
    float* __restrict__ bias0,
    const float* __restrict__ bih1, const float* __restrict__ bhh1,
    float* __restrict__ bias1,
    const float* __restrict__ gcn_w0, const float* __restrict__ gcn_w12,
    ushort* __restrict__ w0t, ushort* __restrict__ w1t, ushort* __restrict__ w2t,
    const float* __restrict__ whh0, const float* __restrict__ whh1,
    unsigned int* __restrict__ wpk0, unsigned int* __restrict__ wpk1,
    const float* __restrict__ wih0, const float* __restrict__ wih1,
    ushort* __restrict__ wih0b, ushort* __restrict__ wih1b)
{
    int i = blockIdx.x * blockDim.x + threadIdx.x;
    if (i >= WPREP_TOTAL) return;
    if (i < 384) {
        float sc = gam[i] * rsqrtf(var[i] + EPS_);
        bn_sc[i] = sc;
        bn_sh[i] = gcn_b[i]*sc + bet[i] - mu[i]*sc;
        return;
    }
    i -= 384;
    if (i < 1024) {
        bias0[i] = bih0[i] + bhh0[i];
        bias1[i] = bih1[i] + bhh1[i];
        return;
    }
    i -= 1024;
    if (i < 2048) {
        int k = i >> 7, c = i & 127;
        w0t[c*16 + k] = f2h(gcn_w0[i]);
        return;
    }
    i -= 2048;
    if (i < 16384) {
        int k = i >> 7, c = i & 127;
        w1t[c*128 + k] = f2h(gcn_w12[i]);
        return;
    }
    i -= 16384;
    if (i < 16384) {
        int k = i >> 7, c = i & 127;
        w2t[c*128 + k] = f2h(gcn_w12[16384 + i]);
        return;
    }
    i -= 16384;
    if (i < 65536) {
        int g = i & 511;
        int qd = i >> 9;
        int dir = qd >> 6, q = qd & 63;
        const float* wr = whh0 + ((long)(dir*512 + g))*128 + 2*q;
        wpk0[i] = (unsigned int)f2h(wr[0]) | ((unsigned int)f2h(wr[1]) << 16);
        return;
    }
    i -= 65536;
    if (i < 65536) {
        int g = i & 511;
        int qd = i >> 9;
        int dir = qd >> 6, q = qd & 63;
        const float* wr = whh1 + ((long)(dir*512 + g))*128 + 2*q;
        wpk1[i] = (unsigned int)f2h(wr[0]) | ((unsigned int)f2h(wr[1]) << 16);
        return;
    }
    i -= 65536;
    if (i < 131072) {
        wih0b[i] = f2h(wih0[i]);
        return;
    }
    i -= 131072;
    wih1b[i] = f2h(wih1[i]);
}

// ---------------- f16 gathers (XCD-chunk swizzled, pk_fma) ----------------
// out[node,:] = h[node,:]*dinv[node]^2 + sum_e h[src,:]*w[e]

// F=128: one wave per node; 64 lanes x f16-pair = 256B row per load.
__global__ __launch_bounds__(256) void gather128_k(
    const ushort* __restrict__ h, ushort* __restrict__ out,
    const int* __restrict__ csr_off, const unsigned int* __restrict__ csr_pk,
    const float* __restrict__ dinv)
{
    int nb = gridDim.x;                  // M/4 blocks, 4 waves each; divisible by 8
    int chunk = nb >> 3;
    int bswz = (blockIdx.x & 7) * chunk + (blockIdx.x >> 3);
    int node = bswz * 4 + (threadIdx.x >> 6);
    int tbase = (node / BN_) * BN_;
    int l2 = (threadIdx.x & 63) * 2;     // feature pair
    const ushort* hrow = h + l2;
    float dv = dinv[node];
    ushort swh = f2h(dv * dv);
    unsigned int swp = (unsigned int)swh | ((unsigned int)swh << 16);
    unsigned int selfv = *(const unsigned int*)(hrow + (long)node*128);
    half2v acc0 = __builtin_bit_cast(half2v, selfv);
    acc0[0] = acc0[0] * __builtin_bit_cast(half2v, swp)[0];
    acc0[1] = acc0[1] * __builtin_bit_cast(half2v, swp)[1];
    half2v acc1 = {(_Float16)0.f, (_Float16)0.f};
    int e0 = csr_off[node], e1 = csr_off[node+1];
    int j = e0;
    for (; j + 4 <= e1; j += 4) {
        unsigned int p0 = csr_pk[j], p1 = csr_pk[j+1], p2 = csr_pk[j+2], p3 = csr_pk[j+3];
        int s0 = tbase + (int)(p0 & 0xffffu), s1 = tbase + (int)(p1 & 0xffffu);
        int s2 = tbase + (int)(p2 & 0xffffu), s3 = tbase + (int)(p3 & 0xffffu);
        unsigned int v0 = *(const unsigned int*)(hrow + (long)s0*128);
        unsigned int v1 = *(const unsigned int*)(hrow + (long)s1*128);
        unsigned int v2 = *(const unsigned int*)(hrow + (long)s2*128);
        unsigned int v3 = *(const unsigned int*)(hrow + (long)s3*128);
        unsigned int w0 = p0 >> 16; w0 |= w0 << 16;
        unsigned int w1 = p1 >> 16; w1 |= w1 << 16;
        unsigned int w2 = p2 >> 16; w2 |= w2 << 16;
        unsigned int w3 = p3 >> 16; w3 |= w3 << 16;
        acc0 = pkfma(v0, w0, acc0);
        acc1 = pkfma(v1, w1, acc1);
        acc0 = pkfma(v2, w2, acc0);
        acc1 = pkfma(v3, w3, acc1);
    }
    for (; j < e1; j++) {
        unsigned int pk = csr_pk[j];
        int sc = tbase + (int)(pk & 0xffffu);
        unsigned int v = *(const unsigned int*)(hrow + (long)sc*128);
        unsigned int w = pk >> 16; w |= w << 16;
        acc0 = pkfma(v, w, acc0);
    }
    float a0 = (float)acc0[0] + (float)acc1[0];
    float a1 = (float)acc0[1] + (float)acc1[1];
    unsigned int ov = (unsigned int)f2h(a0) | ((unsigned int)f2h(a1) << 16);
    *(unsigned int*)(out + (long)node*128 + l2) = ov;
}

// F=16: 32 nodes/block, 8 lanes/node, f16-pair per lane
__global__ __launch_bounds__(256) void gather16_k(
    const ushort* __restrict__ h, ushort* __restrict__ out,
    const int* __restrict__ csr_off, const unsigned int* __restrict__ csr_pk,
    const float* __restrict__ dinv)
{
    int nb = gridDim.x;                  // M/32
    int chunk = nb >> 3;
    int bswz = (blockIdx.x & 7) * chunk + (blockIdx.x >> 3);
    int node = bswz * 32 + (threadIdx.x >> 3);
    int f0 = (threadIdx.x & 7) * 2;
    int tbase = (node / BN_) * BN_;
    float dv = dinv[node];
    ushort swh = f2h(dv * dv);
    unsigned int swp = (unsigned int)swh | ((unsigned int)swh << 16);
    unsigned int selfv = *(const unsigned int*)(h + (long)node*16 + f0);
    half2v acc0 = __builtin_bit_cast(half2v, selfv);
    acc0[0] = acc0[0] * __builtin_bit_cast(half2v, swp)[0];
    acc0[1] = acc0[1] * __builtin_bit_cast(half2v, swp)[1];
    half2v acc1 = {(_Float16)0.f, (_Float16)0.f};
    int e0 = csr_off[node], e1 = csr_off[node+1];
    int j = e0;
    for (; j + 4 <= e1; j += 4) {
        unsigned int p0 = csr_pk[j], p1 = csr_pk[j+1], p2 = csr_pk[j+2], p3 = csr_pk[j+3];
        int s0 = tbase + (int)(p0 & 0xffffu), s1 = tbase + (int)(p1 & 0xffffu);
        int s2 = tbase + (int)(p2 & 0xffffu), s3 = tbase + (int)(p3 & 0xffffu);
        unsigned int v0 = *(const unsigned int*)(h + (long)s0*16 + f0);
        unsigned int v1 = *(const unsigned int*)(h + (long)s1*16 + f0);
        unsigned int v2 = *(const unsigned int*)(h + (long)s2*16 + f0);
        unsigned int v3 = *(const unsigned int*)(h + (long)s3*16 + f0);
        unsigned int w0 = p0 >> 16; w0 |= w0 << 16;
        unsigned int w1 = p1 >> 16; w1 |= w1 << 16;
        unsigned int w2 = p2 >> 16; w2 |= w2 << 16;
        unsigned int w3 = p3 >> 16; w3 |= w3 << 16;
        acc0 = pkfma(v0, w0, acc0);
        acc1 = pkfma(v1, w1, acc1);
        acc0 = pkfma(v2, w2, acc0);
        acc1 = pkfma(v3, w3, acc1);
    }
    for (; j < e1; j++) {
        unsigned int pk = csr_pk[j];
        int sc = tbase + (int)(pk & 0xffffu);
        unsigned int v = *(const unsigned int*)(h + (long)sc*16 + f0);
        unsigned int w = pk >> 16; w |= w << 16;
        acc0 = pkfma(v, w, acc0);
    }
    float a0 = (float)acc0[0] + (float)acc1[0];
    float a1 = (float)acc0[1] + (float)acc1[1];
    unsigned int ov = (unsigned int)f2h(a0) | ((unsigned int)f2h(a1) << 16);
    *(unsigned int*)(out + (long)node*16 + f0) = ov;
}

// ---------------- MFMA GEMM: GCN layers (BN+ReLU+resid epilogue), f16 ---------
// A [Mr,K] f16 row-major; Wt [128][K] f16 (col-major W); C [Mr,128] f16.
template<int K, bool HASRES>
__global__ __launch_bounds__(256) void mm_mfma_k(
    const ushort* __restrict__ A, const ushort* __restrict__ Wt,
    ushort* __restrict__ Cout,
    const float* __restrict__ bnsc, const float* __restrict__ bnsh,
    const ushort* __restrict__ resid)
{
    int tid = threadIdx.x;
    int w = tid >> 6, lane = tid & 63;
    int l16 = lane & 15, lh = lane >> 4;
    int row0 = blockIdx.x * 64 + w * 16;

    f32x4 acc[8];
    #pragma unroll
    for (int i = 0; i < 8; i++) acc[i] = (f32x4){0.f, 0.f, 0.f, 0.f};

    #pragma unroll
    for (int k0 = 0; k0 < K; k0 += 32) {
        int ka = k0 + lh*8;
        f16x8 af;
        bool valid = (K >= 32) || (ka < K);
        if (valid) {
            af = *reinterpret_cast<const f16x8*>(&A[(long)(row0 + l16)*K + ka]);
        } else {
            #pragma unroll
            for (int e = 0; e < 8; e++) af[e] = (_Float16)0.f;
        }
        #pragma unroll
        for (int ct = 0; ct < 8; ct++) {
            f16x8 bfr;
            if (valid) {
                bfr = *reinterpret_cast<const f16x8*>(&Wt[(long)(ct*16 + l16)*K + ka]);
            } else {
                #pragma unroll
                for (int e = 0; e < 8; e++) bfr[e] = (_Float16)0.f;
            }
            acc[ct] = __builtin_amdgcn_mfma_f32_16x16x32_f16(af, bfr, acc[ct], 0, 0, 0);
        }
    }

    #pragma unroll
    for (int ct = 0; ct < 8; ct++) {
        int col = ct*16 + l16;
        float sc = bnsc[col], sh = bnsh[col];
        #pragma unroll
        for (int r = 0; r < 4; r++) {
            int row = row0 + lh*4 + r;
            float v = acc[ct][r] * sc + sh;
            v = fmaxf(v, 0.f);
            if (HASRES) v += h2f(resid[(long)row*128 + col]);
            Cout[(long)row*128 + col] = f2h(v);
        }
    }
}

// ---------------- MFMA GEMM: LSTM input projection (both dirs via blockIdx.z) ----
template<int K>
__global__ __launch_bounds__(256) void mm_pre_k(
    const ushort* __restrict__ A, const ushort* __restrict__ Wt_all,
    float* __restrict__ Cout_all, const float* __restrict__ bias_all)
{
    int dir = blockIdx.z;
    const ushort* Wt = Wt_all + (size_t)dir * 512 * K;
    float* Cout = Cout_all + (size_t)dir * T_ * B_ * 512;
    const float* bias = bias_all + dir * 512;

    int tid = threadIdx.x;
    int w = tid >> 6, lane = tid & 63;
    int l16 = lane & 15, lh = lane >> 4;
    int row0 = blockIdx.x * 64 + w * 16;
    int c0 = blockIdx.y * 128;

    f32x4 acc[8];
    #pragma unroll
    for (int i = 0; i < 8; i++) acc[i] = (f32x4){0.f, 0.f, 0.f, 0.f};

    #pragma unroll
    for (int k0 = 0; k0 < K; k0 += 32) {
        int ka = k0 + lh*8;
        f16x8 af = *reinterpret_cast<const f16x8*>(&A[(long)(row0 + l16)*K + ka]);
        #pragma unroll
        for (int ct = 0; ct < 8; ct++) {
            f16x8 bfr = *reinterpret_cast<const f16x8*>(&Wt[(long)(c0 + ct*16 + l16)*K + ka]);
            acc[ct] = __builtin_amdgcn_mfma_f32_16x16x32_f16(af, bfr, acc[ct], 0, 0, 0);
        }
    }

    #pragma unroll
    for (int ct = 0; ct < 8; ct++) {
        int col = c0 + ct*16 + l16;
        float bv = bias[col];
        #pragma unroll
        for (int r = 0; r < 4; r++) {
            int row = row0 + lh*4 + r;
            Cout[(long)row*512 + col] = acc[ct][r] + bv;
        }
    }
}

// ---------------- mean pool (f16 in, f16 out) ----------------

__global__ void meanpool_k(const ushort* __restrict__ h, ushort* __restrict__ embb) {
    int row = blockIdx.x;            // t*B + b
    int t = row / B_, b = row - t*B_;
    int hh = threadIdx.x;
    const ushort* base = h + ((long)t*BN_ + b*N_)*H_ + hh;
    float acc = 0.f;
    for (int n = 0; n < N_; n++) acc += h2f(base[(long)n*H_]);
    embb[(long)row*H_ + hh] = f2h(acc * (1.f / N_));
}

// ---------------- LSTM scan: f16 dot2, k-split x2, pre-prefetch ----------------
__global__ __launch_bounds__(1024) void lstm_scan_k(
    const float* __restrict__ pre,            // [2][T*B][512]
    const unsigned int* __restrict__ wpkbuf,  // [2][64][512] packed f16 pairs
    float* __restrict__ out,                  // [T*B][256] f32
    ushort* __restrict__ outb)                // [T*B][256] f16 (nullable)
{
    int dir = blockIdx.x >> 5;
    int b   = blockIdx.x & 31;
    int tid = threadIdx.x;
    int half = tid >> 9;
    int g    = tid & 511;

    __shared__ ushort h_s[H_];               // f16 bits
    __shared__ float part[1024];
    if (tid < H_) h_s[tid] = 0;
    float creg = 0.f;

    const unsigned int* wp = wpkbuf + (long)dir * 64 * 512 + (long)half * 32 * 512;
    unsigned int wpk[32];
    #pragma unroll
    for (int q = 0; q < 32; q++) wpk[q] = wp[q*512 + g];

    const float* pred = pre + (long)dir * T_ * B_ * 512;
    int t = dir ? (T_ - 1) : 0;
    int tstep = dir ? -1 : 1;
    float pv = (half == 0) ? pred[((long)t*B_ + b)*512 + g] : 0.f;
    __syncthreads();

    for (int st = 0; st < T_; st++) {
        int tn = t + tstep;
        tn = (tn < 0) ? 0 : ((tn >= T_) ? T_ - 1 : tn);
        float pvn = (half == 0) ? pred[((long)tn*B_ + b)*512 + g] : 0.f;

        const uint4* h4 = (const uint4*)(h_s + half*64);
        float acc = pv;
        #pragma unroll
        for (int jj = 0; jj < 8; jj++) {
            uint4 hv = h4[jj];
            acc = dot2pk(hv.x, wpk[jj*4+0], acc);
            acc = dot2pk(hv.y, wpk[jj*4+1], acc);
            acc = dot2pk(hv.z, wpk[jj*4+2], acc);
            acc = dot2pk(hv.w, wpk[jj*4+3], acc);
        }
        part[tid] = acc;
        __syncthreads();

        if (tid < H_) {
            float ig = sigm (part[tid]       + part[512 + tid]);
            float fg = sigm (part[128 + tid] + part[640 + tid]);
            float gg = ftanh(part[256 + tid] + part[768 + tid]);
            float og = sigm (part[384 + tid] + part[896 + tid]);
            float c = fg * creg + ig * gg;
            float h = og * ftanh(c);
            creg = c;
            h_s[tid] = f2h(h);
            long orow = ((long)t*B_ + b)*256 + dir*H_ + tid;
            out[orow] = h;
            if (outb) outb[orow] = f2h(h);
        }
        __syncthreads();
        pv = pvn;
        t = tn;
    }
}

// ---------------- attention ----------------

__global__ __launch_bounds__(128) void attn_a_k(
    const float* __restrict__ out2, const float* __restrict__ w1,
    const float* __restrict__ b1, const float* __restrict__ w2,
    const float* __restrict__ b2v, float* __restrict__ a)
{
    int row = blockIdx.x;
    int j = threadIdx.x;
    const float* xr = out2 + (long)row * 256;
    float acc = b1[j];
    for (int k = 0; k < 256; k++) acc += xr[k] * w1[k*128 + j];
    float u = tanhf(acc) * w2[j];
    __shared__ float red[128];
    red[j] = u;
    __syncthreads();
    for (int d = 64; d > 0; d >>= 1) {
        if (j < d) red[j] += red[j + d];
        __syncthreads();
    }
    if (j == 0) {
        int t = row / B_, b = row - t*B_;
        a[b*T_ + t] = red[0] + b2v[0];
    }
}

__global__ __launch_bounds__(256) void attn_pool_k(
    const float* __restrict__ out2, const float* __restrict__ a,
    float* __restrict__ wsv)
{
    int b = blockIdx.x;
    __shared__ float w[T_];
    if (threadIdx.x == 0) {
        float m = -1e30f;
        for (int t = 0; t < T_; t++) m = fmaxf(m, a[b*T_ + t]);
        float s = 0.f;
        for (int t = 0; t < T_; t++) { float e = __expf(a[b*T_ + t] - m); w[t] = e; s += e; }
        float inv = 1.f / s;
        for (int t = 0; t < T_; t++) w[t] *= inv;
    }
    __syncthreads();
    int h2 = threadIdx.x;
    float acc = 0.f;
    for (int t = 0; t < T_; t++) acc += w[t] * out2[((long)t*B_ + b)*256 + h2];
    wsv[b*256 + h2] = acc;
}

// ---------------- FC head + log_softmax ----------------

__global__ __launch_bounds__(512) void head_k(
    const float* __restrict__ wsv, const float* __restrict__ w1,
    const float* __restrict__ b1, const float* __restrict__ w2,
    const float* __restrict__ b2, float* __restrict__ outp)
{
    int b = blockIdx.x;
    int tid = threadIdx.x;
    __shared__ float r[128];
    __shared__ float y[C_];
    __shared__ float red[512];
    if (tid < 128) {
        float acc = b1[tid];
        for (int k = 0; k < 256; k++) acc += wsv[b*256 + k] * w1[k*128 + tid];
        r[tid] = fmaxf(acc, 0.f);
    }
    __syncthreads();
    for (int c = tid; c < C_; c += 512) {
        float acc = b2[c];
        for (int k = 0; k < 128; k++) acc += r[k] * w2[k*C_ + c];
        y[c] = acc;
    }
    __syncthreads();
    float m = -1e30f;
    for (int c = tid; c < C_; c += 512) m = fmaxf(m, y[c]);
    red[tid] = m;
    __syncthreads();
    for (int d = 256; d > 0; d >>= 1) {
        if (tid < d) red[tid] = fmaxf(red[tid], red[tid + d]);
        __syncthreads();
    }
    m = red[0];
    __syncthreads();
    float s = 0.f;
    for (int c = tid; c < C_; c += 512) s += __expf(y[c] - m);
    red[tid] = s;
    __syncthreads();
    for (int d = 256; d > 0; d >>= 1) {
        if (tid < d) red[tid] += red[tid + d];
        __syncthreads();
    }
    float lse = m + logf(red[0]);
    for (int c = tid; c < C_; c += 512) outp[(long)b*C_ + c] = y[c] - lse;
}

// ---------------- launch ----------------

extern "C" void kernel_launch(void* const* d_in, const int* in_sizes, int n_in,
                              void* d_out, int out_size, void* d_ws, size_t ws_size,
                              hipStream_t stream) {
    const float* x        = (const float*)d_in[0];
    const int*   ei       = (const int*)d_in[1];
    const float* gcn_w0   = (const float*)d_in[2];
    const float* gcn_w12  = (const float*)d_in[3];
    const float* gcn_b    = (const float*)d_in[4];
    const float* bn_gamma = (const float*)d_in[5];
    const float* bn_beta  = (const float*)d_in[6];
    const float* bn_mean  = (const float*)d_in[7];
    const float* bn_var   = (const float*)d_in[8];
    const float* wih0     = (const float*)d_in[9];
    const float* whh0     = (const float*)d_in[10];
    const float* bih0     = (const float*)d_in[11];
    const float* bhh0     = (const float*)d_in[12];
    const float* wih1     = (const float*)d_in[13];
    const float* whh1     = (const float*)d_in[14];
    const float* bih1     = (const float*)d_in[15];
    const float* bhh1     = (const float*)d_in[16];
    const float* attn_w1  = (const float*)d_in[17];
    const float* attn_b1  = (const float*)d_in[18];
    const float* attn_w2  = (const float*)d_in[19];
    const float* attn_b2  = (const float*)d_in[20];
    const float* fc1_w    = (const float*)d_in[21];
    const float* fc1_b    = (const float*)d_in[22];
    const float* fc2_w    = (const float*)d_in[23];
    const float* fc2_b    = (const float*)d_in[24];

    char* p = (char*)d_ws;
    auto alloc = [&](size_t bytes) {
        void* r = (void*)p;
        p += (bytes + 255) & ~(size_t)255;
        return r;
    };
    ushort* xb     = (ushort*)alloc((size_t)M_*FIN_*2);
    ushort* aggbuf = (ushort*)alloc((size_t)M_*H_*2);
    ushort* hbA    = (ushort*)alloc((size_t)M_*H_*2);
    ushort* hbB    = (ushort*)alloc((size_t)M_*H_*2);
    int*   cnt     = (int*)  alloc((size_t)M_*4);   // cnt + csr_cur contiguous
    int*   csr_cur = (int*)  alloc((size_t)M_*4);   // (single memset covers both)
    float* dinv    = (float*)alloc((size_t)M_*4);
    int*   bsum    = (int*)  alloc((size_t)SCAN_NB*4);
    int*   bexcl   = (int*)  alloc((size_t)SCAN_NB*4);
    int*   csr_off = (int*)  alloc((size_t)(M_+1)*4);
    unsigned int* csr_pk = (unsigned int*)alloc((size_t)TE_*4);
    float* bn_sc   = (float*)alloc(384*4);
    float* bn_sh   = (float*)alloc(384*4);
    float* bias0   = (float*)alloc(1024*4);
    float* bias1   = (float*)alloc(1024*4);
    ushort* w0t    = (ushort*)alloc((size_t)128*16*2);
    ushort* w1t    = (ushort*)alloc((size_t)128*128*2);
    ushort* w2t    = (ushort*)alloc((size_t)128*128*2);
    unsigned int* wpk0 = (unsigned int*)alloc((size_t)2*64*512*4);
    unsigned int* wpk1 = (unsigned int*)alloc((size_t)2*64*512*4);
    ushort* wih0b  = (ushort*)alloc((size_t)2*512*128*2);
    ushort* wih1b  = (ushort*)alloc((size_t)2*512*256*2);
    ushort* embb   = (ushort*)alloc((size_t)T_*B_*H_*2);
    float* pre     = (float*)alloc((size_t)2*T_*B_*512*4);
    float* out1    = (float*)alloc((size_t)T_*B_*256*4);
    ushort* out1b  = (ushort*)alloc((size_t)T_*B_*256*2);
    float* out2v   = (float*)alloc((size_t)T_*B_*256*4);
    float* attn_av = (float*)alloc((size_t)B_*T_*4);
    float* wsv     = (float*)alloc((size_t)B_*256*4);

    // --- graph preprocessing (CSR by dst, packed u16 src + f16 weight) ---
    hipMemsetAsync(cnt, 0, (size_t)2*M_*4, stream);   // cnt + csr_cur
    count_edges_k<<<(TE_+255)/256, 256, 0, stream>>>(ei, cnt);
    scan1_k<<<SCAN_NB, 256, 0, stream>>>(cnt, bsum, dinv);
    scan2_k<<<1, 256, 0, stream>>>(bsum, bexcl, csr_off);
    scan3_k<<<SCAN_NB, 256, 0, stream>>>(cnt, bexcl, csr_off);
    fill_k<<<(TE_+255)/256, 256, 0, stream>>>(ei, csr_off, csr_cur, csr_pk, dinv);

    // --- weight prep (merged) ---
    wprep_k<<<(WPREP_TOTAL+255)/256, 256, 0, stream>>>(
        gcn_b, bn_gamma, bn_beta, bn_mean, bn_var, bn_sc, bn_sh,
        bih0, bhh0, bias0, bih1, bhh1, bias1,
        gcn_w0, gcn_w12, w0t, w1t, w2t,
        whh0, whh1, wpk0, wpk1,
        wih0, wih1, wih0b, wih1b);
    convx_k<<<(M_*FIN_/4 + 255)/256, 256, 0, stream>>>(x, xb);

    // --- GCN layer 0 ---
    gather16_k<<<M_/32, 256, 0, stream>>>(xb, aggbuf, csr_off, csr_pk, dinv);
    mm_mfma_k<16, false><<<M_/64, 256, 0, stream>>>(aggbuf, w0t, hbA,
                                                    bn_sc + 0, bn_sh + 0, nullptr);
    // --- GCN layer 1 ---
    gather128_k<<<M_/4, 256, 0, stream>>>(hbA, aggbuf, csr_off, csr_pk, dinv);
    mm_mfma_k<128, true><<<M_/64, 256, 0, stream>>>(aggbuf, w1t, hbB,
                                                    bn_sc + 128, bn_sh + 128, hbA);
    // --- GCN layer 2 ---
    gather128_k<<<M_/4, 256, 0, stream>>>(hbB, aggbuf, csr_off, csr_pk, dinv);
    mm_mfma_k<128, true><<<M_/64, 256, 0, stream>>>(aggbuf, w2t, hbA,
                                                    bn_sc + 256, bn_sh + 256, hbB);

    // --- mean pool -> embb [T*B,128] f16 ---
    meanpool_k<<<T_*B_, 128, 0, stream>>>(hbA, embb);

    // --- BiLSTM layer 0 ---
    mm_pre_k<128><<<dim3((T_*B_)/64, 4, 2), 256, 0, stream>>>(embb, wih0b, pre, bias0);
    lstm_scan_k<<<64, 1024, 0, stream>>>(pre, wpk0, out1, out1b);

    // --- BiLSTM layer 1 ---
    mm_pre_k<256><<<dim3((T_*B_)/64, 4, 2), 256, 0, stream>>>(out1b, wih1b, pre, bias1);
    lstm_scan_k<<<64, 1024, 0, stream>>>(pre, wpk1, out2v, nullptr);

    // --- attention ---
    attn_a_k<<<T_*B_, 128, 0, stream>>>(out2v, attn_w1, attn_b1, attn_w2, attn_b2, attn_av);
    attn_pool_k<<<B_, 256, 0, stream>>>(out2v, attn_av, wsv);

    // --- head ---
    head_k<<<B_, 512, 0, stream>>>(wsv, fc1_w, fc1_b, fc2_w, fc2_b, (float*)d_out);
}

// Round 9
// 451.665 us; speedup vs baseline: 1.2607x; 1.0354x over previous
//
#include <hip/hip_runtime.h>

#define T_ 48
#define B_ 32
#define N_ 96
#define E_ 24576
#define BN_ (B_*N_)      // 3072
#define M_ (T_*BN_)      // 147456
#define FIN_ 16
#define H_ 128
#define C_ 500
#define TE_ (T_*E_)      // 1179648
#define EPS_ 1e-5f
#define SCAN_NB (M_/256) // 576

typedef _Float16 f16x8 __attribute__((ext_vector_type(8)));
typedef float    f32x4 __attribute__((ext_vector_type(4)));
typedef _Float16 half2v __attribute__((ext_vector_type(2)));

__device__ __forceinline__ ushort f2h(float f) {
    _Float16 h = (_Float16)f;
    union { _Float16 h; ushort u; } v;
    v.h = h;
    return v.u;
}
__device__ __forceinline__ float h2f(ushort u) {
    union { ushort u; _Float16 h; } v;
    v.u = u;
    return (float)v.h;
}
__device__ __forceinline__ half2v pkfma(unsigned int v, unsigned int w, half2v acc) {
#if __has_builtin(__builtin_elementwise_fma)
    return __builtin_elementwise_fma(__builtin_bit_cast(half2v, v),
                                     __builtin_bit_cast(half2v, w), acc);
#else
    half2v hv = __builtin_bit_cast(half2v, v);
    half2v wv = __builtin_bit_cast(half2v, w);
    acc[0] += hv[0]*wv[0];
    acc[1] += hv[1]*wv[1];
    return acc;
#endif
}
__device__ __forceinline__ float dot2pk(unsigned int hbits, unsigned int wbits, float acc) {
#if __has_builtin(__builtin_amdgcn_fdot2)
    return __builtin_amdgcn_fdot2(__builtin_bit_cast(half2v, hbits),
                                  __builtin_bit_cast(half2v, wbits), acc, false);
#else
    half2v hv = __builtin_bit_cast(half2v, hbits);
    half2v wv = __builtin_bit_cast(half2v, wbits);
    acc = fmaf((float)hv[0], (float)hv[0]*0.f + (float)wv[0], acc); // unreachable fallback
    return acc;
#endif
}
__device__ __forceinline__ float sigm(float x) {
    return 1.f / (1.f + __expf(-x));
}
__device__ __forceinline__ float ftanh(float x) {
    x = fminf(15.f, fmaxf(-15.f, x));
    float e = __expf(2.f * x);
    return (e - 1.f) / (e + 1.f);
}

// ---------------- graph preprocessing ----------------

__global__ void count_edges_k(const int* __restrict__ ei, int* __restrict__ cnt) {
    int i = blockIdx.x * blockDim.x + threadIdx.x;
    if (i >= TE_) return;
    int t = i / E_, e = i % E_;
    int dst = ei[(t*2+1)*E_ + e] + t*BN_;
    atomicAdd(&cnt[dst], 1);
}

__global__ void scan1_k(const int* __restrict__ cnt, int* __restrict__ bsum,
                        float* __restrict__ dinv) {
    __shared__ int s[256];
    int i = blockIdx.x*256 + threadIdx.x;
    int v = cnt[i];
    dinv[i] = rsqrtf((float)v + 1.0f);
    s[threadIdx.x] = v;
    __syncthreads();
    for (int d = 128; d > 0; d >>= 1) {
        if (threadIdx.x < d) s[threadIdx.x] += s[threadIdx.x + d];
        __syncthreads();
    }
    if (threadIdx.x == 0) bsum[blockIdx.x] = s[0];
}

__global__ __launch_bounds__(256) void scan2_k(const int* __restrict__ bsum,
                                               int* __restrict__ bexcl,
                                               int* __restrict__ csr_off) {
    __shared__ int part[256];
    int tid = threadIdx.x;
    int base = tid*3;   // 256*3 = 768 >= 576
    int a = (base   < SCAN_NB) ? bsum[base]   : 0;
    int b = (base+1 < SCAN_NB) ? bsum[base+1] : 0;
    int c = (base+2 < SCAN_NB) ? bsum[base+2] : 0;
    int tot = a + b + c;
    part[tid] = tot;
    __syncthreads();
    for (int d = 1; d < 256; d <<= 1) {
        int add = (tid >= d) ? part[tid - d] : 0;
        __syncthreads();
        part[tid] += add;
        __syncthreads();
    }
    int excl = part[tid] - tot;
    if (base   < SCAN_NB) bexcl[base]   = excl;
    if (base+1 < SCAN_NB) bexcl[base+1] = excl + a;
    if (base+2 < SCAN_NB) bexcl[base+2] = excl + a + b;
    if (tid == 255) csr_off[M_] = part[255];
}

__global__ void scan3_k(const int* __restrict__ cnt, const int* __restrict__ bexcl,
                        int* __restrict__ csr_off) {
    __shared__ int s[256];
    int i = blockIdx.x*256 + threadIdx.x;
    int v = cnt[i];
    s[threadIdx.x] = v;
    __syncthreads();
    for (int d = 1; d < 256; d <<= 1) {
        int add = (threadIdx.x >= d) ? s[threadIdx.x - d] : 0;
        __syncthreads();
        s[threadIdx.x] += add;
        __syncthreads();
    }
    csr_off[i] = bexcl[blockIdx.x] + s[threadIdx.x] - v;  // exclusive
}

// pack edges: low16 = src LOCAL index (0..3071), high16 = f16 weight
__global__ void fill_k(const int* __restrict__ ei, const int* __restrict__ csr_off,
                       int* __restrict__ cur, unsigned int* __restrict__ csr_pk,
                       const float* __restrict__ dinv) {
    int i = blockIdx.x * blockDim.x + threadIdx.x;
    if (i >= TE_) return;
    int t = i / E_, e = i % E_;
    int srcl = ei[(t*2+0)*E_ + e];
    int dst  = ei[(t*2+1)*E_ + e] + t*BN_;
    int src  = srcl + t*BN_;
    int pos = atomicAdd(&cur[dst], 1);
    int o = csr_off[dst] + pos;
    float w = dinv[src] * dinv[dst];
    csr_pk[o] = (unsigned int)srcl | ((unsigned int)f2h(w) << 16);
}

// ---------------- merged weight prep ----------------

#define WPREP_TOTAL (384+1024+2048+16384+16384+65536+65536+131072+262144)
__global__ void wprep_k(
    const float* __restrict__ gcn_b, const float* __restrict__ gam,
    const float* __restrict__ bet, const float* __restrict__ mu,
    const float* __restrict__ var,
    float* __restrict__ bn_sc, float* __restrict__ bn_sh,
    const float* __restrict__ bih0, const float* __restrict__ bhh0,
    float* __restrict__ bias0,
    const float* __restrict__ bih1, const float* __restrict__ bhh1,
    float* __restrict__ bias1,
    const float* __restrict__ gcn_w0, const float* __restrict__ gcn_w12,
    ushort* __restrict__ w0t, ushort* __restrict__ w1t, ushort* __restrict__ w2t,
    const float* __restrict__ whh0, const float* __restrict__ whh1,
    unsigned int* __restrict__ wpk0, unsigned int* __restrict__ wpk1,
    const float* __restrict__ wih0, const float* __restrict__ wih1,
    ushort* __restrict__ wih0b, ushort* __restrict__ wih1b)
{
    int i = blockIdx.x * blockDim.x + threadIdx.x;
    if (i >= WPREP_TOTAL) return;
    if (i < 384) {
        float sc = gam[i] * rsqrtf(var[i] + EPS_);
        bn_sc[i] = sc;
        bn_sh[i] = gcn_b[i]*sc + bet[i] - mu[i]*sc;
        return;
    }
    i -= 384;
    if (i < 1024) {
        bias0[i] = bih0[i] + bhh0[i];
        bias1[i] = bih1[i] + bhh1[i];
        return;
    }
    i -= 1024;
    if (i < 2048) {
        int k = i >> 7, c = i & 127;
        w0t[c*16 + k] = f2h(gcn_w0[i]);
        return;
    }
    i -= 2048;
    if (i < 16384) {
        int k = i >> 7, c = i & 127;
        w1t[c*128 + k] = f2h(gcn_w12[i]);
        return;
    }
    i -= 16384;
    if (i < 16384) {
        int k = i >> 7, c = i & 127;
        w2t[c*128 + k] = f2h(gcn_w12[16384 + i]);
        return;
    }
    i -= 16384;
    if (i < 65536) {
        int g = i & 511;
        int qd = i >> 9;
        int dir = qd >> 6, q = qd & 63;
        const float* wr = whh0 + ((long)(dir*512 + g))*128 + 2*q;
        wpk0[i] = (unsigned int)f2h(wr[0]) | ((unsigned int)f2h(wr[1]) << 16);
        return;
    }
    i -= 65536;
    if (i < 65536) {
        int g = i & 511;
        int qd = i >> 9;
        int dir = qd >> 6, q = qd & 63;
        const float* wr = whh1 + ((long)(dir*512 + g))*128 + 2*q;
        wpk1[i] = (unsigned int)f2h(wr[0]) | ((unsigned int)f2h(wr[1]) << 16);
        return;
    }
    i -= 65536;
    if (i < 131072) {
        wih0b[i] = f2h(wih0[i]);
        return;
    }
    i -= 131072;
    wih1b[i] = f2h(wih1[i]);
}

// ---------------- f16 gathers ----------------
// out[node,:] = h[node,:]*dinv[node]^2 + sum_e h[src,:]*w[e]

// F=128: one wave per node; scalar-pipe edge walk (node wave-uniform).
__global__ __launch_bounds__(256) void gather128_k(
    const ushort* __restrict__ h, ushort* __restrict__ out,
    const int* __restrict__ csr_off, const unsigned int* __restrict__ csr_pk,
    const float* __restrict__ dinv)
{
    int nb = gridDim.x;                  // M/4 blocks, 4 waves each; divisible by 8
    int chunk = nb >> 3;
    int bswz = (blockIdx.x & 7) * chunk + (blockIdx.x >> 3);
    int node = __builtin_amdgcn_readfirstlane(bswz * 4 + (threadIdx.x >> 6));
    int tbase = (node / BN_) * BN_;      // scalar
    int l2 = (threadIdx.x & 63) * 2;     // feature pair (per-lane)
    float dv = dinv[node];
    ushort swh = f2h(dv * dv);
    unsigned int swp = (unsigned int)swh * 0x10001u;
    unsigned int selfv = *(const unsigned int*)(h + (size_t)node*128 + l2);
    half2v sp = __builtin_bit_cast(half2v, swp);
    half2v acc0 = __builtin_bit_cast(half2v, selfv);
    acc0[0] = acc0[0] * sp[0];
    acc0[1] = acc0[1] * sp[1];
    half2v acc1 = {(_Float16)0.f, (_Float16)0.f};
    half2v acc2 = {(_Float16)0.f, (_Float16)0.f};
    half2v acc3 = {(_Float16)0.f, (_Float16)0.f};
    int e0 = __builtin_amdgcn_readfirstlane(csr_off[node]);
    int e1 = __builtin_amdgcn_readfirstlane(csr_off[node+1]);
    int j = e0;
    for (; j + 8 <= e1; j += 8) {
        unsigned int p0 = __builtin_amdgcn_readfirstlane(csr_pk[j+0]);
        unsigned int p1 = __builtin_amdgcn_readfirstlane(csr_pk[j+1]);
        unsigned int p2 = __builtin_amdgcn_readfirstlane(csr_pk[j+2]);
        unsigned int p3 = __builtin_amdgcn_readfirstlane(csr_pk[j+3]);
        unsigned int p4 = __builtin_amdgcn_readfirstlane(csr_pk[j+4]);
        unsigned int p5 = __builtin_amdgcn_readfirstlane(csr_pk[j+5]);
        unsigned int p6 = __builtin_amdgcn_readfirstlane(csr_pk[j+6]);
        unsigned int p7 = __builtin_amdgcn_readfirstlane(csr_pk[j+7]);
        // scalar row bases
        const ushort* r0 = h + (size_t)(tbase + (int)(p0 & 0xffffu))*128;
        const ushort* r1 = h + (size_t)(tbase + (int)(p1 & 0xffffu))*128;
        const ushort* r2 = h + (size_t)(tbase + (int)(p2 & 0xffffu))*128;
        const ushort* r3 = h + (size_t)(tbase + (int)(p3 & 0xffffu))*128;
        const ushort* r4 = h + (size_t)(tbase + (int)(p4 & 0xffffu))*128;
        const ushort* r5 = h + (size_t)(tbase + (int)(p5 & 0xffffu))*128;
        const ushort* r6 = h + (size_t)(tbase + (int)(p6 & 0xffffu))*128;
        const ushort* r7 = h + (size_t)(tbase + (int)(p7 & 0xffffu))*128;
        unsigned int v0 = *(const unsigned int*)(r0 + l2);
        unsigned int v1 = *(const unsigned int*)(r1 + l2);
        unsigned int v2 = *(const unsigned int*)(r2 + l2);
        unsigned int v3 = *(const unsigned int*)(r3 + l2);
        unsigned int v4 = *(const unsigned int*)(r4 + l2);
        unsigned int v5 = *(const unsigned int*)(r5 + l2);
        unsigned int v6 = *(const unsigned int*)(r6 + l2);
        unsigned int v7 = *(const unsigned int*)(r7 + l2);
        acc0 = pkfma(v0, (p0 >> 16) * 0x10001u, acc0);
        acc1 = pkfma(v1, (p1 >> 16) * 0x10001u, acc1);
        acc2 = pkfma(v2, (p2 >> 16) * 0x10001u, acc2);
        acc3 = pkfma(v3, (p3 >> 16) * 0x10001u, acc3);
        acc0 = pkfma(v4, (p4 >> 16) * 0x10001u, acc0);
        acc1 = pkfma(v5, (p5 >> 16) * 0x10001u, acc1);
        acc2 = pkfma(v6, (p6 >> 16) * 0x10001u, acc2);
        acc3 = pkfma(v7, (p7 >> 16) * 0x10001u, acc3);
    }
    for (; j < e1; j++) {
        unsigned int pk = __builtin_amdgcn_readfirstlane(csr_pk[j]);
        const ushort* r = h + (size_t)(tbase + (int)(pk & 0xffffu))*128;
        unsigned int v = *(const unsigned int*)(r + l2);
        acc0 = pkfma(v, (pk >> 16) * 0x10001u, acc0);
    }
    float a0 = ((float)acc0[0] + (float)acc1[0]) + ((float)acc2[0] + (float)acc3[0]);
    float a1 = ((float)acc0[1] + (float)acc1[1]) + ((float)acc2[1] + (float)acc3[1]);
    unsigned int ov = (unsigned int)f2h(a0) | ((unsigned int)f2h(a1) << 16);
    *(unsigned int*)(out + (size_t)node*128 + l2) = ov;
}

// F=16, fused f32->f16 conversion: reads x (f32), writes f16 agg.
// 32 nodes/block, 8 lanes/node, float2 per lane.
__global__ __launch_bounds__(256) void gather16f_k(
    const float* __restrict__ x, ushort* __restrict__ out,
    const int* __restrict__ csr_off, const unsigned int* __restrict__ csr_pk,
    const float* __restrict__ dinv)
{
    int nb = gridDim.x;                  // M/32
    int chunk = nb >> 3;
    int bswz = (blockIdx.x & 7) * chunk + (blockIdx.x >> 3);
    int node = bswz * 32 + (threadIdx.x >> 3);
    int f0 = (threadIdx.x & 7) * 2;
    int tbase = (node / BN_) * BN_;
    float dv = dinv[node];
    float2 sv = *(const float2*)(x + (long)node*16 + f0);
    float s = dv * dv;
    float a0 = sv.x*s, a1 = sv.y*s;
    int e0 = csr_off[node], e1 = csr_off[node+1];
    int j = e0;
    for (; j + 4 <= e1; j += 4) {
        unsigned int p0 = csr_pk[j], p1 = csr_pk[j+1], p2 = csr_pk[j+2], p3 = csr_pk[j+3];
        int s0 = tbase + (int)(p0 & 0xffffu), s1 = tbase + (int)(p1 & 0xffffu);
        int s2 = tbase + (int)(p2 & 0xffffu), s3 = tbase + (int)(p3 & 0xffffu);
        float w0 = h2f((ushort)(p0 >> 16)), w1 = h2f((ushort)(p1 >> 16));
        float w2 = h2f((ushort)(p2 >> 16)), w3 = h2f((ushort)(p3 >> 16));
        float2 v0 = *(const float2*)(x + (long)s0*16 + f0);
        float2 v1 = *(const float2*)(x + (long)s1*16 + f0);
        float2 v2 = *(const float2*)(x + (long)s2*16 + f0);
        float2 v3 = *(const float2*)(x + (long)s3*16 + f0);
        a0 += v0.x*w0 + v1.x*w1 + v2.x*w2 + v3.x*w3;
        a1 += v0.y*w0 + v1.y*w1 + v2.y*w2 + v3.y*w3;
    }
    for (; j < e1; j++) {
        unsigned int pk = csr_pk[j];
        int sc = tbase + (int)(pk & 0xffffu);
        float en = h2f((ushort)(pk >> 16));
        float2 v = *(const float2*)(x + (long)sc*16 + f0);
        a0 += v.x*en; a1 += v.y*en;
    }
    unsigned int ov = (unsigned int)f2h(a0) | ((unsigned int)f2h(a1) << 16);
    *(unsigned int*)(out + (long)node*16 + f0) = ov;
}

// ---------------- MFMA GEMM: GCN layers (BN+ReLU+resid epilogue), f16 ---------
template<int K, bool HASRES>
__global__ __launch_bounds__(256) void mm_mfma_k(
    const ushort* __restrict__ A, const ushort* __restrict__ Wt,
    ushort* __restrict__ Cout,
    const float* __restrict__ bnsc, const float* __restrict__ bnsh,
    const ushort* __restrict__ resid)
{
    int tid = threadIdx.x;
    int w = tid >> 6, lane = tid & 63;
    int l16 = lane & 15, lh = lane >> 4;
    int row0 = blockIdx.x * 64 + w * 16;

    f32x4 acc[8];
    #pragma unroll
    for (int i = 0; i < 8; i++) acc[i] = (f32x4){0.f, 0.f, 0.f, 0.f};

    #pragma unroll
    for (int k0 = 0; k0 < K; k0 += 32) {
        int ka = k0 + lh*8;
        f16x8 af;
        bool valid = (K >= 32) || (ka < K);
        if (valid) {
            af = *reinterpret_cast<const f16x8*>(&A[(long)(row0 + l16)*K + ka]);
        } else {
            #pragma unroll
            for (int e = 0; e < 8; e++) af[e] = (_Float16)0.f;
        }
        #pragma unroll
        for (int ct = 0; ct < 8; ct++) {
            f16x8 bfr;
            if (valid) {
                bfr = *reinterpret_cast<const f16x8*>(&Wt[(long)(ct*16 + l16)*K + ka]);
            } else {
                #pragma unroll
                for (int e = 0; e < 8; e++) bfr[e] = (_Float16)0.f;
            }
            acc[ct] = __builtin_amdgcn_mfma_f32_16x16x32_f16(af, bfr, acc[ct], 0, 0, 0);
        }
    }

    #pragma unroll
    for (int ct = 0; ct < 8; ct++) {
        int col = ct*16 + l16;
        float sc = bnsc[col], sh = bnsh[col];
        #pragma unroll
        for (int r = 0; r < 4; r++) {
            int row = row0 + lh*4 + r;
            float v = acc[ct][r] * sc + sh;
            v = fmaxf(v, 0.f);
            if (HASRES) v += h2f(resid[(long)row*128 + col]);
            Cout[(long)row*128 + col] = f2h(v);
        }
    }
}

// ---------------- MFMA GEMM: LSTM input projection (both dirs via blockIdx.z) ----
template<int K>
__global__ __launch_bounds__(256) void mm_pre_k(
    const ushort* __restrict__ A, const ushort* __restrict__ Wt_all,
    float* __restrict__ Cout_all, const float* __restrict__ bias_all)
{
    int dir = blockIdx.z;
    const ushort* Wt = Wt_all + (size_t)dir * 512 * K;
    float* Cout = Cout_all + (size_t)dir * T_ * B_ * 512;
    const float* bias = bias_all + dir * 512;

    int tid = threadIdx.x;
    int w = tid >> 6, lane = tid & 63;
    int l16 = lane & 15, lh = lane >> 4;
    int row0 = blockIdx.x * 64 + w * 16;
    int c0 = blockIdx.y * 128;

    f32x4 acc[8];
    #pragma unroll
    for (int i = 0; i < 8; i++) acc[i] = (f32x4){0.f, 0.f, 0.f, 0.f};

    #pragma unroll
    for (int k0 = 0; k0 < K; k0 += 32) {
        int ka = k0 + lh*8;
        f16x8 af = *reinterpret_cast<const f16x8*>(&A[(long)(row0 + l16)*K + ka]);
        #pragma unroll
        for (int ct = 0; ct < 8; ct++) {
            f16x8 bfr = *reinterpret_cast<const f16x8*>(&Wt[(long)(c0 + ct*16 + l16)*K + ka]);
            acc[ct] = __builtin_amdgcn_mfma_f32_16x16x32_f16(af, bfr, acc[ct], 0, 0, 0);
        }
    }

    #pragma unroll
    for (int ct = 0; ct < 8; ct++) {
        int col = c0 + ct*16 + l16;
        float bv = bias[col];
        #pragma unroll
        for (int r = 0; r < 4; r++) {
            int row = row0 + lh*4 + r;
            Cout[(long)row*512 + col] = acc[ct][r] + bv;
        }
    }
}

// ---------------- mean pool (f16 in, f16 out) ----------------

__global__ void meanpool_k(const ushort* __restrict__ h, ushort* __restrict__ embb) {
    int row = blockIdx.x;            // t*B + b
    int t = row / B_, b = row - t*B_;
    int hh = threadIdx.x;
    const ushort* base = h + ((long)t*BN_ + b*N_)*H_ + hh;
    float acc = 0.f;
    for (int n = 0; n < N_; n++) acc += h2f(base[(long)n*H_]);
    embb[(long)row*H_ + hh] = f2h(acc * (1.f / N_));
}

// ---------------- LSTM scan: f16 dot2, k-split x2, pre-prefetch ----------------
__global__ __launch_bounds__(1024) void lstm_scan_k(
    const float* __restrict__ pre,            // [2][T*B][512]
    const unsigned int* __restrict__ wpkbuf,  // [2][64][512] packed f16 pairs
    float* __restrict__ out,                  // [T*B][256] f32
    ushort* __restrict__ outb)                // [T*B][256] f16 (nullable)
{
    int dir = blockIdx.x >> 5;
    int b   = blockIdx.x & 31;
    int tid = threadIdx.x;
    int half = tid >> 9;
    int g    = tid & 511;

    __shared__ ushort h_s[H_];               // f16 bits
    __shared__ float part[1024];
    if (tid < H_) h_s[tid] = 0;
    float creg = 0.f;

    const unsigned int* wp = wpkbuf + (long)dir * 64 * 512 + (long)half * 32 * 512;
    unsigned int wpk[32];
    #pragma unroll
    for (int q = 0; q < 32; q++) wpk[q] = wp[q*512 + g];

    const float* pred = pre + (long)dir * T_ * B_ * 512;
    int t = dir ? (T_ - 1) : 0;
    int tstep = dir ? -1 : 1;
    float pv = (half == 0) ? pred[((long)t*B_ + b)*512 + g] : 0.f;
    __syncthreads();

    for (int st = 0; st < T_; st++) {
        int tn = t + tstep;
        tn = (tn < 0) ? 0 : ((tn >= T_) ? T_ - 1 : tn);
        float pvn = (half == 0) ? pred[((long)tn*B_ + b)*512 + g] : 0.f;

        const uint4* h4 = (const uint4*)(h_s + half*64);
        float acc = pv;
        #pragma unroll
        for (int jj = 0; jj < 8; jj++) {
            uint4 hv = h4[jj];
            acc = dot2pk(hv.x, wpk[jj*4+0], acc);
            acc = dot2pk(hv.y, wpk[jj*4+1], acc);
            acc = dot2pk(hv.z, wpk[jj*4+2], acc);
            acc = dot2pk(hv.w, wpk[jj*4+3], acc);
        }
        part[tid] = acc;
        __syncthreads();

        if (tid < H_) {
            float ig = sigm (part[tid]       + part[512 + tid]);
            float fg = sigm (part[128 + tid] + part[640 + tid]);
            float gg = ftanh(part[256 + tid] + part[768 + tid]);
            float og = sigm (part[384 + tid] + part[896 + tid]);
            float c = fg * creg + ig * gg;
            float h = og * ftanh(c);
            creg = c;
            h_s[tid] = f2h(h);
            long orow = ((long)t*B_ + b)*256 + dir*H_ + tid;
            out[orow] = h;
            if (outb) outb[orow] = f2h(h);
        }
        __syncthreads();
        pv = pvn;
        t = tn;
    }
}

// ---------------- attention ----------------

__global__ __launch_bounds__(128) void attn_a_k(
    const float* __restrict__ out2, const float* __restrict__ w1,
    const float* __restrict__ b1, const float* __restrict__ w2,
    const float* __restrict__ b2v, float* __restrict__ a)
{
    int row = blockIdx.x;
    int j = threadIdx.x;
    const float* xr = out2 + (long)row * 256;
    float acc = b1[j];
    for (int k = 0; k < 256; k++) acc += xr[k] * w1[k*128 + j];
    float u = tanhf(acc) * w2[j];
    __shared__ float red[128];
    red[j] = u;
    __syncthreads();
    for (int d = 64; d > 0; d >>= 1) {
        if (j < d) red[j] += red[j + d];
        __syncthreads();
    }
    if (j == 0) {
        int t = row / B_, b = row - t*B_;
        a[b*T_ + t] = red[0] + b2v[0];
    }
}

__global__ __launch_bounds__(256) void attn_pool_k(
    const float* __restrict__ out2, const float* __restrict__ a,
    float* __restrict__ wsv)
{
    int b = blockIdx.x;
    __shared__ float w[T_];
    if (threadIdx.x == 0) {
        float m = -1e30f;
        for (int t = 0; t < T_; t++) m = fmaxf(m, a[b*T_ + t]);
        float s = 0.f;
        for (int t = 0; t < T_; t++) { float e = __expf(a[b*T_ + t] - m); w[t] = e; s += e; }
        float inv = 1.f / s;
        for (int t = 0; t < T_; t++) w[t] *= inv;
    }
    __syncthreads();
    int h2 = threadIdx.x;
    float acc = 0.f;
    for (int t = 0; t < T_; t++) acc += w[t] * out2[((long)t*B_ + b)*256 + h2];
    wsv[b*256 + h2] = acc;
}

// ---------------- FC head + log_softmax ----------------

__global__ __launch_bounds__(512) void head_k(
    const float* __restrict__ wsv, const float* __restrict__ w1,
    const float* __restrict__ b1, const float* __restrict__ w2,
    const float* __restrict__ b2, float* __restrict__ outp)
{
    int b = blockIdx.x;
    int tid = threadIdx.x;
    __shared__ float r[128];
    __shared__ float y[C_];
    __shared__ float red[512];
    if (tid < 128) {
        float acc = b1[tid];
        for (int k = 0; k < 256; k++) acc += wsv[b*256 + k] * w1[k*128 + tid];
        r[tid] = fmaxf(acc, 0.f);
    }
    __syncthreads();
    for (int c = tid; c < C_; c += 512) {
        float acc = b2[c];
        for (int k = 0; k < 128; k++) acc += r[k] * w2[k*C_ + c];
        y[c] = acc;
    }
    __syncthreads();
    float m = -1e30f;
    for (int c = tid; c < C_; c += 512) m = fmaxf(m, y[c]);
    red[tid] = m;
    __syncthreads();
    for (int d = 256; d > 0; d >>= 1) {
        if (tid < d) red[tid] = fmaxf(red[tid], red[tid + d]);
        __syncthreads();
    }
    m = red[0];
    __syncthreads();
    float s = 0.f;
    for (int c = tid; c < C_; c += 512) s += __expf(y[c] - m);
    red[tid] = s;
    __syncthreads();
    for (int d = 256; d > 0; d >>= 1) {
        if (tid < d) red[tid] += red[tid + d];
        __syncthreads();
    }
    float lse = m + logf(red[0]);
    for (int c = tid; c < C_; c += 512) outp[(long)b*C_ + c] = y[c] - lse;
}

// ---------------- launch ----------------

extern "C" void kernel_launch(void* const* d_in, const int* in_sizes, int n_in,
                              void* d_out, int out_size, void* d_ws, size_t ws_size,
                              hipStream_t stream) {
    const float* x        = (const float*)d_in[0];
    const int*   ei       = (const int*)d_in[1];
    const float* gcn_w0   = (const float*)d_in[2];
    const float* gcn_w12  = (const float*)d_in[3];
    const float* gcn_b    = (const float*)d_in[4];
    const float* bn_gamma = (const float*)d_in[5];
    const float* bn_beta  = (const float*)d_in[6];
    const float* bn_mean  = (const float*)d_in[7];
    const float* bn_var   = (const float*)d_in[8];
    const float* wih0     = (const float*)d_in[9];
    const float* whh0     = (const float*)d_in[10];
    const float* bih0     = (const float*)d_in[11];
    const float* bhh0     = (const float*)d_in[12];
    const float* wih1     = (const float*)d_in[13];
    const float* whh1     = (const float*)d_in[14];
    const float* bih1     = (const float*)d_in[15];
    const float* bhh1     = (const float*)d_in[16];
    const float* attn_w1  = (const float*)d_in[17];
    const float* attn_b1  = (const float*)d_in[18];
    const float* attn_w2  = (const float*)d_in[19];
    const float* attn_b2  = (const float*)d_in[20];
    const float* fc1_w    = (const float*)d_in[21];
    const float* fc1_b    = (const float*)d_in[22];
    const float* fc2_w    = (const float*)d_in[23];
    const float* fc2_b    = (const float*)d_in[24];

    char* p = (char*)d_ws;
    auto alloc = [&](size_t bytes) {
        void* r = (void*)p;
        p += (bytes + 255) & ~(size_t)255;
        return r;
    };
    ushort* aggbuf = (ushort*)alloc((size_t)M_*H_*2);
    ushort* hbA    = (ushort*)alloc((size_t)M_*H_*2);
    ushort* hbB    = (ushort*)alloc((size_t)M_*H_*2);
    int*   cnt     = (int*)  alloc((size_t)M_*4);   // cnt + csr_cur contiguous
    int*   csr_cur = (int*)  alloc((size_t)M_*4);   // (single memset covers both)
    float* dinv    = (float*)alloc((size_t)M_*4);
    int*   bsum    = (int*)  alloc((size_t)SCAN_NB*4);
    int*   bexcl   = (int*)  alloc((size_t)SCAN_NB*4);
    int*   csr_off = (int*)  alloc((size_t)(M_+1)*4);
    unsigned int* csr_pk = (unsigned int*)alloc((size_t)TE_*4);
    float* bn_sc   = (float*)alloc(384*4);
    float* bn_sh   = (float*)alloc(384*4);
    float* bias0   = (float*)alloc(1024*4);
    float* bias1   = (float*)alloc(1024*4);
    ushort* w0t    = (ushort*)alloc((size_t)128*16*2);
    ushort* w1t    = (ushort*)alloc((size_t)128*128*2);
    ushort* w2t    = (ushort*)alloc((size_t)128*128*2);
    unsigned int* wpk0 = (unsigned int*)alloc((size_t)2*64*512*4);
    unsigned int* wpk1 = (unsigned int*)alloc((size_t)2*64*512*4);
    ushort* wih0b  = (ushort*)alloc((size_t)2*512*128*2);
    ushort* wih1b  = (ushort*)alloc((size_t)2*512*256*2);
    ushort* embb   = (ushort*)alloc((size_t)T_*B_*H_*2);
    float* pre     = (float*)alloc((size_t)2*T_*B_*512*4);
    float* out1    = (float*)alloc((size_t)T_*B_*256*4);
    ushort* out1b  = (ushort*)alloc((size_t)T_*B_*256*2);
    float* out2v   = (float*)alloc((size_t)T_*B_*256*4);
    float* attn_av = (float*)alloc((size_t)B_*T_*4);
    float* wsv     = (float*)alloc((size_t)B_*256*4);

    // --- graph preprocessing (CSR by dst, packed u16 src + f16 weight) ---
    hipMemsetAsync(cnt, 0, (size_t)2*M_*4, stream);   // cnt + csr_cur
    count_edges_k<<<(TE_+255)/256, 256, 0, stream>>>(ei, cnt);
    scan1_k<<<SCAN_NB, 256, 0, stream>>>(cnt, bsum, dinv);
    scan2_k<<<1, 256, 0, stream>>>(bsum, bexcl, csr_off);
    scan3_k<<<SCAN_NB, 256, 0, stream>>>(cnt, bexcl, csr_off);
    fill_k<<<(TE_+255)/256, 256, 0, stream>>>(ei, csr_off, csr_cur, csr_pk, dinv);

    // --- weight prep (merged) ---
    wprep_k<<<(WPREP_TOTAL+255)/256, 256, 0, stream>>>(
        gcn_b, bn_gamma, bn_beta, bn_mean, bn_var, bn_sc, bn_sh,
        bih0, bhh0, bias0, bih1, bhh1, bias1,
        gcn_w0, gcn_w12, w0t, w1t, w2t,
        whh0, whh1, wpk0, wpk1,
        wih0, wih1, wih0b, wih1b);

    // --- GCN layer 0 (conversion fused into gather) ---
    gather16f_k<<<M_/32, 256, 0, stream>>>(x, aggbuf, csr_off, csr_pk, dinv);
    mm_mfma_k<16, false><<<M_/64, 256, 0, stream>>>(aggbuf, w0t, hbA,
                                                    bn_sc + 0, bn_sh + 0, nullptr);
    // --- GCN layer 1 ---
    gather128_k<<<M_/4, 256, 0, stream>>>(hbA, aggbuf, csr_off, csr_pk, dinv);
    mm_mfma_k<128, true><<<M_/64, 256, 0, stream>>>(aggbuf, w1t, hbB,
                                                    bn_sc + 128, bn_sh + 128, hbA);
    // --- GCN layer 2 ---
    gather128_k<<<M_/4, 256, 0, stream>>>(hbB, aggbuf, csr_off, csr_pk, dinv);
    mm_mfma_k<128, true><<<M_/64, 256, 0, stream>>>(aggbuf, w2t, hbA,
                                                    bn_sc + 256, bn_sh + 256, hbB);

    // --- mean pool -> embb [T*B,128] f16 ---
    meanpool_k<<<T_*B_, 128, 0, stream>>>(hbA, embb);

    // --- BiLSTM layer 0 ---
    mm_pre_k<128><<<dim3((T_*B_)/64, 4, 2), 256, 0, stream>>>(embb, wih0b, pre, bias0);
    lstm_scan_k<<<64, 1024, 0, stream>>>(pre, wpk0, out1, out1b);

    // --- BiLSTM layer 1 ---
    mm_pre_k<256><<<dim3((T_*B_)/64, 4, 2), 256, 0, stream>>>(out1b, wih1b, pre, bias1);
    lstm_scan_k<<<64, 1024, 0, stream>>>(pre, wpk1, out2v, nullptr);

    // --- attention ---
    attn_a_k<<<T_*B_, 128, 0, stream>>>(out2v, attn_w1, attn_b1, attn_w2, attn_b2, attn_av);
    attn_pool_k<<<B_, 256, 0, stream>>>(out2v, attn_av, wsv);

    // --- head ---
    head_k<<<B_, 512, 0, stream>>>(wsv, fc1_w, fc1_b, fc2_w, fc2_b, (float*)d_out);
}

// Round 10
// 415.056 us; speedup vs baseline: 1.3719x; 1.0882x over previous
//
#include <hip/hip_runtime.h>

#define T_ 48
#define B_ 32
#define N_ 96
#define E_ 24576
#define BN_ (B_*N_)      // 3072
#define M_ (T_*BN_)      // 147456
#define FIN_ 16
#define H_ 128
#define C_ 500
#define TE_ (T_*E_)      // 1179648
#define EPS_ 1e-5f
#define SCAN_NB (M_/256) // 576

typedef _Float16 f16x8 __attribute__((ext_vector_type(8)));
typedef float    f32x4 __attribute__((ext_vector_type(4)));
typedef _Float16 half2v __attribute__((ext_vector_type(2)));

__device__ __forceinline__ ushort f2h(float f) {
    _Float16 h = (_Float16)f;
    union { _Float16 h; ushort u; } v;
    v.h = h;
    return v.u;
}
__device__ __forceinline__ float h2f(ushort u) {
    union { ushort u; _Float16 h; } v;
    v.u = u;
    return (float)v.h;
}
__device__ __forceinline__ half2v pkfma(unsigned int v, unsigned int w, half2v acc) {
#if __has_builtin(__builtin_elementwise_fma)
    return __builtin_elementwise_fma(__builtin_bit_cast(half2v, v),
                                     __builtin_bit_cast(half2v, w), acc);
#else
    half2v hv = __builtin_bit_cast(half2v, v);
    half2v wv = __builtin_bit_cast(half2v, w);
    acc[0] += hv[0]*wv[0];
    acc[1] += hv[1]*wv[1];
    return acc;
#endif
}
__device__ __forceinline__ float dot2pk(unsigned int hbits, unsigned int wbits, float acc) {
#if __has_builtin(__builtin_amdgcn_fdot2)
    return __builtin_amdgcn_fdot2(__builtin_bit_cast(half2v, hbits),
                                  __builtin_bit_cast(half2v, wbits), acc, false);
#else
    half2v hv = __builtin_bit_cast(half2v, hbits);
    half2v wv = __builtin_bit_cast(half2v, wbits);
    acc = fmaf((float)hv[0], (float)wv[0], acc);
    acc = fmaf((float)hv[1], (float)wv[1], acc);
    return acc;
#endif
}
__device__ __forceinline__ float sigm(float x) {
    return 1.f / (1.f + __expf(-x));
}
__device__ __forceinline__ float ftanh(float x) {
    x = fminf(15.f, fmaxf(-15.f, x));
    float e = __expf(2.f * x);
    return (e - 1.f) / (e + 1.f);
}

// ---------------- graph preprocessing ----------------

__global__ void count_edges_k(const int* __restrict__ ei, int* __restrict__ cnt) {
    int i = blockIdx.x * blockDim.x + threadIdx.x;
    if (i >= TE_) return;
    int t = i / E_, e = i % E_;
    int dst = ei[(t*2+1)*E_ + e] + t*BN_;
    atomicAdd(&cnt[dst], 1);
}

__global__ void scan1_k(const int* __restrict__ cnt, int* __restrict__ bsum,
                        float* __restrict__ dinv) {
    __shared__ int s[256];
    int i = blockIdx.x*256 + threadIdx.x;
    int v = cnt[i];
    dinv[i] = rsqrtf((float)v + 1.0f);
    s[threadIdx.x] = v;
    __syncthreads();
    for (int d = 128; d > 0; d >>= 1) {
        if (threadIdx.x < d) s[threadIdx.x] += s[threadIdx.x + d];
        __syncthreads();
    }
    if (threadIdx.x == 0) bsum[blockIdx.x] = s[0];
}

__global__ __launch_bounds__(256) void scan2_k(const int* __restrict__ bsum,
                                               int* __restrict__ bexcl,
                                               int* __restrict__ csr_off) {
    __shared__ int part[256];
    int tid = threadIdx.x;
    int base = tid*3;   // 256*3 = 768 >= 576
    int a = (base   < SCAN_NB) ? bsum[base]   : 0;
    int b = (base+1 < SCAN_NB) ? bsum[base+1] : 0;
    int c = (base+2 < SCAN_NB) ? bsum[base+2] : 0;
    int tot = a + b + c;
    part[tid] = tot;
    __syncthreads();
    for (int d = 1; d < 256; d <<= 1) {
        int add = (tid >= d) ? part[tid - d] : 0;
        __syncthreads();
        part[tid] += add;
        __syncthreads();
    }
    int excl = part[tid] - tot;
    if (base   < SCAN_NB) bexcl[base]   = excl;
    if (base+1 < SCAN_NB) bexcl[base+1] = excl + a;
    if (base+2 < SCAN_NB) bexcl[base+2] = excl + a + b;
    if (tid == 255) csr_off[M_] = part[255];
}

__global__ void scan3_k(const int* __restrict__ cnt, const int* __restrict__ bexcl,
                        int* __restrict__ csr_off) {
    __shared__ int s[256];
    int i = blockIdx.x*256 + threadIdx.x;
    int v = cnt[i];
    s[threadIdx.x] = v;
    __syncthreads();
    for (int d = 1; d < 256; d <<= 1) {
        int add = (threadIdx.x >= d) ? s[threadIdx.x - d] : 0;
        __syncthreads();
        s[threadIdx.x] += add;
        __syncthreads();
    }
    csr_off[i] = bexcl[blockIdx.x] + s[threadIdx.x] - v;  // exclusive
}

// pack edges: low16 = src LOCAL index (0..3071), high16 = f16 weight
__global__ void fill_k(const int* __restrict__ ei, const int* __restrict__ csr_off,
                       int* __restrict__ cur, unsigned int* __restrict__ csr_pk,
                       const float* __restrict__ dinv) {
    int i = blockIdx.x * blockDim.x + threadIdx.x;
    if (i >= TE_) return;
    int t = i / E_, e = i % E_;
    int srcl = ei[(t*2+0)*E_ + e];
    int dst  = ei[(t*2+1)*E_ + e] + t*BN_;
    int src  = srcl + t*BN_;
    int pos = atomicAdd(&cur[dst], 1);
    int o = csr_off[dst] + pos;
    float w = dinv[src] * dinv[dst];
    csr_pk[o] = (unsigned int)srcl | ((unsigned int)f2h(w) << 16);
}

// ---------------- merged weight prep (fragment-swizzled MFMA weights) --------
// Fragment layout for mfma_f32_16x16x32_f16 B operand:
//   frag[tile][kk][lane][8]  where col = tile*16 + (lane&15), k = kk*32 + (lane>>4)*8 + e
// segments:
//  [0,384)      bn scale/shift
//  [+1024)      lstm bias0/bias1
//  [+4096)      w0t  frag (8 ct x 1 kk x 64 x 8; zeros for k>=16)
//  [+16384)     w1t  frag (8 ct x 4 kk x 64 x 8)
//  [+16384)     w2t  frag
//  [+65536)     wpk0 (whh0 packed f16 pairs [2][64][512])
//  [+65536)     wpk1
//  [+131072)    wih0b frag (2 dir x 32 nt x 4 kk x 64 x 8)
//  [+262144)    wih1b frag (2 dir x 32 nt x 8 kk x 64 x 8)
#define WPREP_TOTAL (384+1024+4096+16384+16384+65536+65536+131072+262144)
__global__ void wprep_k(
    const float* __restrict__ gcn_b, const float* __restrict__ gam,
    const float* __restrict__ bet, const float* __restrict__ mu,
    const float* __restrict__ var,
    float* __restrict__ bn_sc, float* __restrict__ bn_sh,
    const float* __restrict__ bih0, const float* __restrict__ bhh0,
    float* __restrict__ bias0,
    const float* __restrict__ bih1, const float* __restrict__ bhh1,
    float* __restrict__ bias1,
    const float* __restrict__ gcn_w0, const float* __restrict__ gcn_w12,
    ushort* __restrict__ w0t, ushort* __restrict__ w1t, ushort* __restrict__ w2t,
    const float* __restrict__ whh0, const float* __restrict__ whh1,
    unsigned int* __restrict__ wpk0, unsigned int* __restrict__ wpk1,
    const float* __restrict__ wih0, const float* __restrict__ wih1,
    ushort* __restrict__ wih0b, ushort* __restrict__ wih1b)
{
    int i = blockIdx.x * blockDim.x + threadIdx.x;
    if (i >= WPREP_TOTAL) return;
    if (i < 384) {
        float sc = gam[i] * rsqrtf(var[i] + EPS_);
        bn_sc[i] = sc;
        bn_sh[i] = gcn_b[i]*sc + bet[i] - mu[i]*sc;
        return;
    }
    i -= 384;
    if (i < 1024) {
        bias0[i] = bih0[i] + bhh0[i];
        bias1[i] = bih1[i] + bhh1[i];
        return;
    }
    i -= 1024;
    if (i < 4096) {       // w0t frag, K=16
        int e = i & 7, lane = (i >> 3) & 63, ct = i >> 9;
        int k = (lane >> 4)*8 + e;
        int c = ct*16 + (lane & 15);
        w0t[i] = (k < 16) ? f2h(gcn_w0[k*128 + c]) : (ushort)0;
        return;
    }
    i -= 4096;
    if (i < 16384) {      // w1t frag, K=128
        int e = i & 7, lane = (i >> 3) & 63, kk = (i >> 9) & 3, ct = i >> 11;
        int k = kk*32 + (lane >> 4)*8 + e;
        int c = ct*16 + (lane & 15);
        w1t[i] = f2h(gcn_w12[k*128 + c]);
        return;
    }
    i -= 16384;
    if (i < 16384) {      // w2t frag
        int e = i & 7, lane = (i >> 3) & 63, kk = (i >> 9) & 3, ct = i >> 11;
        int k = kk*32 + (lane >> 4)*8 + e;
        int c = ct*16 + (lane & 15);
        w2t[i] = f2h(gcn_w12[16384 + k*128 + c]);
        return;
    }
    i -= 16384;
    if (i < 65536) {
        int g = i & 511;
        int qd = i >> 9;
        int dir = qd >> 6, q = qd & 63;
        const float* wr = whh0 + ((long)(dir*512 + g))*128 + 2*q;
        wpk0[i] = (unsigned int)f2h(wr[0]) | ((unsigned int)f2h(wr[1]) << 16);
        return;
    }
    i -= 65536;
    if (i < 65536) {
        int g = i & 511;
        int qd = i >> 9;
        int dir = qd >> 6, q = qd & 63;
        const float* wr = whh1 + ((long)(dir*512 + g))*128 + 2*q;
        wpk1[i] = (unsigned int)f2h(wr[0]) | ((unsigned int)f2h(wr[1]) << 16);
        return;
    }
    i -= 65536;
    if (i < 131072) {     // wih0b frag, N=512, K=128
        int dir = i >> 16, r = i & 0xFFFF;
        int nt = r >> 11, kk = (r >> 9) & 3, lane = (r >> 3) & 63, e = r & 7;
        int n = nt*16 + (lane & 15);
        int k = kk*32 + (lane >> 4)*8 + e;
        wih0b[i] = f2h(wih0[((long)dir*512 + n)*128 + k]);
        return;
    }
    i -= 131072;
    {                     // wih1b frag, N=512, K=256
        int dir = i >> 17, r = i & 0x1FFFF;
        int nt = r >> 12, kk = (r >> 9) & 7, lane = (r >> 3) & 63, e = r & 7;
        int n = nt*16 + (lane & 15);
        int k = kk*32 + (lane >> 4)*8 + e;
        wih1b[i] = f2h(wih1[((long)dir*512 + n)*256 + k]);
    }
}

// ---------------- f16 gathers ----------------
// out[node,:] = h[node,:]*dinv[node]^2 + sum_e h[src,:]*w[e]

// F=128: one wave per node; scalar-pipe edge walk (node wave-uniform).
__global__ __launch_bounds__(256) void gather128_k(
    const ushort* __restrict__ h, ushort* __restrict__ out,
    const int* __restrict__ csr_off, const unsigned int* __restrict__ csr_pk,
    const float* __restrict__ dinv)
{
    int nb = gridDim.x;                  // M/4 blocks, 4 waves each; divisible by 8
    int chunk = nb >> 3;
    int bswz = (blockIdx.x & 7) * chunk + (blockIdx.x >> 3);
    int node = __builtin_amdgcn_readfirstlane(bswz * 4 + (threadIdx.x >> 6));
    int tbase = (node / BN_) * BN_;      // scalar
    int l2 = (threadIdx.x & 63) * 2;     // feature pair (per-lane)
    float dv = dinv[node];
    ushort swh = f2h(dv * dv);
    unsigned int swp = (unsigned int)swh * 0x10001u;
    unsigned int selfv = *(const unsigned int*)(h + (size_t)node*128 + l2);
    half2v sp = __builtin_bit_cast(half2v, swp);
    half2v acc0 = __builtin_bit_cast(half2v, selfv);
    acc0[0] = acc0[0] * sp[0];
    acc0[1] = acc0[1] * sp[1];
    half2v acc1 = {(_Float16)0.f, (_Float16)0.f};
    half2v acc2 = {(_Float16)0.f, (_Float16)0.f};
    half2v acc3 = {(_Float16)0.f, (_Float16)0.f};
    int e0 = __builtin_amdgcn_readfirstlane(csr_off[node]);
    int e1 = __builtin_amdgcn_readfirstlane(csr_off[node+1]);
    int j = e0;
    for (; j + 8 <= e1; j += 8) {
        unsigned int p0 = __builtin_amdgcn_readfirstlane(csr_pk[j+0]);
        unsigned int p1 = __builtin_amdgcn_readfirstlane(csr_pk[j+1]);
        unsigned int p2 = __builtin_amdgcn_readfirstlane(csr_pk[j+2]);
        unsigned int p3 = __builtin_amdgcn_readfirstlane(csr_pk[j+3]);
        unsigned int p4 = __builtin_amdgcn_readfirstlane(csr_pk[j+4]);
        unsigned int p5 = __builtin_amdgcn_readfirstlane(csr_pk[j+5]);
        unsigned int p6 = __builtin_amdgcn_readfirstlane(csr_pk[j+6]);
        unsigned int p7 = __builtin_amdgcn_readfirstlane(csr_pk[j+7]);
        const ushort* r0 = h + (size_t)(tbase + (int)(p0 & 0xffffu))*128;
        const ushort* r1 = h + (size_t)(tbase + (int)(p1 & 0xffffu))*128;
        const ushort* r2 = h + (size_t)(tbase + (int)(p2 & 0xffffu))*128;
        const ushort* r3 = h + (size_t)(tbase + (int)(p3 & 0xffffu))*128;
        const ushort* r4 = h + (size_t)(tbase + (int)(p4 & 0xffffu))*128;
        const ushort* r5 = h + (size_t)(tbase + (int)(p5 & 0xffffu))*128;
        const ushort* r6 = h + (size_t)(tbase + (int)(p6 & 0xffffu))*128;
        const ushort* r7 = h + (size_t)(tbase + (int)(p7 & 0xffffu))*128;
        unsigned int v0 = *(const unsigned int*)(r0 + l2);
        unsigned int v1 = *(const unsigned int*)(r1 + l2);
        unsigned int v2 = *(const unsigned int*)(r2 + l2);
        unsigned int v3 = *(const unsigned int*)(r3 + l2);
        unsigned int v4 = *(const unsigned int*)(r4 + l2);
        unsigned int v5 = *(const unsigned int*)(r5 + l2);
        unsigned int v6 = *(const unsigned int*)(r6 + l2);
        unsigned int v7 = *(const unsigned int*)(r7 + l2);
        acc0 = pkfma(v0, (p0 >> 16) * 0x10001u, acc0);
        acc1 = pkfma(v1, (p1 >> 16) * 0x10001u, acc1);
        acc2 = pkfma(v2, (p2 >> 16) * 0x10001u, acc2);
        acc3 = pkfma(v3, (p3 >> 16) * 0x10001u, acc3);
        acc0 = pkfma(v4, (p4 >> 16) * 0x10001u, acc0);
        acc1 = pkfma(v5, (p5 >> 16) * 0x10001u, acc1);
        acc2 = pkfma(v6, (p6 >> 16) * 0x10001u, acc2);
        acc3 = pkfma(v7, (p7 >> 16) * 0x10001u, acc3);
    }
    for (; j < e1; j++) {
        unsigned int pk = __builtin_amdgcn_readfirstlane(csr_pk[j]);
        const ushort* r = h + (size_t)(tbase + (int)(pk & 0xffffu))*128;
        unsigned int v = *(const unsigned int*)(r + l2);
        acc0 = pkfma(v, (pk >> 16) * 0x10001u, acc0);
    }
    float a0 = ((float)acc0[0] + (float)acc1[0]) + ((float)acc2[0] + (float)acc3[0]);
    float a1 = ((float)acc0[1] + (float)acc1[1]) + ((float)acc2[1] + (float)acc3[1]);
    unsigned int ov = (unsigned int)f2h(a0) | ((unsigned int)f2h(a1) << 16);
    *(unsigned int*)(out + (size_t)node*128 + l2) = ov;
}

// F=16, fused f32->f16 conversion: reads x (f32), writes f16 agg.
__global__ __launch_bounds__(256) void gather16f_k(
    const float* __restrict__ x, ushort* __restrict__ out,
    const int* __restrict__ csr_off, const unsigned int* __restrict__ csr_pk,
    const float* __restrict__ dinv)
{
    int nb = gridDim.x;                  // M/32
    int chunk = nb >> 3;
    int bswz = (blockIdx.x & 7) * chunk + (blockIdx.x >> 3);
    int node = bswz * 32 + (threadIdx.x >> 3);
    int f0 = (threadIdx.x & 7) * 2;
    int tbase = (node / BN_) * BN_;
    float dv = dinv[node];
    float2 sv = *(const float2*)(x + (long)node*16 + f0);
    float s = dv * dv;
    float a0 = sv.x*s, a1 = sv.y*s;
    int e0 = csr_off[node], e1 = csr_off[node+1];
    int j = e0;
    for (; j + 4 <= e1; j += 4) {
        unsigned int p0 = csr_pk[j], p1 = csr_pk[j+1], p2 = csr_pk[j+2], p3 = csr_pk[j+3];
        int s0 = tbase + (int)(p0 & 0xffffu), s1 = tbase + (int)(p1 & 0xffffu);
        int s2 = tbase + (int)(p2 & 0xffffu), s3 = tbase + (int)(p3 & 0xffffu);
        float w0 = h2f((ushort)(p0 >> 16)), w1 = h2f((ushort)(p1 >> 16));
        float w2 = h2f((ushort)(p2 >> 16)), w3 = h2f((ushort)(p3 >> 16));
        float2 v0 = *(const float2*)(x + (long)s0*16 + f0);
        float2 v1 = *(const float2*)(x + (long)s1*16 + f0);
        float2 v2 = *(const float2*)(x + (long)s2*16 + f0);
        float2 v3 = *(const float2*)(x + (long)s3*16 + f0);
        a0 += v0.x*w0 + v1.x*w1 + v2.x*w2 + v3.x*w3;
        a1 += v0.y*w0 + v1.y*w1 + v2.y*w2 + v3.y*w3;
    }
    for (; j < e1; j++) {
        unsigned int pk = csr_pk[j];
        int sc = tbase + (int)(pk & 0xffffu);
        float en = h2f((ushort)(pk >> 16));
        float2 v = *(const float2*)(x + (long)sc*16 + f0);
        a0 += v.x*en; a1 += v.y*en;
    }
    unsigned int ov = (unsigned int)f2h(a0) | ((unsigned int)f2h(a1) << 16);
    *(unsigned int*)(out + (long)node*16 + f0) = ov;
}

// ---------------- MFMA GEMM: GCN layers, frag-swizzled Wt, LDS epilogue -------
// A [Mr,K] f16 row-major; Wt in frag layout; C [Mr,128] f16.
template<int K, bool HASRES>
__global__ __launch_bounds__(256) void mm_mfma_k(
    const ushort* __restrict__ A, const ushort* __restrict__ Wt,
    ushort* __restrict__ Cout,
    const float* __restrict__ bnsc, const float* __restrict__ bnsh,
    const ushort* __restrict__ resid)
{
    constexpr int KST = (K >= 32) ? (K/32) : 1;
    int tid = threadIdx.x;
    int w = tid >> 6, lane = tid & 63;
    int l16 = lane & 15, lh = lane >> 4;
    int row0 = blockIdx.x * 64 + w * 16;
    __shared__ ushort cl[64][136];   // padded to kill bank conflicts

    f32x4 acc[8];
    #pragma unroll
    for (int i = 0; i < 8; i++) acc[i] = (f32x4){0.f, 0.f, 0.f, 0.f};

    #pragma unroll
    for (int kk = 0; kk < KST; kk++) {
        int ka = kk*32 + lh*8;
        f16x8 af;
        bool valid = (K >= 32) || (ka < K);
        if (valid) {
            af = *reinterpret_cast<const f16x8*>(&A[(long)(row0 + l16)*K + ka]);
        } else {
            #pragma unroll
            for (int e = 0; e < 8; e++) af[e] = (_Float16)0.f;
        }
        #pragma unroll
        for (int ct = 0; ct < 8; ct++) {
            f16x8 bfr = *reinterpret_cast<const f16x8*>(
                &Wt[(((long)ct*KST + kk)*64 + lane)*8]);
            acc[ct] = __builtin_amdgcn_mfma_f32_16x16x32_f16(af, bfr, acc[ct], 0, 0, 0);
        }
    }

    // BN+ReLU into LDS (f16), then coalesced vectorized write (+resid)
    #pragma unroll
    for (int ct = 0; ct < 8; ct++) {
        int col = ct*16 + l16;
        float sc = bnsc[col], sh = bnsh[col];
        #pragma unroll
        for (int r = 0; r < 4; r++) {
            int rl = w*16 + lh*4 + r;
            float v = acc[ct][r] * sc + sh;
            cl[rl][col] = f2h(fmaxf(v, 0.f));
        }
    }
    __syncthreads();
    long rowblock = (long)blockIdx.x * 64;
    #pragma unroll
    for (int it = 0; it < 4; it++) {
        int s = it*256 + tid;           // 1024 segments: 64 rows x 16 (8-col segs)
        int rl = s >> 4, c8 = (s & 15) * 8;
        uint4 v = *(const uint4*)&cl[rl][c8];
        if (HASRES) {
            uint4 rv = *(const uint4*)&resid[(rowblock + rl)*128 + c8];
            half2v* vv = (half2v*)&v;
            const half2v* rr = (const half2v*)&rv;
            vv[0] += rr[0]; vv[1] += rr[1]; vv[2] += rr[2]; vv[3] += rr[3];
        }
        *(uint4*)&Cout[(rowblock + rl)*128 + c8] = v;
    }
}

// ---------------- MFMA GEMM: LSTM input projection (frag-swizzled Wt) --------
template<int K>
__global__ __launch_bounds__(256) void mm_pre_k(
    const ushort* __restrict__ A, const ushort* __restrict__ Wt_all,
    float* __restrict__ Cout_all, const float* __restrict__ bias_all)
{
    constexpr int KST = K/32;
    int dir = blockIdx.z;
    const ushort* Wt = Wt_all + (size_t)dir * 512 * K;
    float* Cout = Cout_all + (size_t)dir * T_ * B_ * 512;
    const float* bias = bias_all + dir * 512;

    int tid = threadIdx.x;
    int w = tid >> 6, lane = tid & 63;
    int l16 = lane & 15, lh = lane >> 4;
    int row0 = blockIdx.x * 64 + w * 16;
    int nt0 = blockIdx.y * 8;    // col-tile base (8 tiles of 16 -> 128 cols)

    f32x4 acc[8];
    #pragma unroll
    for (int i = 0; i < 8; i++) acc[i] = (f32x4){0.f, 0.f, 0.f, 0.f};

    #pragma unroll
    for (int kk = 0; kk < KST; kk++) {
        int ka = kk*32 + lh*8;
        f16x8 af = *reinterpret_cast<const f16x8*>(&A[(long)(row0 + l16)*K + ka]);
        #pragma unroll
        for (int ct = 0; ct < 8; ct++) {
            f16x8 bfr = *reinterpret_cast<const f16x8*>(
                &Wt[(((long)(nt0 + ct)*KST + kk)*64 + lane)*8]);
            acc[ct] = __builtin_amdgcn_mfma_f32_16x16x32_f16(af, bfr, acc[ct], 0, 0, 0);
        }
    }

    #pragma unroll
    for (int ct = 0; ct < 8; ct++) {
        int col = (nt0 + ct)*16 + l16;
        float bv = bias[col];
        #pragma unroll
        for (int r = 0; r < 4; r++) {
            int row = row0 + lh*4 + r;
            Cout[(long)row*512 + col] = acc[ct][r] + bv;
        }
    }
}

// ---------------- mean pool (f16 in, f16 out) ----------------

__global__ void meanpool_k(const ushort* __restrict__ h, ushort* __restrict__ embb) {
    int row = blockIdx.x;            // t*B + b
    int t = row / B_, b = row - t*B_;
    int hh = threadIdx.x;
    const ushort* base = h + ((long)t*BN_ + b*N_)*H_ + hh;
    float acc = 0.f;
    for (int n = 0; n < N_; n++) acc += h2f(base[(long)n*H_]);
    embb[(long)row*H_ + hh] = f2h(acc * (1.f / N_));
}

// ---------------- LSTM scan: f16 dot2, k-split x2, pre-prefetch ----------------
__global__ __launch_bounds__(1024) void lstm_scan_k(
    const float* __restrict__ pre,            // [2][T*B][512]
    const unsigned int* __restrict__ wpkbuf,  // [2][64][512] packed f16 pairs
    float* __restrict__ out,                  // [T*B][256] f32
    ushort* __restrict__ outb)                // [T*B][256] f16 (nullable)
{
    int dir = blockIdx.x >> 5;
    int b   = blockIdx.x & 31;
    int tid = threadIdx.x;
    int half = tid >> 9;
    int g    = tid & 511;

    __shared__ ushort h_s[H_];               // f16 bits
    __shared__ float part[1024];
    if (tid < H_) h_s[tid] = 0;
    float creg = 0.f;

    const unsigned int* wp = wpkbuf + (long)dir * 64 * 512 + (long)half * 32 * 512;
    unsigned int wpk[32];
    #pragma unroll
    for (int q = 0; q < 32; q++) wpk[q] = wp[q*512 + g];

    const float* pred = pre + (long)dir * T_ * B_ * 512;
    int t = dir ? (T_ - 1) : 0;
    int tstep = dir ? -1 : 1;
    float pv = (half == 0) ? pred[((long)t*B_ + b)*512 + g] : 0.f;
    __syncthreads();

    for (int st = 0; st < T_; st++) {
        int tn = t + tstep;
        tn = (tn < 0) ? 0 : ((tn >= T_) ? T_ - 1 : tn);
        float pvn = (half == 0) ? pred[((long)tn*B_ + b)*512 + g] : 0.f;

        const uint4* h4 = (const uint4*)(h_s + half*64);
        float acc = pv;
        #pragma unroll
        for (int jj = 0; jj < 8; jj++) {
            uint4 hv = h4[jj];
            acc = dot2pk(hv.x, wpk[jj*4+0], acc);
            acc = dot2pk(hv.y, wpk[jj*4+1], acc);
            acc = dot2pk(hv.z, wpk[jj*4+2], acc);
            acc = dot2pk(hv.w, wpk[jj*4+3], acc);
        }
        part[tid] = acc;
        __syncthreads();

        if (tid < H_) {
            float ig = sigm (part[tid]       + part[512 + tid]);
            float fg = sigm (part[128 + tid] + part[640 + tid]);
            float gg = ftanh(part[256 + tid] + part[768 + tid]);
            float og = sigm (part[384 + tid] + part[896 + tid]);
            float c = fg * creg + ig * gg;
            float h = og * ftanh(c);
            creg = c;
            h_s[tid] = f2h(h);
            long orow = ((long)t*B_ + b)*256 + dir*H_ + tid;
            out[orow] = h;
            if (outb) outb[orow] = f2h(h);
        }
        __syncthreads();
        pv = pvn;
        t = tn;
    }
}

// ---------------- attention ----------------

__global__ __launch_bounds__(128) void attn_a_k(
    const float* __restrict__ out2, const float* __restrict__ w1,
    const float* __restrict__ b1, const float* __restrict__ w2,
    const float* __restrict__ b2v, float* __restrict__ a)
{
    int row = blockIdx.x;
    int j = threadIdx.x;
    const float* xr = out2 + (long)row * 256;
    float acc = b1[j];
    for (int k = 0; k < 256; k++) acc += xr[k] * w1[k*128 + j];
    float u = tanhf(acc) * w2[j];
    __shared__ float red[128];
    red[j] = u;
    __syncthreads();
    for (int d = 64; d > 0; d >>= 1) {
        if (j < d) red[j] += red[j + d];
        __syncthreads();
    }
    if (j == 0) {
        int t = row / B_, b = row - t*B_;
        a[b*T_ + t] = red[0] + b2v[0];
    }
}

__global__ __launch_bounds__(256) void attn_pool_k(
    const float* __restrict__ out2, const float* __restrict__ a,
    float* __restrict__ wsv)
{
    int b = blockIdx.x;
    __shared__ float w[T_];
    if (threadIdx.x == 0) {
        float m = -1e30f;
        for (int t = 0; t < T_; t++) m = fmaxf(m, a[b*T_ + t]);
        float s = 0.f;
        for (int t = 0; t < T_; t++) { float e = __expf(a[b*T_ + t] - m); w[t] = e; s += e; }
        float inv = 1.f / s;
        for (int t = 0; t < T_; t++) w[t] *= inv;
    }
    __syncthreads();
    int h2 = threadIdx.x;
    float acc = 0.f;
    for (int t = 0; t < T_; t++) acc += w[t] * out2[((long)t*B_ + b)*256 + h2];
    wsv[b*256 + h2] = acc;
}

// ---------------- FC head + log_softmax ----------------

__global__ __launch_bounds__(512) void head_k(
    const float* __restrict__ wsv, const float* __restrict__ w1,
    const float* __restrict__ b1, const float* __restrict__ w2,
    const float* __restrict__ b2, float* __restrict__ outp)
{
    int b = blockIdx.x;
    int tid = threadIdx.x;
    __shared__ float r[128];
    __shared__ float y[C_];
    __shared__ float red[512];
    if (tid < 128) {
        float acc = b1[tid];
        for (int k = 0; k < 256; k++) acc += wsv[b*256 + k] * w1[k*128 + tid];
        r[tid] = fmaxf(acc, 0.f);
    }
    __syncthreads();
    for (int c = tid; c < C_; c += 512) {
        float acc = b2[c];
        for (int k = 0; k < 128; k++) acc += r[k] * w2[k*C_ + c];
        y[c] = acc;
    }
    __syncthreads();
    float m = -1e30f;
    for (int c = tid; c < C_; c += 512) m = fmaxf(m, y[c]);
    red[tid] = m;
    __syncthreads();
    for (int d = 256; d > 0; d >>= 1) {
        if (tid < d) red[tid] = fmaxf(red[tid], red[tid + d]);
        __syncthreads();
    }
    m = red[0];
    __syncthreads();
    float s = 0.f;
    for (int c = tid; c < C_; c += 512) s += __expf(y[c] - m);
    red[tid] = s;
    __syncthreads();
    for (int d = 256; d > 0; d >>= 1) {
        if (tid < d) red[tid] += red[tid + d];
        __syncthreads();
    }
    float lse = m + logf(red[0]);
    for (int c = tid; c < C_; c += 512) outp[(long)b*C_ + c] = y[c] - lse;
}

// ---------------- launch ----------------

extern "C" void kernel_launch(void* const* d_in, const int* in_sizes, int n_in,
                              void* d_out, int out_size, void* d_ws, size_t ws_size,
                              hipStream_t stream) {
    const float* x        = (const float*)d_in[0];
    const int*   ei       = (const int*)d_in[1];
    const float* gcn_w0   = (const float*)d_in[2];
    const float* gcn_w12  = (const float*)d_in[3];
    const float* gcn_b    = (const float*)d_in[4];
    const float* bn_gamma = (const float*)d_in[5];
    const float* bn_beta  = (const float*)d_in[6];
    const float* bn_mean  = (const float*)d_in[7];
    const float* bn_var   = (const float*)d_in[8];
    const float* wih0     = (const float*)d_in[9];
    const float* whh0     = (const float*)d_in[10];
    const float* bih0     = (const float*)d_in[11];
    const float* bhh0     = (const float*)d_in[12];
    const float* wih1     = (const float*)d_in[13];
    const float* whh1     = (const float*)d_in[14];
    const float* bih1     = (const float*)d_in[15];
    const float* bhh1     = (const float*)d_in[16];
    const float* attn_w1  = (const float*)d_in[17];
    const float* attn_b1  = (const float*)d_in[18];
    const float* attn_w2  = (const float*)d_in[19];
    const float* attn_b2  = (const float*)d_in[20];
    const float* fc1_w    = (const float*)d_in[21];
    const float* fc1_b    = (const float*)d_in[22];
    const float* fc2_w    = (const float*)d_in[23];
    const float* fc2_b    = (const float*)d_in[24];

    char* p = (char*)d_ws;
    auto alloc = [&](size_t bytes) {
        void* r = (void*)p;
        p += (bytes + 255) & ~(size_t)255;
        return r;
    };
    ushort* aggbuf = (ushort*)alloc((size_t)M_*H_*2);
    ushort* hbA    = (ushort*)alloc((size_t)M_*H_*2);
    ushort* hbB    = (ushort*)alloc((size_t)M_*H_*2);
    int*   cnt     = (int*)  alloc((size_t)M_*4);   // cnt + csr_cur contiguous
    int*   csr_cur = (int*)  alloc((size_t)M_*4);   // (single memset covers both)
    float* dinv    = (float*)alloc((size_t)M_*4);
    int*   bsum    = (int*)  alloc((size_t)SCAN_NB*4);
    int*   bexcl   = (int*)  alloc((size_t)SCAN_NB*4);
    int*   csr_off = (int*)  alloc((size_t)(M_+1)*4);
    unsigned int* csr_pk = (unsigned int*)alloc((size_t)TE_*4);
    float* bn_sc   = (float*)alloc(384*4);
    float* bn_sh   = (float*)alloc(384*4);
    float* bias0   = (float*)alloc(1024*4);
    float* bias1   = (float*)alloc(1024*4);
    ushort* w0t    = (ushort*)alloc((size_t)4096*2);
    ushort* w1t    = (ushort*)alloc((size_t)16384*2);
    ushort* w2t    = (ushort*)alloc((size_t)16384*2);
    unsigned int* wpk0 = (unsigned int*)alloc((size_t)2*64*512*4);
    unsigned int* wpk1 = (unsigned int*)alloc((size_t)2*64*512*4);
    ushort* wih0b  = (ushort*)alloc((size_t)2*512*128*2);
    ushort* wih1b  = (ushort*)alloc((size_t)2*512*256*2);
    ushort* embb   = (ushort*)alloc((size_t)T_*B_*H_*2);
    float* pre     = (float*)alloc((size_t)2*T_*B_*512*4);
    float* out1    = (float*)alloc((size_t)T_*B_*256*4);
    ushort* out1b  = (ushort*)alloc((size_t)T_*B_*256*2);
    float* out2v   = (float*)alloc((size_t)T_*B_*256*4);
    float* attn_av = (float*)alloc((size_t)B_*T_*4);
    float* wsv     = (float*)alloc((size_t)B_*256*4);

    // --- graph preprocessing (CSR by dst, packed u16 src + f16 weight) ---
    hipMemsetAsync(cnt, 0, (size_t)2*M_*4, stream);   // cnt + csr_cur
    count_edges_k<<<(TE_+255)/256, 256, 0, stream>>>(ei, cnt);
    scan1_k<<<SCAN_NB, 256, 0, stream>>>(cnt, bsum, dinv);
    scan2_k<<<1, 256, 0, stream>>>(bsum, bexcl, csr_off);
    scan3_k<<<SCAN_NB, 256, 0, stream>>>(cnt, bexcl, csr_off);
    fill_k<<<(TE_+255)/256, 256, 0, stream>>>(ei, csr_off, csr_cur, csr_pk, dinv);

    // --- weight prep (merged, fragment-swizzled) ---
    wprep_k<<<(WPREP_TOTAL+255)/256, 256, 0, stream>>>(
        gcn_b, bn_gamma, bn_beta, bn_mean, bn_var, bn_sc, bn_sh,
        bih0, bhh0, bias0, bih1, bhh1, bias1,
        gcn_w0, gcn_w12, w0t, w1t, w2t,
        whh0, whh1, wpk0, wpk1,
        wih0, wih1, wih0b, wih1b);

    // --- GCN layer 0 (conversion fused into gather) ---
    gather16f_k<<<M_/32, 256, 0, stream>>>(x, aggbuf, csr_off, csr_pk, dinv);
    mm_mfma_k<16, false><<<M_/64, 256, 0, stream>>>(aggbuf, w0t, hbA,
                                                    bn_sc + 0, bn_sh + 0, nullptr);
    // --- GCN layer 1 ---
    gather128_k<<<M_/4, 256, 0, stream>>>(hbA, aggbuf, csr_off, csr_pk, dinv);
    mm_mfma_k<128, true><<<M_/64, 256, 0, stream>>>(aggbuf, w1t, hbB,
                                                    bn_sc + 128, bn_sh + 128, hbA);
    // --- GCN layer 2 ---
    gather128_k<<<M_/4, 256, 0, stream>>>(hbB, aggbuf, csr_off, csr_pk, dinv);
    mm_mfma_k<128, true><<<M_/64, 256, 0, stream>>>(aggbuf, w2t, hbA,
                                                    bn_sc + 256, bn_sh + 256, hbB);

    // --- mean pool -> embb [T*B,128] f16 ---
    meanpool_k<<<T_*B_, 128, 0, stream>>>(hbA, embb);

    // --- BiLSTM layer 0 ---
    mm_pre_k<128><<<dim3((T_*B_)/64, 4, 2), 256, 0, stream>>>(embb, wih0b, pre, bias0);
    lstm_scan_k<<<64, 1024, 0, stream>>>(pre, wpk0, out1, out1b);

    // --- BiLSTM layer 1 ---
    mm_pre_k<256><<<dim3((T_*B_)/64, 4, 2), 256, 0, stream>>>(out1b, wih1b, pre, bias1);
    lstm_scan_k<<<64, 1024, 0, stream>>>(pre, wpk1, out2v, nullptr);

    // --- attention ---
    attn_a_k<<<T_*B_, 128, 0, stream>>>(out2v, attn_w1, attn_b1, attn_w2, attn_b2, attn_av);
    attn_pool_k<<<B_, 256, 0, stream>>>(out2v, attn_av, wsv);

    // --- head ---
    head_k<<<B_, 512, 0, stream>>>(wsv, fc1_w, fc1_b, fc2_w, fc2_b, (float*)d_out);
}

// Round 11
// 335.913 us; speedup vs baseline: 1.6951x; 1.2356x over previous
//
#include <hip/hip_runtime.h>

#define T_ 48
#define B_ 32
#define N_ 96
#define E_ 24576
#define BN_ (B_*N_)      // 3072
#define M_ (T_*BN_)      // 147456
#define FIN_ 16
#define H_ 128
#define C_ 500
#define TE_ (T_*E_)      // 1179648
#define EPS_ 1e-5f

typedef _Float16 f16x8 __attribute__((ext_vector_type(8)));
typedef float    f32x4 __attribute__((ext_vector_type(4)));
typedef _Float16 half2v __attribute__((ext_vector_type(2)));

__device__ __forceinline__ ushort f2h(float f) {
    _Float16 h = (_Float16)f;
    union { _Float16 h; ushort u; } v;
    v.h = h;
    return v.u;
}
__device__ __forceinline__ float h2f(ushort u) {
    union { ushort u; _Float16 h; } v;
    v.u = u;
    return (float)v.h;
}
__device__ __forceinline__ half2v pkfma(unsigned int v, unsigned int w, half2v acc) {
#if __has_builtin(__builtin_elementwise_fma)
    return __builtin_elementwise_fma(__builtin_bit_cast(half2v, v),
                                     __builtin_bit_cast(half2v, w), acc);
#else
    half2v hv = __builtin_bit_cast(half2v, v);
    half2v wv = __builtin_bit_cast(half2v, w);
    acc[0] += hv[0]*wv[0];
    acc[1] += hv[1]*wv[1];
    return acc;
#endif
}
__device__ __forceinline__ float dot2pk(unsigned int hbits, unsigned int wbits, float acc) {
#if __has_builtin(__builtin_amdgcn_fdot2)
    return __builtin_amdgcn_fdot2(__builtin_bit_cast(half2v, hbits),
                                  __builtin_bit_cast(half2v, wbits), acc, false);
#else
    half2v hv = __builtin_bit_cast(half2v, hbits);
    half2v wv = __builtin_bit_cast(half2v, wbits);
    acc = fmaf((float)hv[0], (float)wv[0], acc);
    acc = fmaf((float)hv[1], (float)wv[1], acc);
    return acc;
#endif
}
__device__ __forceinline__ float sigm(float x) {
    return 1.f / (1.f + __expf(-x));
}
__device__ __forceinline__ float ftanh(float x) {
    x = fminf(15.f, fmaxf(-15.f, x));
    float e = __expf(2.f * x);
    return (e - 1.f) / (e + 1.f);
}

// ---------------- fused CSR build: one block per timestep ----------------
// Each timestep owns nodes [t*BN, (t+1)*BN) and edges [t*E, (t+1)*E) exclusively.
// LDS: count (12K) + cursor (12K) + scan (4K) + staged packed edges (96K) = 124 KB.
__global__ __launch_bounds__(1024) void csr_build_k(
    const int* __restrict__ ei, int* __restrict__ csr_off,
    unsigned int* __restrict__ csr_pk, float* __restrict__ dinv)
{
    int t = blockIdx.x;
    int tid = threadIdx.x;
    __shared__ int cnt[BN_];
    __shared__ int cur[BN_];
    __shared__ int scanbuf[1024];
    __shared__ unsigned int pk[E_];

    #pragma unroll
    for (int i = 0; i < 3; i++) cnt[tid + i*1024] = 0;
    __syncthreads();

    const int* srcp = ei + ((long)t*2+0)*E_;
    const int* dstp = ei + ((long)t*2+1)*E_;
    #pragma unroll
    for (int i = 0; i < E_/1024; i++)
        atomicAdd(&cnt[dstp[tid + i*1024]], 1);
    __syncthreads();

    // exclusive scan over 3072 counts (3 contiguous per thread)
    int n0 = tid*3;
    int a = cnt[n0], b = cnt[n0+1], c = cnt[n0+2];
    int tot = a + b + c;
    scanbuf[tid] = tot;
    __syncthreads();
    for (int d = 1; d < 1024; d <<= 1) {
        int add = (tid >= d) ? scanbuf[tid-d] : 0;
        __syncthreads();
        scanbuf[tid] += add;
        __syncthreads();
    }
    int excl = scanbuf[tid] - tot;
    cur[n0] = excl; cur[n0+1] = excl + a; cur[n0+2] = excl + a + b;
    int gbase = t*BN_, ebase = t*E_;
    csr_off[gbase+n0]   = ebase + excl;
    csr_off[gbase+n0+1] = ebase + excl + a;
    csr_off[gbase+n0+2] = ebase + excl + a + b;
    dinv[gbase+n0]   = rsqrtf((float)a + 1.f);
    dinv[gbase+n0+1] = rsqrtf((float)b + 1.f);
    dinv[gbase+n0+2] = rsqrtf((float)c + 1.f);
    if (t == T_-1 && tid == 0) csr_off[M_] = TE_;
    __syncthreads();

    // scatter packed edges into LDS staging
    #pragma unroll
    for (int i = 0; i < E_/1024; i++) {
        int e = tid + i*1024;
        int s = srcp[e], d = dstp[e];
        int pos = atomicAdd(&cur[d], 1);
        float w = rsqrtf((float)cnt[s] + 1.f) * rsqrtf((float)cnt[d] + 1.f);
        pk[pos] = (unsigned int)s | ((unsigned int)f2h(w) << 16);
    }
    __syncthreads();

    // contiguous coalesced write-out
    uint4* dpk = (uint4*)(csr_pk + ebase);
    const uint4* spk = (const uint4*)pk;
    #pragma unroll
    for (int i = 0; i < E_/4096; i++)
        dpk[tid + i*1024] = spk[tid + i*1024];
}

// ---------------- merged weight prep (fragment-swizzled MFMA weights) --------
#define WPREP_TOTAL (384+1024+4096+16384+16384+65536+65536+131072+262144)
__global__ void wprep_k(
    const float* __restrict__ gcn_b, const float* __restrict__ gam,
    const float* __restrict__ bet, const float* __restrict__ mu,
    const float* __restrict__ var,
    float* __restrict__ bn_sc, float* __restrict__ bn_sh,
    const float* __restrict__ bih0, const float* __restrict__ bhh0,
    float* __restrict__ bias0,
    const float* __restrict__ bih1, const float* __restrict__ bhh1,
    float* __restrict__ bias1,
    const float* __restrict__ gcn_w0, const float* __restrict__ gcn_w12,
    ushort* __restrict__ w0t, ushort* __restrict__ w1t, ushort* __restrict__ w2t,
    const float* __restrict__ whh0, const float* __restrict__ whh1,
    unsigned int* __restrict__ wpk0, unsigned int* __restrict__ wpk1,
    const float* __restrict__ wih0, const float* __restrict__ wih1,
    ushort* __restrict__ wih0b, ushort* __restrict__ wih1b)
{
    int i = blockIdx.x * blockDim.x + threadIdx.x;
    if (i >= WPREP_TOTAL) return;
    if (i < 384) {
        float sc = gam[i] * rsqrtf(var[i] + EPS_);
        bn_sc[i] = sc;
        bn_sh[i] = gcn_b[i]*sc + bet[i] - mu[i]*sc;
        return;
    }
    i -= 384;
    if (i < 1024) {
        bias0[i] = bih0[i] + bhh0[i];
        bias1[i] = bih1[i] + bhh1[i];
        return;
    }
    i -= 1024;
    if (i < 4096) {       // w0t frag, K=16
        int e = i & 7, lane = (i >> 3) & 63, ct = i >> 9;
        int k = (lane >> 4)*8 + e;
        int c = ct*16 + (lane & 15);
        w0t[i] = (k < 16) ? f2h(gcn_w0[k*128 + c]) : (ushort)0;
        return;
    }
    i -= 4096;
    if (i < 16384) {      // w1t frag, K=128
        int e = i & 7, lane = (i >> 3) & 63, kk = (i >> 9) & 3, ct = i >> 11;
        int k = kk*32 + (lane >> 4)*8 + e;
        int c = ct*16 + (lane & 15);
        w1t[i] = f2h(gcn_w12[k*128 + c]);
        return;
    }
    i -= 16384;
    if (i < 16384) {      // w2t frag
        int e = i & 7, lane = (i >> 3) & 63, kk = (i >> 9) & 3, ct = i >> 11;
        int k = kk*32 + (lane >> 4)*8 + e;
        int c = ct*16 + (lane & 15);
        w2t[i] = f2h(gcn_w12[16384 + k*128 + c]);
        return;
    }
    i -= 16384;
    if (i < 65536) {
        int g = i & 511;
        int qd = i >> 9;
        int dir = qd >> 6, q = qd & 63;
        const float* wr = whh0 + ((long)(dir*512 + g))*128 + 2*q;
        wpk0[i] = (unsigned int)f2h(wr[0]) | ((unsigned int)f2h(wr[1]) << 16);
        return;
    }
    i -= 65536;
    if (i < 65536) {
        int g = i & 511;
        int qd = i >> 9;
        int dir = qd >> 6, q = qd & 63;
        const float* wr = whh1 + ((long)(dir*512 + g))*128 + 2*q;
        wpk1[i] = (unsigned int)f2h(wr[0]) | ((unsigned int)f2h(wr[1]) << 16);
        return;
    }
    i -= 65536;
    if (i < 131072) {     // wih0b frag, N=512, K=128
        int dir = i >> 16, r = i & 0xFFFF;
        int nt = r >> 11, kk = (r >> 9) & 3, lane = (r >> 3) & 63, e = r & 7;
        int n = nt*16 + (lane & 15);
        int k = kk*32 + (lane >> 4)*8 + e;
        wih0b[i] = f2h(wih0[((long)dir*512 + n)*128 + k]);
        return;
    }
    i -= 131072;
    {                     // wih1b frag, N=512, K=256
        int dir = i >> 17, r = i & 0x1FFFF;
        int nt = r >> 12, kk = (r >> 9) & 7, lane = (r >> 3) & 63, e = r & 7;
        int n = nt*16 + (lane & 15);
        int k = kk*32 + (lane >> 4)*8 + e;
        wih1b[i] = f2h(wih1[((long)dir*512 + n)*256 + k]);
    }
}

// ---------------- f16 gathers ----------------
// out[node,:] = h[node,:]*dinv[node]^2 + sum_e h[src,:]*w[e]

// F=128: one wave per node; scalar-pipe edge walk (node wave-uniform).
__global__ __launch_bounds__(256) void gather128_k(
    const ushort* __restrict__ h, ushort* __restrict__ out,
    const int* __restrict__ csr_off, const unsigned int* __restrict__ csr_pk,
    const float* __restrict__ dinv)
{
    int nb = gridDim.x;                  // M/4 blocks, 4 waves each; divisible by 8
    int chunk = nb >> 3;
    int bswz = (blockIdx.x & 7) * chunk + (blockIdx.x >> 3);
    int node = __builtin_amdgcn_readfirstlane(bswz * 4 + (threadIdx.x >> 6));
    int tbase = (node / BN_) * BN_;      // scalar
    int l2 = (threadIdx.x & 63) * 2;     // feature pair (per-lane)
    float dv = dinv[node];
    ushort swh = f2h(dv * dv);
    unsigned int swp = (unsigned int)swh * 0x10001u;
    unsigned int selfv = *(const unsigned int*)(h + (size_t)node*128 + l2);
    half2v sp = __builtin_bit_cast(half2v, swp);
    half2v acc0 = __builtin_bit_cast(half2v, selfv);
    acc0[0] = acc0[0] * sp[0];
    acc0[1] = acc0[1] * sp[1];
    half2v acc1 = {(_Float16)0.f, (_Float16)0.f};
    half2v acc2 = {(_Float16)0.f, (_Float16)0.f};
    half2v acc3 = {(_Float16)0.f, (_Float16)0.f};
    int e0 = __builtin_amdgcn_readfirstlane(csr_off[node]);
    int e1 = __builtin_amdgcn_readfirstlane(csr_off[node+1]);
    int j = e0;
    for (; j + 8 <= e1; j += 8) {
        unsigned int p0 = __builtin_amdgcn_readfirstlane(csr_pk[j+0]);
        unsigned int p1 = __builtin_amdgcn_readfirstlane(csr_pk[j+1]);
        unsigned int p2 = __builtin_amdgcn_readfirstlane(csr_pk[j+2]);
        unsigned int p3 = __builtin_amdgcn_readfirstlane(csr_pk[j+3]);
        unsigned int p4 = __builtin_amdgcn_readfirstlane(csr_pk[j+4]);
        unsigned int p5 = __builtin_amdgcn_readfirstlane(csr_pk[j+5]);
        unsigned int p6 = __builtin_amdgcn_readfirstlane(csr_pk[j+6]);
        unsigned int p7 = __builtin_amdgcn_readfirstlane(csr_pk[j+7]);
        const ushort* r0 = h + (size_t)(tbase + (int)(p0 & 0xffffu))*128;
        const ushort* r1 = h + (size_t)(tbase + (int)(p1 & 0xffffu))*128;
        const ushort* r2 = h + (size_t)(tbase + (int)(p2 & 0xffffu))*128;
        const ushort* r3 = h + (size_t)(tbase + (int)(p3 & 0xffffu))*128;
        const ushort* r4 = h + (size_t)(tbase + (int)(p4 & 0xffffu))*128;
        const ushort* r5 = h + (size_t)(tbase + (int)(p5 & 0xffffu))*128;
        const ushort* r6 = h + (size_t)(tbase + (int)(p6 & 0xffffu))*128;
        const ushort* r7 = h + (size_t)(tbase + (int)(p7 & 0xffffu))*128;
        unsigned int v0 = *(const unsigned int*)(r0 + l2);
        unsigned int v1 = *(const unsigned int*)(r1 + l2);
        unsigned int v2 = *(const unsigned int*)(r2 + l2);
        unsigned int v3 = *(const unsigned int*)(r3 + l2);
        unsigned int v4 = *(const unsigned int*)(r4 + l2);
        unsigned int v5 = *(const unsigned int*)(r5 + l2);
        unsigned int v6 = *(const unsigned int*)(r6 + l2);
        unsigned int v7 = *(const unsigned int*)(r7 + l2);
        acc0 = pkfma(v0, (p0 >> 16) * 0x10001u, acc0);
        acc1 = pkfma(v1, (p1 >> 16) * 0x10001u, acc1);
        acc2 = pkfma(v2, (p2 >> 16) * 0x10001u, acc2);
        acc3 = pkfma(v3, (p3 >> 16) * 0x10001u, acc3);
        acc0 = pkfma(v4, (p4 >> 16) * 0x10001u, acc0);
        acc1 = pkfma(v5, (p5 >> 16) * 0x10001u, acc1);
        acc2 = pkfma(v6, (p6 >> 16) * 0x10001u, acc2);
        acc3 = pkfma(v7, (p7 >> 16) * 0x10001u, acc3);
    }
    for (; j < e1; j++) {
        unsigned int pk = __builtin_amdgcn_readfirstlane(csr_pk[j]);
        const ushort* r = h + (size_t)(tbase + (int)(pk & 0xffffu))*128;
        unsigned int v = *(const unsigned int*)(r + l2);
        acc0 = pkfma(v, (pk >> 16) * 0x10001u, acc0);
    }
    float a0 = ((float)acc0[0] + (float)acc1[0]) + ((float)acc2[0] + (float)acc3[0]);
    float a1 = ((float)acc0[1] + (float)acc1[1]) + ((float)acc2[1] + (float)acc3[1]);
    unsigned int ov = (unsigned int)f2h(a0) | ((unsigned int)f2h(a1) << 16);
    *(unsigned int*)(out + (size_t)node*128 + l2) = ov;
}

// F=16, fused f32->f16 conversion: reads x (f32), writes f16 agg.
__global__ __launch_bounds__(256) void gather16f_k(
    const float* __restrict__ x, ushort* __restrict__ out,
    const int* __restrict__ csr_off, const unsigned int* __restrict__ csr_pk,
    const float* __restrict__ dinv)
{
    int nb = gridDim.x;                  // M/32
    int chunk = nb >> 3;
    int bswz = (blockIdx.x & 7) * chunk + (blockIdx.x >> 3);
    int node = bswz * 32 + (threadIdx.x >> 3);
    int f0 = (threadIdx.x & 7) * 2;
    int tbase = (node / BN_) * BN_;
    float dv = dinv[node];
    float2 sv = *(const float2*)(x + (long)node*16 + f0);
    float s = dv * dv;
    float a0 = sv.x*s, a1 = sv.y*s;
    int e0 = csr_off[node], e1 = csr_off[node+1];
    int j = e0;
    for (; j + 4 <= e1; j += 4) {
        unsigned int p0 = csr_pk[j], p1 = csr_pk[j+1], p2 = csr_pk[j+2], p3 = csr_pk[j+3];
        int s0 = tbase + (int)(p0 & 0xffffu), s1 = tbase + (int)(p1 & 0xffffu);
        int s2 = tbase + (int)(p2 & 0xffffu), s3 = tbase + (int)(p3 & 0xffffu);
        float w0 = h2f((ushort)(p0 >> 16)), w1 = h2f((ushort)(p1 >> 16));
        float w2 = h2f((ushort)(p2 >> 16)), w3 = h2f((ushort)(p3 >> 16));
        float2 v0 = *(const float2*)(x + (long)s0*16 + f0);
        float2 v1 = *(const float2*)(x + (long)s1*16 + f0);
        float2 v2 = *(const float2*)(x + (long)s2*16 + f0);
        float2 v3 = *(const float2*)(x + (long)s3*16 + f0);
        a0 += v0.x*w0 + v1.x*w1 + v2.x*w2 + v3.x*w3;
        a1 += v0.y*w0 + v1.y*w1 + v2.y*w2 + v3.y*w3;
    }
    for (; j < e1; j++) {
        unsigned int pk = csr_pk[j];
        int sc = tbase + (int)(pk & 0xffffu);
        float en = h2f((ushort)(pk >> 16));
        float2 v = *(const float2*)(x + (long)sc*16 + f0);
        a0 += v.x*en; a1 += v.y*en;
    }
    unsigned int ov = (unsigned int)f2h(a0) | ((unsigned int)f2h(a1) << 16);
    *(unsigned int*)(out + (long)node*16 + f0) = ov;
}

// ---------------- MFMA GEMM: GCN layers, frag-swizzled Wt, LDS epilogue -------
template<int K, bool HASRES>
__global__ __launch_bounds__(256) void mm_mfma_k(
    const ushort* __restrict__ A, const ushort* __restrict__ Wt,
    ushort* __restrict__ Cout,
    const float* __restrict__ bnsc, const float* __restrict__ bnsh,
    const ushort* __restrict__ resid)
{
    constexpr int KST = (K >= 32) ? (K/32) : 1;
    int tid = threadIdx.x;
    int w = tid >> 6, lane = tid & 63;
    int l16 = lane & 15, lh = lane >> 4;
    int row0 = blockIdx.x * 64 + w * 16;
    __shared__ ushort cl[64][136];   // padded to kill bank conflicts

    f32x4 acc[8];
    #pragma unroll
    for (int i = 0; i < 8; i++) acc[i] = (f32x4){0.f, 0.f, 0.f, 0.f};

    #pragma unroll
    for (int kk = 0; kk < KST; kk++) {
        int ka = kk*32 + lh*8;
        f16x8 af;
        bool valid = (K >= 32) || (ka < K);
        if (valid) {
            af = *reinterpret_cast<const f16x8*>(&A[(long)(row0 + l16)*K + ka]);
        } else {
            #pragma unroll
            for (int e = 0; e < 8; e++) af[e] = (_Float16)0.f;
        }
        #pragma unroll
        for (int ct = 0; ct < 8; ct++) {
            f16x8 bfr = *reinterpret_cast<const f16x8*>(
                &Wt[(((long)ct*KST + kk)*64 + lane)*8]);
            acc[ct] = __builtin_amdgcn_mfma_f32_16x16x32_f16(af, bfr, acc[ct], 0, 0, 0);
        }
    }

    // BN+ReLU into LDS (f16), then coalesced vectorized write (+resid)
    #pragma unroll
    for (int ct = 0; ct < 8; ct++) {
        int col = ct*16 + l16;
        float sc = bnsc[col], sh = bnsh[col];
        #pragma unroll
        for (int r = 0; r < 4; r++) {
            int rl = w*16 + lh*4 + r;
            float v = acc[ct][r] * sc + sh;
            cl[rl][col] = f2h(fmaxf(v, 0.f));
        }
    }
    __syncthreads();
    long rowblock = (long)blockIdx.x * 64;
    #pragma unroll
    for (int it = 0; it < 4; it++) {
        int s = it*256 + tid;           // 1024 segments: 64 rows x 16 (8-col segs)
        int rl = s >> 4, c8 = (s & 15) * 8;
        uint4 v = *(const uint4*)&cl[rl][c8];
        if (HASRES) {
            uint4 rv = *(const uint4*)&resid[(rowblock + rl)*128 + c8];
            half2v* vv = (half2v*)&v;
            const half2v* rr = (const half2v*)&rv;
            vv[0] += rr[0]; vv[1] += rr[1]; vv[2] += rr[2]; vv[3] += rr[3];
        }
        *(uint4*)&Cout[(rowblock + rl)*128 + c8] = v;
    }
}

// ---------------- MFMA GEMM: LSTM input projection (frag-swizzled Wt) --------
template<int K>
__global__ __launch_bounds__(256) void mm_pre_k(
    const ushort* __restrict__ A, const ushort* __restrict__ Wt_all,
    float* __restrict__ Cout_all, const float* __restrict__ bias_all)
{
    constexpr int KST = K/32;
    int dir = blockIdx.z;
    const ushort* Wt = Wt_all + (size_t)dir * 512 * K;
    float* Cout = Cout_all + (size_t)dir * T_ * B_ * 512;
    const float* bias = bias_all + dir * 512;

    int tid = threadIdx.x;
    int w = tid >> 6, lane = tid & 63;
    int l16 = lane & 15, lh = lane >> 4;
    int row0 = blockIdx.x * 64 + w * 16;
    int nt0 = blockIdx.y * 8;    // col-tile base (8 tiles of 16 -> 128 cols)

    f32x4 acc[8];
    #pragma unroll
    for (int i = 0; i < 8; i++) acc[i] = (f32x4){0.f, 0.f, 0.f, 0.f};

    #pragma unroll
    for (int kk = 0; kk < KST; kk++) {
        int ka = kk*32 + lh*8;
        f16x8 af = *reinterpret_cast<const f16x8*>(&A[(long)(row0 + l16)*K + ka]);
        #pragma unroll
        for (int ct = 0; ct < 8; ct++) {
            f16x8 bfr = *reinterpret_cast<const f16x8*>(
                &Wt[(((long)(nt0 + ct)*KST + kk)*64 + lane)*8]);
            acc[ct] = __builtin_amdgcn_mfma_f32_16x16x32_f16(af, bfr, acc[ct], 0, 0, 0);
        }
    }

    #pragma unroll
    for (int ct = 0; ct < 8; ct++) {
        int col = (nt0 + ct)*16 + l16;
        float bv = bias[col];
        #pragma unroll
        for (int r = 0; r < 4; r++) {
            int row = row0 + lh*4 + r;
            Cout[(long)row*512 + col] = acc[ct][r] + bv;
        }
    }
}

// ---------------- mean pool (f16 in, f16 out) ----------------

__global__ void meanpool_k(const ushort* __restrict__ h, ushort* __restrict__ embb) {
    int row = blockIdx.x;            // t*B + b
    int t = row / B_, b = row - t*B_;
    int hh = threadIdx.x;
    const ushort* base = h + ((long)t*BN_ + b*N_)*H_ + hh;
    float acc = 0.f;
    for (int n = 0; n < N_; n++) acc += h2f(base[(long)n*H_]);
    embb[(long)row*H_ + hh] = f2h(acc * (1.f / N_));
}

// ---------------- LSTM scan: f16 dot2, k-split x2, pre-prefetch ----------------
__global__ __launch_bounds__(1024) void lstm_scan_k(
    const float* __restrict__ pre,            // [2][T*B][512]
    const unsigned int* __restrict__ wpkbuf,  // [2][64][512] packed f16 pairs
    float* __restrict__ out,                  // [T*B][256] f32
    ushort* __restrict__ outb)                // [T*B][256] f16 (nullable)
{
    int dir = blockIdx.x >> 5;
    int b   = blockIdx.x & 31;
    int tid = threadIdx.x;
    int half = tid >> 9;
    int g    = tid & 511;

    __shared__ ushort h_s[H_];               // f16 bits
    __shared__ float part[1024];
    if (tid < H_) h_s[tid] = 0;
    float creg = 0.f;

    const unsigned int* wp = wpkbuf + (long)dir * 64 * 512 + (long)half * 32 * 512;
    unsigned int wpk[32];
    #pragma unroll
    for (int q = 0; q < 32; q++) wpk[q] = wp[q*512 + g];

    const float* pred = pre + (long)dir * T_ * B_ * 512;
    int t = dir ? (T_ - 1) : 0;
    int tstep = dir ? -1 : 1;
    float pv = (half == 0) ? pred[((long)t*B_ + b)*512 + g] : 0.f;
    __syncthreads();

    for (int st = 0; st < T_; st++) {
        int tn = t + tstep;
        tn = (tn < 0) ? 0 : ((tn >= T_) ? T_ - 1 : tn);
        float pvn = (half == 0) ? pred[((long)tn*B_ + b)*512 + g] : 0.f;

        const uint4* h4 = (const uint4*)(h_s + half*64);
        float acc = pv;
        #pragma unroll
        for (int jj = 0; jj < 8; jj++) {
            uint4 hv = h4[jj];
            acc = dot2pk(hv.x, wpk[jj*4+0], acc);
            acc = dot2pk(hv.y, wpk[jj*4+1], acc);
            acc = dot2pk(hv.z, wpk[jj*4+2], acc);
            acc = dot2pk(hv.w, wpk[jj*4+3], acc);
        }
        part[tid] = acc;
        __syncthreads();

        if (tid < H_) {
            float ig = sigm (part[tid]       + part[512 + tid]);
            float fg = sigm (part[128 + tid] + part[640 + tid]);
            float gg = ftanh(part[256 + tid] + part[768 + tid]);
            float og = sigm (part[384 + tid] + part[896 + tid]);
            float c = fg * creg + ig * gg;
            float h = og * ftanh(c);
            creg = c;
            h_s[tid] = f2h(h);
            long orow = ((long)t*B_ + b)*256 + dir*H_ + tid;
            out[orow] = h;
            if (outb) outb[orow] = f2h(h);
        }
        __syncthreads();
        pv = pvn;
        t = tn;
    }
}

// ---------------- attention ----------------

__global__ __launch_bounds__(128) void attn_a_k(
    const float* __restrict__ out2, const float* __restrict__ w1,
    const float* __restrict__ b1, const float* __restrict__ w2,
    const float* __restrict__ b2v, float* __restrict__ a)
{
    int row = blockIdx.x;
    int j = threadIdx.x;
    const float* xr = out2 + (long)row * 256;
    float acc = b1[j];
    for (int k = 0; k < 256; k++) acc += xr[k] * w1[k*128 + j];
    float u = tanhf(acc) * w2[j];
    __shared__ float red[128];
    red[j] = u;
    __syncthreads();
    for (int d = 64; d > 0; d >>= 1) {
        if (j < d) red[j] += red[j + d];
        __syncthreads();
    }
    if (j == 0) {
        int t = row / B_, b = row - t*B_;
        a[b*T_ + t] = red[0] + b2v[0];
    }
}

__global__ __launch_bounds__(256) void attn_pool_k(
    const float* __restrict__ out2, const float* __restrict__ a,
    float* __restrict__ wsv)
{
    int b = blockIdx.x;
    __shared__ float w[T_];
    if (threadIdx.x == 0) {
        float m = -1e30f;
        for (int t = 0; t < T_; t++) m = fmaxf(m, a[b*T_ + t]);
        float s = 0.f;
        for (int t = 0; t < T_; t++) { float e = __expf(a[b*T_ + t] - m); w[t] = e; s += e; }
        float inv = 1.f / s;
        for (int t = 0; t < T_; t++) w[t] *= inv;
    }
    __syncthreads();
    int h2 = threadIdx.x;
    float acc = 0.f;
    for (int t = 0; t < T_; t++) acc += w[t] * out2[((long)t*B_ + b)*256 + h2];
    wsv[b*256 + h2] = acc;
}

// ---------------- FC head + log_softmax ----------------

__global__ __launch_bounds__(512) void head_k(
    const float* __restrict__ wsv, const float* __restrict__ w1,
    const float* __restrict__ b1, const float* __restrict__ w2,
    const float* __restrict__ b2, float* __restrict__ outp)
{
    int b = blockIdx.x;
    int tid = threadIdx.x;
    __shared__ float r[128];
    __shared__ float y[C_];
    __shared__ float red[512];
    if (tid < 128) {
        float acc = b1[tid];
        for (int k = 0; k < 256; k++) acc += wsv[b*256 + k] * w1[k*128 + tid];
        r[tid] = fmaxf(acc, 0.f);
    }
    __syncthreads();
    for (int c = tid; c < C_; c += 512) {
        float acc = b2[c];
        for (int k = 0; k < 128; k++) acc += r[k] * w2[k*C_ + c];
        y[c] = acc;
    }
    __syncthreads();
    float m = -1e30f;
    for (int c = tid; c < C_; c += 512) m = fmaxf(m, y[c]);
    red[tid] = m;
    __syncthreads();
    for (int d = 256; d > 0; d >>= 1) {
        if (tid < d) red[tid] = fmaxf(red[tid], red[tid + d]);
        __syncthreads();
    }
    m = red[0];
    __syncthreads();
    float s = 0.f;
    for (int c = tid; c < C_; c += 512) s += __expf(y[c] - m);
    red[tid] = s;
    __syncthreads();
    for (int d = 256; d > 0; d >>= 1) {
        if (tid < d) red[tid] += red[tid + d];
        __syncthreads();
    }
    float lse = m + logf(red[0]);
    for (int c = tid; c < C_; c += 512) outp[(long)b*C_ + c] = y[c] - lse;
}

// ---------------- launch ----------------

extern "C" void kernel_launch(void* const* d_in, const int* in_sizes, int n_in,
                              void* d_out, int out_size, void* d_ws, size_t ws_size,
                              hipStream_t stream) {
    const float* x        = (const float*)d_in[0];
    const int*   ei       = (const int*)d_in[1];
    const float* gcn_w0   = (const float*)d_in[2];
    const float* gcn_w12  = (const float*)d_in[3];
    const float* gcn_b    = (const float*)d_in[4];
    const float* bn_gamma = (const float*)d_in[5];
    const float* bn_beta  = (const float*)d_in[6];
    const float* bn_mean  = (const float*)d_in[7];
    const float* bn_var   = (const float*)d_in[8];
    const float* wih0     = (const float*)d_in[9];
    const float* whh0     = (const float*)d_in[10];
    const float* bih0     = (const float*)d_in[11];
    const float* bhh0     = (const float*)d_in[12];
    const float* wih1     = (const float*)d_in[13];
    const float* whh1     = (const float*)d_in[14];
    const float* bih1     = (const float*)d_in[15];
    const float* bhh1     = (const float*)d_in[16];
    const float* attn_w1  = (const float*)d_in[17];
    const float* attn_b1  = (const float*)d_in[18];
    const float* attn_w2  = (const float*)d_in[19];
    const float* attn_b2  = (const float*)d_in[20];
    const float* fc1_w    = (const float*)d_in[21];
    const float* fc1_b    = (const float*)d_in[22];
    const float* fc2_w    = (const float*)d_in[23];
    const float* fc2_b    = (const float*)d_in[24];

    char* p = (char*)d_ws;
    auto alloc = [&](size_t bytes) {
        void* r = (void*)p;
        p += (bytes + 255) & ~(size_t)255;
        return r;
    };
    ushort* aggbuf = (ushort*)alloc((size_t)M_*H_*2);
    ushort* hbA    = (ushort*)alloc((size_t)M_*H_*2);
    ushort* hbB    = (ushort*)alloc((size_t)M_*H_*2);
    float* dinv    = (float*)alloc((size_t)M_*4);
    int*   csr_off = (int*)  alloc((size_t)(M_+1)*4);
    unsigned int* csr_pk = (unsigned int*)alloc((size_t)TE_*4);
    float* bn_sc   = (float*)alloc(384*4);
    float* bn_sh   = (float*)alloc(384*4);
    float* bias0   = (float*)alloc(1024*4);
    float* bias1   = (float*)alloc(1024*4);
    ushort* w0t    = (ushort*)alloc((size_t)4096*2);
    ushort* w1t    = (ushort*)alloc((size_t)16384*2);
    ushort* w2t    = (ushort*)alloc((size_t)16384*2);
    unsigned int* wpk0 = (unsigned int*)alloc((size_t)2*64*512*4);
    unsigned int* wpk1 = (unsigned int*)alloc((size_t)2*64*512*4);
    ushort* wih0b  = (ushort*)alloc((size_t)2*512*128*2);
    ushort* wih1b  = (ushort*)alloc((size_t)2*512*256*2);
    ushort* embb   = (ushort*)alloc((size_t)T_*B_*H_*2);
    float* pre     = (float*)alloc((size_t)2*T_*B_*512*4);
    float* out1    = (float*)alloc((size_t)T_*B_*256*4);
    ushort* out1b  = (ushort*)alloc((size_t)T_*B_*256*2);
    float* out2v   = (float*)alloc((size_t)T_*B_*256*4);
    float* attn_av = (float*)alloc((size_t)B_*T_*4);
    float* wsv     = (float*)alloc((size_t)B_*256*4);

    // --- fused CSR build (count+scan+scatter per timestep, LDS-staged) ---
    csr_build_k<<<T_, 1024, 0, stream>>>(ei, csr_off, csr_pk, dinv);

    // --- weight prep (merged, fragment-swizzled) ---
    wprep_k<<<(WPREP_TOTAL+255)/256, 256, 0, stream>>>(
        gcn_b, bn_gamma, bn_beta, bn_mean, bn_var, bn_sc, bn_sh,
        bih0, bhh0, bias0, bih1, bhh1, bias1,
        gcn_w0, gcn_w12, w0t, w1t, w2t,
        whh0, whh1, wpk0, wpk1,
        wih0, wih1, wih0b, wih1b);

    // --- GCN layer 0 (conversion fused into gather) ---
    gather16f_k<<<M_/32, 256, 0, stream>>>(x, aggbuf, csr_off, csr_pk, dinv);
    mm_mfma_k<16, false><<<M_/64, 256, 0, stream>>>(aggbuf, w0t, hbA,
                                                    bn_sc + 0, bn_sh + 0, nullptr);
    // --- GCN layer 1 ---
    gather128_k<<<M_/4, 256, 0, stream>>>(hbA, aggbuf, csr_off, csr_pk, dinv);
    mm_mfma_k<128, true><<<M_/64, 256, 0, stream>>>(aggbuf, w1t, hbB,
                                                    bn_sc + 128, bn_sh + 128, hbA);
    // --- GCN layer 2 ---
    gather128_k<<<M_/4, 256, 0, stream>>>(hbB, aggbuf, csr_off, csr_pk, dinv);
    mm_mfma_k<128, true><<<M_/64, 256, 0, stream>>>(aggbuf, w2t, hbA,
                                                    bn_sc + 256, bn_sh + 256, hbB);

    // --- mean pool -> embb [T*B,128] f16 ---
    meanpool_k<<<T_*B_, 128, 0, stream>>>(hbA, embb);

    // --- BiLSTM layer 0 ---
    mm_pre_k<128><<<dim3((T_*B_)/64, 4, 2), 256, 0, stream>>>(embb, wih0b, pre, bias0);
    lstm_scan_k<<<64, 1024, 0, stream>>>(pre, wpk0, out1, out1b);

    // --- BiLSTM layer 1 ---
    mm_pre_k<256><<<dim3((T_*B_)/64, 4, 2), 256, 0, stream>>>(out1b, wih1b, pre, bias1);
    lstm_scan_k<<<64, 1024, 0, stream>>>(pre, wpk1, out2v, nullptr);

    // --- attention ---
    attn_a_k<<<T_*B_, 128, 0, stream>>>(out2v, attn_w1, attn_b1, attn_w2, attn_b2, attn_av);
    attn_pool_k<<<B_, 256, 0, stream>>>(out2v, attn_av, wsv);

    // --- head ---
    head_k<<<B_, 512, 0, stream>>>(wsv, fc1_w, fc1_b, fc2_w, fc2_b, (float*)d_out);
}

// Round 12
// 332.935 us; speedup vs baseline: 1.7102x; 1.0089x over previous
//
#include <hip/hip_runtime.h>

#define T_ 48
#define B_ 32
#define N_ 96
#define E_ 24576
#define BN_ (B_*N_)      // 3072
#define M_ (T_*BN_)      // 147456
#define FIN_ 16
#define H_ 128
#define C_ 500
#define TE_ (T_*E_)      // 1179648
#define EPS_ 1e-5f

typedef _Float16 f16x8 __attribute__((ext_vector_type(8)));
typedef float    f32x4 __attribute__((ext_vector_type(4)));
typedef _Float16 half2v __attribute__((ext_vector_type(2)));

__device__ __forceinline__ ushort f2h(float f) {
    _Float16 h = (_Float16)f;
    union { _Float16 h; ushort u; } v;
    v.h = h;
    return v.u;
}
__device__ __forceinline__ float h2f(ushort u) {
    union { ushort u; _Float16 h; } v;
    v.u = u;
    return (float)v.h;
}
__device__ __forceinline__ half2v pkfma(unsigned int v, unsigned int w, half2v acc) {
#if __has_builtin(__builtin_elementwise_fma)
    return __builtin_elementwise_fma(__builtin_bit_cast(half2v, v),
                                     __builtin_bit_cast(half2v, w), acc);
#else
    half2v hv = __builtin_bit_cast(half2v, v);
    half2v wv = __builtin_bit_cast(half2v, w);
    acc[0] += hv[0]*wv[0];
    acc[1] += hv[1]*wv[1];
    return acc;
#endif
}
__device__ __forceinline__ float dot2pk(unsigned int hbits, unsigned int wbits, float acc) {
#if __has_builtin(__builtin_amdgcn_fdot2)
    return __builtin_amdgcn_fdot2(__builtin_bit_cast(half2v, hbits),
                                  __builtin_bit_cast(half2v, wbits), acc, false);
#else
    half2v hv = __builtin_bit_cast(half2v, hbits);
    half2v wv = __builtin_bit_cast(half2v, wbits);
    acc = fmaf((float)hv[0], (float)wv[0], acc);
    acc = fmaf((float)hv[1], (float)wv[1], acc);
    return acc;
#endif
}
__device__ __forceinline__ float sigm(float x) {
    return 1.f / (1.f + __expf(-x));
}
__device__ __forceinline__ float ftanh(float x) {
    x = fminf(15.f, fmaxf(-15.f, x));
    float e = __expf(2.f * x);
    return (e - 1.f) / (e + 1.f);
}

// ---------------- fused CSR build: one block per timestep ----------------
__global__ __launch_bounds__(1024) void csr_build_k(
    const int* __restrict__ ei, int* __restrict__ csr_off,
    unsigned int* __restrict__ csr_pk, float* __restrict__ dinv)
{
    int t = blockIdx.x;
    int tid = threadIdx.x;
    __shared__ int cnt[BN_];
    __shared__ int cur[BN_];
    __shared__ int scanbuf[1024];
    __shared__ unsigned int pk[E_];

    #pragma unroll
    for (int i = 0; i < 3; i++) cnt[tid + i*1024] = 0;
    __syncthreads();

    const int* srcp = ei + ((long)t*2+0)*E_;
    const int* dstp = ei + ((long)t*2+1)*E_;
    #pragma unroll
    for (int i = 0; i < E_/1024; i++)
        atomicAdd(&cnt[dstp[tid + i*1024]], 1);
    __syncthreads();

    // exclusive scan over 3072 counts (3 contiguous per thread)
    int n0 = tid*3;
    int a = cnt[n0], b = cnt[n0+1], c = cnt[n0+2];
    int tot = a + b + c;
    scanbuf[tid] = tot;
    __syncthreads();
    for (int d = 1; d < 1024; d <<= 1) {
        int add = (tid >= d) ? scanbuf[tid-d] : 0;
        __syncthreads();
        scanbuf[tid] += add;
        __syncthreads();
    }
    int excl = scanbuf[tid] - tot;
    cur[n0] = excl; cur[n0+1] = excl + a; cur[n0+2] = excl + a + b;
    int gbase = t*BN_, ebase = t*E_;
    csr_off[gbase+n0]   = ebase + excl;
    csr_off[gbase+n0+1] = ebase + excl + a;
    csr_off[gbase+n0+2] = ebase + excl + a + b;
    dinv[gbase+n0]   = rsqrtf((float)a + 1.f);
    dinv[gbase+n0+1] = rsqrtf((float)b + 1.f);
    dinv[gbase+n0+2] = rsqrtf((float)c + 1.f);
    if (t == T_-1 && tid == 0) csr_off[M_] = TE_;
    __syncthreads();

    // scatter packed edges into LDS staging
    #pragma unroll
    for (int i = 0; i < E_/1024; i++) {
        int e = tid + i*1024;
        int s = srcp[e], d = dstp[e];
        int pos = atomicAdd(&cur[d], 1);
        float w = rsqrtf((float)cnt[s] + 1.f) * rsqrtf((float)cnt[d] + 1.f);
        pk[pos] = (unsigned int)s | ((unsigned int)f2h(w) << 16);
    }
    __syncthreads();

    // contiguous coalesced write-out
    uint4* dpk = (uint4*)(csr_pk + ebase);
    const uint4* spk = (const uint4*)pk;
    #pragma unroll
    for (int i = 0; i < E_/4096; i++)
        dpk[tid + i*1024] = spk[tid + i*1024];
}

// ---------------- merged weight prep (fragment-swizzled MFMA weights) --------
#define WPREP_TOTAL (384+1024+4096+16384+16384+65536+65536+131072+262144)
__global__ void wprep_k(
    const float* __restrict__ gcn_b, const float* __restrict__ gam,
    const float* __restrict__ bet, const float* __restrict__ mu,
    const float* __restrict__ var,
    float* __restrict__ bn_sc, float* __restrict__ bn_sh,
    const float* __restrict__ bih0, const float* __restrict__ bhh0,
    float* __restrict__ bias0,
    const float* __restrict__ bih1, const float* __restrict__ bhh1,
    float* __restrict__ bias1,
    const float* __restrict__ gcn_w0, const float* __restrict__ gcn_w12,
    ushort* __restrict__ w0t, ushort* __restrict__ w1t, ushort* __restrict__ w2t,
    const float* __restrict__ whh0, const float* __restrict__ whh1,
    unsigned int* __restrict__ wpk0, unsigned int* __restrict__ wpk1,
    const float* __restrict__ wih0, const float* __restrict__ wih1,
    ushort* __restrict__ wih0b, ushort* __restrict__ wih1b)
{
    int i = blockIdx.x * blockDim.x + threadIdx.x;
    if (i >= WPREP_TOTAL) return;
    if (i < 384) {
        float sc = gam[i] * rsqrtf(var[i] + EPS_);
        bn_sc[i] = sc;
        bn_sh[i] = gcn_b[i]*sc + bet[i] - mu[i]*sc;
        return;
    }
    i -= 384;
    if (i < 1024) {
        bias0[i] = bih0[i] + bhh0[i];
        bias1[i] = bih1[i] + bhh1[i];
        return;
    }
    i -= 1024;
    if (i < 4096) {       // w0t frag, K=16
        int e = i & 7, lane = (i >> 3) & 63, ct = i >> 9;
        int k = (lane >> 4)*8 + e;
        int c = ct*16 + (lane & 15);
        w0t[i] = (k < 16) ? f2h(gcn_w0[k*128 + c]) : (ushort)0;
        return;
    }
    i -= 4096;
    if (i < 16384) {      // w1t frag, K=128
        int e = i & 7, lane = (i >> 3) & 63, kk = (i >> 9) & 3, ct = i >> 11;
        int k = kk*32 + (lane >> 4)*8 + e;
        int c = ct*16 + (lane & 15);
        w1t[i] = f2h(gcn_w12[k*128 + c]);
        return;
    }
    i -= 16384;
    if (i < 16384) {      // w2t frag
        int e = i & 7, lane = (i >> 3) & 63, kk = (i >> 9) & 3, ct = i >> 11;
        int k = kk*32 + (lane >> 4)*8 + e;
        int c = ct*16 + (lane & 15);
        w2t[i] = f2h(gcn_w12[16384 + k*128 + c]);
        return;
    }
    i -= 16384;
    if (i < 65536) {
        int g = i & 511;
        int qd = i >> 9;
        int dir = qd >> 6, q = qd & 63;
        const float* wr = whh0 + ((long)(dir*512 + g))*128 + 2*q;
        wpk0[i] = (unsigned int)f2h(wr[0]) | ((unsigned int)f2h(wr[1]) << 16);
        return;
    }
    i -= 65536;
    if (i < 65536) {
        int g = i & 511;
        int qd = i >> 9;
        int dir = qd >> 6, q = qd & 63;
        const float* wr = whh1 + ((long)(dir*512 + g))*128 + 2*q;
        wpk1[i] = (unsigned int)f2h(wr[0]) | ((unsigned int)f2h(wr[1]) << 16);
        return;
    }
    i -= 65536;
    if (i < 131072) {     // wih0b frag, N=512, K=128
        int dir = i >> 16, r = i & 0xFFFF;
        int nt = r >> 11, kk = (r >> 9) & 3, lane = (r >> 3) & 63, e = r & 7;
        int n = nt*16 + (lane & 15);
        int k = kk*32 + (lane >> 4)*8 + e;
        wih0b[i] = f2h(wih0[((long)dir*512 + n)*128 + k]);
        return;
    }
    i -= 131072;
    {                     // wih1b frag, N=512, K=256
        int dir = i >> 17, r = i & 0x1FFFF;
        int nt = r >> 12, kk = (r >> 9) & 7, lane = (r >> 3) & 63, e = r & 7;
        int n = nt*16 + (lane & 15);
        int k = kk*32 + (lane >> 4)*8 + e;
        wih1b[i] = f2h(wih1[((long)dir*512 + n)*256 + k]);
    }
}

// ---------------- f16 gathers ----------------
// out[node,:] = h[node,:]*dinv[node]^2 + sum_e h[src,:]*w[e]

// F=128: one wave per node; lane-parallel edge-word prefetch + readlane walk.
__global__ __launch_bounds__(256) void gather128_k(
    const ushort* __restrict__ h, ushort* __restrict__ out,
    const int* __restrict__ csr_off, const unsigned int* __restrict__ csr_pk,
    const float* __restrict__ dinv)
{
    int nb = gridDim.x;                  // M/4 blocks, 4 waves each; divisible by 8
    int chunk = nb >> 3;
    int bswz = (blockIdx.x & 7) * chunk + (blockIdx.x >> 3);
    int node = __builtin_amdgcn_readfirstlane(bswz * 4 + (threadIdx.x >> 6));
    int tbase = (node / BN_) * BN_;      // scalar
    int lane = threadIdx.x & 63;
    int l2 = lane * 2;                   // feature pair (per-lane)
    int e0 = __builtin_amdgcn_readfirstlane(csr_off[node]);
    int e1 = __builtin_amdgcn_readfirstlane(csr_off[node+1]);
    int deg = e1 - e0;
    // whole edge list in ONE lane-parallel load (deg <= 64 in practice)
    unsigned int mypk = (lane < deg) ? csr_pk[e0 + lane] : 0u;
    float dv = dinv[node];
    ushort swh = f2h(dv * dv);
    unsigned int swp = (unsigned int)swh * 0x10001u;
    unsigned int selfv = *(const unsigned int*)(h + (size_t)node*128 + l2);
    half2v sp = __builtin_bit_cast(half2v, swp);
    half2v acc0 = __builtin_bit_cast(half2v, selfv);
    acc0[0] = acc0[0] * sp[0];
    acc0[1] = acc0[1] * sp[1];
    half2v acc1 = {(_Float16)0.f, (_Float16)0.f};
    half2v acc2 = {(_Float16)0.f, (_Float16)0.f};
    half2v acc3 = {(_Float16)0.f, (_Float16)0.f};
    int dcap = (deg < 64) ? deg : 64;
    int j = 0;
    for (; j + 8 <= dcap; j += 8) {
        unsigned int p0 = (unsigned int)__builtin_amdgcn_readlane((int)mypk, j+0);
        unsigned int p1 = (unsigned int)__builtin_amdgcn_readlane((int)mypk, j+1);
        unsigned int p2 = (unsigned int)__builtin_amdgcn_readlane((int)mypk, j+2);
        unsigned int p3 = (unsigned int)__builtin_amdgcn_readlane((int)mypk, j+3);
        unsigned int p4 = (unsigned int)__builtin_amdgcn_readlane((int)mypk, j+4);
        unsigned int p5 = (unsigned int)__builtin_amdgcn_readlane((int)mypk, j+5);
        unsigned int p6 = (unsigned int)__builtin_amdgcn_readlane((int)mypk, j+6);
        unsigned int p7 = (unsigned int)__builtin_amdgcn_readlane((int)mypk, j+7);
        const ushort* r0 = h + (size_t)(tbase + (int)(p0 & 0xffffu))*128;
        const ushort* r1 = h + (size_t)(tbase + (int)(p1 & 0xffffu))*128;
        const ushort* r2 = h + (size_t)(tbase + (int)(p2 & 0xffffu))*128;
        const ushort* r3 = h + (size_t)(tbase + (int)(p3 & 0xffffu))*128;
        const ushort* r4 = h + (size_t)(tbase + (int)(p4 & 0xffffu))*128;
        const ushort* r5 = h + (size_t)(tbase + (int)(p5 & 0xffffu))*128;
        const ushort* r6 = h + (size_t)(tbase + (int)(p6 & 0xffffu))*128;
        const ushort* r7 = h + (size_t)(tbase + (int)(p7 & 0xffffu))*128;
        unsigned int v0 = *(const unsigned int*)(r0 + l2);
        unsigned int v1 = *(const unsigned int*)(r1 + l2);
        unsigned int v2 = *(const unsigned int*)(r2 + l2);
        unsigned int v3 = *(const unsigned int*)(r3 + l2);
        unsigned int v4 = *(const unsigned int*)(r4 + l2);
        unsigned int v5 = *(const unsigned int*)(r5 + l2);
        unsigned int v6 = *(const unsigned int*)(r6 + l2);
        unsigned int v7 = *(const unsigned int*)(r7 + l2);
        acc0 = pkfma(v0, (p0 >> 16) * 0x10001u, acc0);
        acc1 = pkfma(v1, (p1 >> 16) * 0x10001u, acc1);
        acc2 = pkfma(v2, (p2 >> 16) * 0x10001u, acc2);
        acc3 = pkfma(v3, (p3 >> 16) * 0x10001u, acc3);
        acc0 = pkfma(v4, (p4 >> 16) * 0x10001u, acc0);
        acc1 = pkfma(v5, (p5 >> 16) * 0x10001u, acc1);
        acc2 = pkfma(v6, (p6 >> 16) * 0x10001u, acc2);
        acc3 = pkfma(v7, (p7 >> 16) * 0x10001u, acc3);
    }
    for (; j + 2 <= dcap; j += 2) {
        unsigned int p0 = (unsigned int)__builtin_amdgcn_readlane((int)mypk, j+0);
        unsigned int p1 = (unsigned int)__builtin_amdgcn_readlane((int)mypk, j+1);
        const ushort* r0 = h + (size_t)(tbase + (int)(p0 & 0xffffu))*128;
        const ushort* r1 = h + (size_t)(tbase + (int)(p1 & 0xffffu))*128;
        unsigned int v0 = *(const unsigned int*)(r0 + l2);
        unsigned int v1 = *(const unsigned int*)(r1 + l2);
        acc0 = pkfma(v0, (p0 >> 16) * 0x10001u, acc0);
        acc1 = pkfma(v1, (p1 >> 16) * 0x10001u, acc1);
    }
    for (; j < dcap; j++) {
        unsigned int p0 = (unsigned int)__builtin_amdgcn_readlane((int)mypk, j);
        const ushort* r0 = h + (size_t)(tbase + (int)(p0 & 0xffffu))*128;
        unsigned int v0 = *(const unsigned int*)(r0 + l2);
        acc0 = pkfma(v0, (p0 >> 16) * 0x10001u, acc0);
    }
    // fallback for pathological deg > 64
    for (int jj = e0 + 64; jj < e1; jj++) {
        unsigned int pk = __builtin_amdgcn_readfirstlane(csr_pk[jj]);
        const ushort* r = h + (size_t)(tbase + (int)(pk & 0xffffu))*128;
        unsigned int v = *(const unsigned int*)(r + l2);
        acc0 = pkfma(v, (pk >> 16) * 0x10001u, acc0);
    }
    float a0 = ((float)acc0[0] + (float)acc1[0]) + ((float)acc2[0] + (float)acc3[0]);
    float a1 = ((float)acc0[1] + (float)acc1[1]) + ((float)acc2[1] + (float)acc3[1]);
    unsigned int ov = (unsigned int)f2h(a0) | ((unsigned int)f2h(a1) << 16);
    *(unsigned int*)(out + (size_t)node*128 + l2) = ov;
}

// F=16, fused f32->f16 conversion: reads x (f32), writes f16 agg.
__global__ __launch_bounds__(256) void gather16f_k(
    const float* __restrict__ x, ushort* __restrict__ out,
    const int* __restrict__ csr_off, const unsigned int* __restrict__ csr_pk,
    const float* __restrict__ dinv)
{
    int nb = gridDim.x;                  // M/32
    int chunk = nb >> 3;
    int bswz = (blockIdx.x & 7) * chunk + (blockIdx.x >> 3);
    int node = bswz * 32 + (threadIdx.x >> 3);
    int f0 = (threadIdx.x & 7) * 2;
    int tbase = (node / BN_) * BN_;
    float dv = dinv[node];
    float2 sv = *(const float2*)(x + (long)node*16 + f0);
    float s = dv * dv;
    float a0 = sv.x*s, a1 = sv.y*s;
    int e0 = csr_off[node], e1 = csr_off[node+1];
    int j = e0;
    for (; j + 4 <= e1; j += 4) {
        unsigned int p0 = csr_pk[j], p1 = csr_pk[j+1], p2 = csr_pk[j+2], p3 = csr_pk[j+3];
        int s0 = tbase + (int)(p0 & 0xffffu), s1 = tbase + (int)(p1 & 0xffffu);
        int s2 = tbase + (int)(p2 & 0xffffu), s3 = tbase + (int)(p3 & 0xffffu);
        float w0 = h2f((ushort)(p0 >> 16)), w1 = h2f((ushort)(p1 >> 16));
        float w2 = h2f((ushort)(p2 >> 16)), w3 = h2f((ushort)(p3 >> 16));
        float2 v0 = *(const float2*)(x + (long)s0*16 + f0);
        float2 v1 = *(const float2*)(x + (long)s1*16 + f0);
        float2 v2 = *(const float2*)(x + (long)s2*16 + f0);
        float2 v3 = *(const float2*)(x + (long)s3*16 + f0);
        a0 += v0.x*w0 + v1.x*w1 + v2.x*w2 + v3.x*w3;
        a1 += v0.y*w0 + v1.y*w1 + v2.y*w2 + v3.y*w3;
    }
    for (; j < e1; j++) {
        unsigned int pk = csr_pk[j];
        int sc = tbase + (int)(pk & 0xffffu);
        float en = h2f((ushort)(pk >> 16));
        float2 v = *(const float2*)(x + (long)sc*16 + f0);
        a0 += v.x*en; a1 += v.y*en;
    }
    unsigned int ov = (unsigned int)f2h(a0) | ((unsigned int)f2h(a1) << 16);
    *(unsigned int*)(out + (long)node*16 + f0) = ov;
}

// ---------------- MFMA GEMM: GCN layers, frag-swizzled Wt, LDS epilogue -------
template<int K, bool HASRES>
__global__ __launch_bounds__(256) void mm_mfma_k(
    const ushort* __restrict__ A, const ushort* __restrict__ Wt,
    ushort* __restrict__ Cout,
    const float* __restrict__ bnsc, const float* __restrict__ bnsh,
    const ushort* __restrict__ resid)
{
    constexpr int KST = (K >= 32) ? (K/32) : 1;
    int tid = threadIdx.x;
    int w = tid >> 6, lane = tid & 63;
    int l16 = lane & 15, lh = lane >> 4;
    int row0 = blockIdx.x * 64 + w * 16;
    __shared__ ushort cl[64][136];   // padded to kill bank conflicts

    f32x4 acc[8];
    #pragma unroll
    for (int i = 0; i < 8; i++) acc[i] = (f32x4){0.f, 0.f, 0.f, 0.f};

    #pragma unroll
    for (int kk = 0; kk < KST; kk++) {
        int ka = kk*32 + lh*8;
        f16x8 af;
        bool valid = (K >= 32) || (ka < K);
        if (valid) {
            af = *reinterpret_cast<const f16x8*>(&A[(long)(row0 + l16)*K + ka]);
        } else {
            #pragma unroll
            for (int e = 0; e < 8; e++) af[e] = (_Float16)0.f;
        }
        #pragma unroll
        for (int ct = 0; ct < 8; ct++) {
            f16x8 bfr = *reinterpret_cast<const f16x8*>(
                &Wt[(((long)ct*KST + kk)*64 + lane)*8]);
            acc[ct] = __builtin_amdgcn_mfma_f32_16x16x32_f16(af, bfr, acc[ct], 0, 0, 0);
        }
    }

    // BN+ReLU into LDS (f16), then coalesced vectorized write (+resid)
    #pragma unroll
    for (int ct = 0; ct < 8; ct++) {
        int col = ct*16 + l16;
        float sc = bnsc[col], sh = bnsh[col];
        #pragma unroll
        for (int r = 0; r < 4; r++) {
            int rl = w*16 + lh*4 + r;
            float v = acc[ct][r] * sc + sh;
            cl[rl][col] = f2h(fmaxf(v, 0.f));
        }
    }
    __syncthreads();
    long rowblock = (long)blockIdx.x * 64;
    #pragma unroll
    for (int it = 0; it < 4; it++) {
        int s = it*256 + tid;           // 1024 segments: 64 rows x 16 (8-col segs)
        int rl = s >> 4, c8 = (s & 15) * 8;
        uint4 v = *(const uint4*)&cl[rl][c8];
        if (HASRES) {
            uint4 rv = *(const uint4*)&resid[(rowblock + rl)*128 + c8];
            half2v* vv = (half2v*)&v;
            const half2v* rr = (const half2v*)&rv;
            vv[0] += rr[0]; vv[1] += rr[1]; vv[2] += rr[2]; vv[3] += rr[3];
        }
        *(uint4*)&Cout[(rowblock + rl)*128 + c8] = v;
    }
}

// ---------------- MFMA GEMM: LSTM input projection (frag-swizzled Wt) --------
template<int K>
__global__ __launch_bounds__(256) void mm_pre_k(
    const ushort* __restrict__ A, const ushort* __restrict__ Wt_all,
    float* __restrict__ Cout_all, const float* __restrict__ bias_all)
{
    constexpr int KST = K/32;
    int dir = blockIdx.z;
    const ushort* Wt = Wt_all + (size_t)dir * 512 * K;
    float* Cout = Cout_all + (size_t)dir * T_ * B_ * 512;
    const float* bias = bias_all + dir * 512;

    int tid = threadIdx.x;
    int w = tid >> 6, lane = tid & 63;
    int l16 = lane & 15, lh = lane >> 4;
    int row0 = blockIdx.x * 64 + w * 16;
    int nt0 = blockIdx.y * 8;    // col-tile base (8 tiles of 16 -> 128 cols)

    f32x4 acc[8];
    #pragma unroll
    for (int i = 0; i < 8; i++) acc[i] = (f32x4){0.f, 0.f, 0.f, 0.f};

    #pragma unroll
    for (int kk = 0; kk < KST; kk++) {
        int ka = kk*32 + lh*8;
        f16x8 af = *reinterpret_cast<const f16x8*>(&A[(long)(row0 + l16)*K + ka]);
        #pragma unroll
        for (int ct = 0; ct < 8; ct++) {
            f16x8 bfr = *reinterpret_cast<const f16x8*>(
                &Wt[(((long)(nt0 + ct)*KST + kk)*64 + lane)*8]);
            acc[ct] = __builtin_amdgcn_mfma_f32_16x16x32_f16(af, bfr, acc[ct], 0, 0, 0);
        }
    }

    #pragma unroll
    for (int ct = 0; ct < 8; ct++) {
        int col = (nt0 + ct)*16 + l16;
        float bv = bias[col];
        #pragma unroll
        for (int r = 0; r < 4; r++) {
            int row = row0 + lh*4 + r;
            Cout[(long)row*512 + col] = acc[ct][r] + bv;
        }
    }
}

// ---------------- mean pool (f16 in, f16 out) ----------------

__global__ void meanpool_k(const ushort* __restrict__ h, ushort* __restrict__ embb) {
    int row = blockIdx.x;            // t*B + b
    int t = row / B_, b = row - t*B_;
    int hh = threadIdx.x;
    const ushort* base = h + ((long)t*BN_ + b*N_)*H_ + hh;
    float acc = 0.f;
    for (int n = 0; n < N_; n++) acc += h2f(base[(long)n*H_]);
    embb[(long)row*H_ + hh] = f2h(acc * (1.f / N_));
}

// ---------------- LSTM scan: f16 dot2, k-split x2, pre-prefetch ----------------
__global__ __launch_bounds__(1024) void lstm_scan_k(
    const float* __restrict__ pre,            // [2][T*B][512]
    const unsigned int* __restrict__ wpkbuf,  // [2][64][512] packed f16 pairs
    float* __restrict__ out,                  // [T*B][256] f32 (nullable)
    ushort* __restrict__ outb)                // [T*B][256] f16 (nullable)
{
    int dir = blockIdx.x >> 5;
    int b   = blockIdx.x & 31;
    int tid = threadIdx.x;
    int half = tid >> 9;
    int g    = tid & 511;

    __shared__ ushort h_s[H_];               // f16 bits
    __shared__ float part[1024];
    if (tid < H_) h_s[tid] = 0;
    float creg = 0.f;

    const unsigned int* wp = wpkbuf + (long)dir * 64 * 512 + (long)half * 32 * 512;
    unsigned int wpk[32];
    #pragma unroll
    for (int q = 0; q < 32; q++) wpk[q] = wp[q*512 + g];

    const float* pred = pre + (long)dir * T_ * B_ * 512;
    int t = dir ? (T_ - 1) : 0;
    int tstep = dir ? -1 : 1;
    float pv = (half == 0) ? pred[((long)t*B_ + b)*512 + g] : 0.f;
    __syncthreads();

    for (int st = 0; st < T_; st++) {
        int tn = t + tstep;
        tn = (tn < 0) ? 0 : ((tn >= T_) ? T_ - 1 : tn);
        float pvn = (half == 0) ? pred[((long)tn*B_ + b)*512 + g] : 0.f;

        const uint4* h4 = (const uint4*)(h_s + half*64);
        float acc = pv;
        #pragma unroll
        for (int jj = 0; jj < 8; jj++) {
            uint4 hv = h4[jj];
            acc = dot2pk(hv.x, wpk[jj*4+0], acc);
            acc = dot2pk(hv.y, wpk[jj*4+1], acc);
            acc = dot2pk(hv.z, wpk[jj*4+2], acc);
            acc = dot2pk(hv.w, wpk[jj*4+3], acc);
        }
        part[tid] = acc;
        __syncthreads();

        if (tid < H_) {
            float ig = sigm (part[tid]       + part[512 + tid]);
            float fg = sigm (part[128 + tid] + part[640 + tid]);
            float gg = ftanh(part[256 + tid] + part[768 + tid]);
            float og = sigm (part[384 + tid] + part[896 + tid]);
            float c = fg * creg + ig * gg;
            float h = og * ftanh(c);
            creg = c;
            h_s[tid] = f2h(h);
            long orow = ((long)t*B_ + b)*256 + dir*H_ + tid;
            if (out)  out[orow] = h;
            if (outb) outb[orow] = f2h(h);
        }
        __syncthreads();
        pv = pvn;
        t = tn;
    }
}

// ---------------- attention ----------------

__global__ __launch_bounds__(128) void attn_a_k(
    const float* __restrict__ out2, const float* __restrict__ w1,
    const float* __restrict__ b1, const float* __restrict__ w2,
    const float* __restrict__ b2v, float* __restrict__ a)
{
    int row = blockIdx.x;
    int j = threadIdx.x;
    const float* xr = out2 + (long)row * 256;
    float acc = b1[j];
    for (int k = 0; k < 256; k++) acc += xr[k] * w1[k*128 + j];
    float u = tanhf(acc) * w2[j];
    __shared__ float red[128];
    red[j] = u;
    __syncthreads();
    for (int d = 64; d > 0; d >>= 1) {
        if (j < d) red[j] += red[j + d];
        __syncthreads();
    }
    if (j == 0) {
        int t = row / B_, b = row - t*B_;
        a[b*T_ + t] = red[0] + b2v[0];
    }
}

__global__ __launch_bounds__(256) void attn_pool_k(
    const float* __restrict__ out2, const float* __restrict__ a,
    float* __restrict__ wsv)
{
    int b = blockIdx.x;
    __shared__ float w[T_];
    if (threadIdx.x == 0) {
        float m = -1e30f;
        for (int t = 0; t < T_; t++) m = fmaxf(m, a[b*T_ + t]);
        float s = 0.f;
        for (int t = 0; t < T_; t++) { float e = __expf(a[b*T_ + t] - m); w[t] = e; s += e; }
        float inv = 1.f / s;
        for (int t = 0; t < T_; t++) w[t] *= inv;
    }
    __syncthreads();
    int h2 = threadIdx.x;
    float acc = 0.f;
    for (int t = 0; t < T_; t++) acc += w[t] * out2[((long)t*B_ + b)*256 + h2];
    wsv[b*256 + h2] = acc;
}

// ---------------- FC head + log_softmax ----------------

__global__ __launch_bounds__(512) void head_k(
    const float* __restrict__ wsv, const float* __restrict__ w1,
    const float* __restrict__ b1, const float* __restrict__ w2,
    const float* __restrict__ b2, float* __restrict__ outp)
{
    int b = blockIdx.x;
    int tid = threadIdx.x;
    __shared__ float r[128];
    __shared__ float y[C_];
    __shared__ float red[512];
    if (tid < 128) {
        float acc = b1[tid];
        for (int k = 0; k < 256; k++) acc += wsv[b*256 + k] * w1[k*128 + tid];
        r[tid] = fmaxf(acc, 0.f);
    }
    __syncthreads();
    for (int c = tid; c < C_; c += 512) {
        float acc = b2[c];
        for (int k = 0; k < 128; k++) acc += r[k] * w2[k*C_ + c];
        y[c] = acc;
    }
    __syncthreads();
    float m = -1e30f;
    for (int c = tid; c < C_; c += 512) m = fmaxf(m, y[c]);
    red[tid] = m;
    __syncthreads();
    for (int d = 256; d > 0; d >>= 1) {
        if (tid < d) red[tid] = fmaxf(red[tid], red[tid + d]);
        __syncthreads();
    }
    m = red[0];
    __syncthreads();
    float s = 0.f;
    for (int c = tid; c < C_; c += 512) s += __expf(y[c] - m);
    red[tid] = s;
    __syncthreads();
    for (int d = 256; d > 0; d >>= 1) {
        if (tid < d) red[tid] += red[tid + d];
        __syncthreads();
    }
    float lse = m + logf(red[0]);
    for (int c = tid; c < C_; c += 512) outp[(long)b*C_ + c] = y[c] - lse;
}

// ---------------- launch ----------------

extern "C" void kernel_launch(void* const* d_in, const int* in_sizes, int n_in,
                              void* d_out, int out_size, void* d_ws, size_t ws_size,
                              hipStream_t stream) {
    const float* x        = (const float*)d_in[0];
    const int*   ei       = (const int*)d_in[1];
    const float* gcn_w0   = (const float*)d_in[2];
    const float* gcn_w12  = (const float*)d_in[3];
    const float* gcn_b    = (const float*)d_in[4];
    const float* bn_gamma = (const float*)d_in[5];
    const float* bn_beta  = (const float*)d_in[6];
    const float* bn_mean  = (const float*)d_in[7];
    const float* bn_var   = (const float*)d_in[8];
    const float* wih0     = (const float*)d_in[9];
    const float* whh0     = (const float*)d_in[10];
    const float* bih0     = (const float*)d_in[11];
    const float* bhh0     = (const float*)d_in[12];
    const float* wih1     = (const float*)d_in[13];
    const float* whh1     = (const float*)d_in[14];
    const float* bih1     = (const float*)d_in[15];
    const float* bhh1     = (const float*)d_in[16];
    const float* attn_w1  = (const float*)d_in[17];
    const float* attn_b1  = (const float*)d_in[18];
    const float* attn_w2  = (const float*)d_in[19];
    const float* attn_b2  = (const float*)d_in[20];
    const float* fc1_w    = (const float*)d_in[21];
    const float* fc1_b    = (const float*)d_in[22];
    const float* fc2_w    = (const float*)d_in[23];
    const float* fc2_b    = (const float*)d_in[24];

    char* p = (char*)d_ws;
    auto alloc = [&](size_t bytes) {
        void* r = (void*)p;
        p += (bytes + 255) & ~(size_t)255;
        return r;
    };
    ushort* aggbuf = (ushort*)alloc((size_t)M_*H_*2);
    ushort* hbA    = (ushort*)alloc((size_t)M_*H_*2);
    ushort* hbB    = (ushort*)alloc((size_t)M_*H_*2);
    float* dinv    = (float*)alloc((size_t)M_*4);
    int*   csr_off = (int*)  alloc((size_t)(M_+1)*4);
    unsigned int* csr_pk = (unsigned int*)alloc((size_t)TE_*4);
    float* bn_sc   = (float*)alloc(384*4);
    float* bn_sh   = (float*)alloc(384*4);
    float* bias0   = (float*)alloc(1024*4);
    float* bias1   = (float*)alloc(1024*4);
    ushort* w0t    = (ushort*)alloc((size_t)4096*2);
    ushort* w1t    = (ushort*)alloc((size_t)16384*2);
    ushort* w2t    = (ushort*)alloc((size_t)16384*2);
    unsigned int* wpk0 = (unsigned int*)alloc((size_t)2*64*512*4);
    unsigned int* wpk1 = (unsigned int*)alloc((size_t)2*64*512*4);
    ushort* wih0b  = (ushort*)alloc((size_t)2*512*128*2);
    ushort* wih1b  = (ushort*)alloc((size_t)2*512*256*2);
    ushort* embb   = (ushort*)alloc((size_t)T_*B_*H_*2);
    float* pre     = (float*)alloc((size_t)2*T_*B_*512*4);
    ushort* out1b  = (ushort*)alloc((size_t)T_*B_*256*2);
    float* out2v   = (float*)alloc((size_t)T_*B_*256*4);
    float* attn_av = (float*)alloc((size_t)B_*T_*4);
    float* wsv     = (float*)alloc((size_t)B_*256*4);

    // --- fused CSR build (count+scan+scatter per timestep, LDS-staged) ---
    csr_build_k<<<T_, 1024, 0, stream>>>(ei, csr_off, csr_pk, dinv);

    // --- weight prep (merged, fragment-swizzled) ---
    wprep_k<<<(WPREP_TOTAL+255)/256, 256, 0, stream>>>(
        gcn_b, bn_gamma, bn_beta, bn_mean, bn_var, bn_sc, bn_sh,
        bih0, bhh0, bias0, bih1, bhh1, bias1,
        gcn_w0, gcn_w12, w0t, w1t, w2t,
        whh0, whh1, wpk0, wpk1,
        wih0, wih1, wih0b, wih1b);

    // --- GCN layer 0 (conversion fused into gather) ---
    gather16f_k<<<M_/32, 256, 0, stream>>>(x, aggbuf, csr_off, csr_pk, dinv);
    mm_mfma_k<16, false><<<M_/64, 256, 0, stream>>>(aggbuf, w0t, hbA,
                                                    bn_sc + 0, bn_sh + 0, nullptr);
    // --- GCN layer 1 ---
    gather128_k<<<M_/4, 256, 0, stream>>>(hbA, aggbuf, csr_off, csr_pk, dinv);
    mm_mfma_k<128, true><<<M_/64, 256, 0, stream>>>(aggbuf, w1t, hbB,
                                                    bn_sc + 128, bn_sh + 128, hbA);
    // --- GCN layer 2 ---
    gather128_k<<<M_/4, 256, 0, stream>>>(hbB, aggbuf, csr_off, csr_pk, dinv);
    mm_mfma_k<128, true><<<M_/64, 256, 0, stream>>>(aggbuf, w2t, hbA,
                                                    bn_sc + 256, bn_sh + 256, hbB);

    // --- mean pool -> embb [T*B,128] f16 ---
    meanpool_k<<<T_*B_, 128, 0, stream>>>(hbA, embb);

    // --- BiLSTM layer 0 ---
    mm_pre_k<128><<<dim3((T_*B_)/64, 4, 2), 256, 0, stream>>>(embb, wih0b, pre, bias0);
    lstm_scan_k<<<64, 1024, 0, stream>>>(pre, wpk0, nullptr, out1b);

    // --- BiLSTM layer 1 ---
    mm_pre_k<256><<<dim3((T_*B_)/64, 4, 2), 256, 0, stream>>>(out1b, wih1b, pre, bias1);
    lstm_scan_k<<<64, 1024, 0, stream>>>(pre, wpk1, out2v, nullptr);

    // --- attention ---
    attn_a_k<<<T_*B_, 128, 0, stream>>>(out2v, attn_w1, attn_b1, attn_w2, attn_b2, attn_av);
    attn_pool_k<<<B_, 256, 0, stream>>>(out2v, attn_av, wsv);

    // --- head ---
    head_k<<<B_, 512, 0, stream>>>(wsv, fc1_w, fc1_b, fc2_w, fc2_b, (float*)d_out);
}